// Round 9
// baseline (251.532 us; speedup 1.0000x reference)
//
#include <hip/hip_runtime.h>

#define T_  4
#define B_  2
#define C_  384
#define L_  1024
#define H_  8
#define C2_ 768

typedef __attribute__((ext_vector_type(8))) short short8;
typedef __attribute__((ext_vector_type(4))) float floatx4;
typedef __attribute__((ext_vector_type(16))) float floatx16;

__device__ __forceinline__ unsigned bf16_rne(float v) {
    unsigned u = __float_as_uint(v);
    u += 0x7FFFu + ((u >> 16) & 1u);
    return u >> 16;
}
__device__ __forceinline__ float bf16_to_f(unsigned h) { return __uint_as_float(h << 16); }
__device__ __forceinline__ void split3(float v, unsigned& hi, unsigned& mi, unsigned& lo) {
    hi = bf16_rne(v);
    float r1 = v - bf16_to_f(hi);
    mi = bf16_rne(r1);
    float r2 = r1 - bf16_to_f(mi);
    lo = bf16_rne(r2);
}

// ==== K1+K0: blocks 0-383 run the xs scan (64l x 32c tiles, prefetched);
// blocks 384-815 split both fp32 weight tensors into 3 bf16 planes.
__global__ __launch_bounds__(256) void scan_and_split(
    const float* __restrict__ src, unsigned short* __restrict__ dstT,
    unsigned short* __restrict__ xsF,
    const float* __restrict__ Wa, int n4a,
    unsigned short* __restrict__ hia, unsigned short* __restrict__ mia,
    unsigned short* __restrict__ loa,
    const float* __restrict__ Wb, int n4b,
    unsigned short* __restrict__ hib, unsigned short* __restrict__ mib,
    unsigned short* __restrict__ lob) {
    __shared__ unsigned short tile[32][72];
    const int tid = threadIdx.x;
    if (blockIdx.x >= 384) {
        int i = (blockIdx.x - 384) * 256 + tid;
        const float* W; unsigned short *hi, *mi, *lo;
        if (i < n4a) { W = Wa; hi = hia; mi = mia; lo = loa; }
        else {
            i -= n4a;
            if (i >= n4b) return;
            W = Wb; hi = hib; mi = mib; lo = lob;
        }
        float4 v = ((const float4*)W)[i];
        float vv[4] = {v.x, v.y, v.z, v.w};
        union { unsigned short us[4]; uint2 u2; } h, m, l;
#pragma unroll
        for (int e = 0; e < 4; e++) {
            unsigned hh, mm, ll; split3(vv[e], hh, mm, ll);
            h.us[e] = (unsigned short)hh; m.us[e] = (unsigned short)mm; l.us[e] = (unsigned short)ll;
        }
        ((uint2*)hi)[i] = h.u2; ((uint2*)mi)[i] = m.u2; ((uint2*)lo)[i] = l.u2;
        return;
    }
    // ---- scan branch: job 0..383 = l0(16) x c0(12) x b(2) ----
    const int job = blockIdx.x;
    const int l0 = (job & 15) * 64;
    const int c0 = ((job >> 4) % 12) * 32;
    const int b  = job / 192;
    const int row = tid >> 3, seg = tid & 7;     // 32 c-rows x 8 l-segs
    float mem[8], sp[8];
#pragma unroll
    for (int e = 0; e < 8; e++) { mem[e] = 0.f; sp[e] = 0.f; }
    const size_t base0 = ((size_t)(b*C_ + c0 + row))*L_ + l0 + seg*8;
    float4 nx0 = *(const float4*)(src + base0);
    float4 nx1 = *(const float4*)(src + base0 + 4);
    for (int t = 0; t < T_; t++) {
        float4 v0 = nx0, v1 = nx1;
        if (t < 3) {
            const size_t nb = ((size_t)(((t+1)*B_ + b)*C_ + c0 + row))*L_ + l0 + seg*8;
            nx0 = *(const float4*)(src + nb);
            nx1 = *(const float4*)(src + nb + 4);
        }
        float vv[8] = {v0.x,v0.y,v0.z,v0.w,v1.x,v1.y,v1.z,v1.w};
        unsigned bs[8];
#pragma unroll
        for (int e = 0; e < 8; e++) {
            mem[e] = mem[e]*0.25f*(1.f - sp[e]) + vv[e];
            bool sb = mem[e] > 0.5f;
            sp[e] = sb ? 1.f : 0.f;
            bs[e] = sb ? 0x3F80u : 0u;
        }
#pragma unroll
        for (int p2 = 0; p2 < 4; p2++)
            *(unsigned*)&tile[row][seg*8 + p2*2] = bs[p2*2] | (bs[p2*2+1] << 16);
        __syncthreads();
        {
            const int lr = tid >> 2, cs = tid & 3;   // 64 l-rows x 4 c-chunks
            unsigned wv[4];
#pragma unroll
            for (int p = 0; p < 4; p++) {
                unsigned e0 = tile[cs*8 + p*2][lr];
                unsigned e1 = tile[cs*8 + p*2 + 1][lr];
                wv[p] = e0 | (e1 << 16);
            }
            uint4 o; o.x = wv[0]; o.y = wv[1]; o.z = wv[2]; o.w = wv[3];
            const int cc = c0 + cs*8;
            *(uint4*)(dstT + ((size_t)(t*B_ + b)*L_ + l0 + lr)*C_ + cc) = o;
            const int hh = cc / 48, kc = (cc % 48) >> 3;
            *(uint4*)(xsF + ((((size_t)(t*B_ + b)*H_ + hh)*6 + kc)*L_ + l0 + lr)*8) = o;
        }
        __syncthreads();
    }
}

// ============ K5: scan over T of (outpre + outpre2) + bf16 transpose =======
__global__ __launch_bounds__(256) void scan_transpose2(
    const float* __restrict__ srcA, const float* __restrict__ srcB,
    unsigned short* __restrict__ dstT) {
    __shared__ unsigned short tile[32][72];
    const int tid = threadIdx.x;
    const int job = blockIdx.x;
    const int l0 = (job & 15) * 64;
    const int c0 = ((job >> 4) % 12) * 32;
    const int b  = job / 192;
    const int row = tid >> 3, seg = tid & 7;
    float mem[8], sp[8];
#pragma unroll
    for (int e = 0; e < 8; e++) { mem[e] = 0.f; sp[e] = 0.f; }
    const size_t base0 = ((size_t)(b*C_ + c0 + row))*L_ + l0 + seg*8;
    float4 na0 = *(const float4*)(srcA + base0);
    float4 na1 = *(const float4*)(srcA + base0 + 4);
    float4 nb0 = *(const float4*)(srcB + base0);
    float4 nb1 = *(const float4*)(srcB + base0 + 4);
    for (int t = 0; t < T_; t++) {
        float4 a0 = na0, a1 = na1, b0 = nb0, b1 = nb1;
        if (t < 3) {
            const size_t nb = ((size_t)(((t+1)*B_ + b)*C_ + c0 + row))*L_ + l0 + seg*8;
            na0 = *(const float4*)(srcA + nb);
            na1 = *(const float4*)(srcA + nb + 4);
            nb0 = *(const float4*)(srcB + nb);
            nb1 = *(const float4*)(srcB + nb + 4);
        }
        float vv[8] = {a0.x+b0.x, a0.y+b0.y, a0.z+b0.z, a0.w+b0.w,
                       a1.x+b1.x, a1.y+b1.y, a1.z+b1.z, a1.w+b1.w};
        unsigned bs[8];
#pragma unroll
        for (int e = 0; e < 8; e++) {
            mem[e] = mem[e]*0.25f*(1.f - sp[e]) + vv[e];
            bool sb = mem[e] > 0.5f;
            sp[e] = sb ? 1.f : 0.f;
            bs[e] = sb ? 0x3F80u : 0u;
        }
#pragma unroll
        for (int p2 = 0; p2 < 4; p2++)
            *(unsigned*)&tile[row][seg*8 + p2*2] = bs[p2*2] | (bs[p2*2+1] << 16);
        __syncthreads();
        {
            const int lr = tid >> 2, cs = tid & 3;
            unsigned wv[4];
#pragma unroll
            for (int p = 0; p < 4; p++) {
                unsigned e0 = tile[cs*8 + p*2][lr];
                unsigned e1 = tile[cs*8 + p*2 + 1][lr];
                wv[p] = e0 | (e1 << 16);
            }
            uint4 o; o.x = wv[0]; o.y = wv[1]; o.z = wv[2]; o.w = wv[3];
            *(uint4*)(dstT + ((size_t)(t*B_ + b)*L_ + l0 + lr)*C_ + c0 + cs*8) = o;
        }
        __syncthreads();
    }
}

// ============ K2: y = BN1(W @ xs) via MFMA, 96m x 64l tile =================
// Register-prefetched K-loop (next K-step loads fly under current MFMAs) +
// LDS row stride 44 shorts (22 dwords, gcd(22,32)=2 -> free 2-way instead of
// 4-way read conflicts at stride 40).
__global__ __launch_bounds__(256) void gemm1_mfma(
    const unsigned short* __restrict__ whi, const unsigned short* __restrict__ wmi,
    const unsigned short* __restrict__ wlo, const unsigned short* __restrict__ xsT,
    const float* __restrict__ g, const float* __restrict__ be,
    const float* __restrict__ mn, const float* __restrict__ vr,
    unsigned short* __restrict__ y1hi, unsigned short* __restrict__ y1mi,
    unsigned short* __restrict__ y1lo,
    unsigned short* __restrict__ y2hi, unsigned short* __restrict__ y2mi,
    unsigned short* __restrict__ y2lo) {
    __shared__ unsigned short smem[15488];   // A: 3 x 96 x 44 @ {0,4224,8448}; B: 64 x 44 @ 12672
    const int tid = threadIdx.x;
    const int flat = blockIdx.x;
    const int tb = flat & 7;
    const int ii = flat >> 3;
    const int mt = ii >> 4, lt = ii & 15;
    const int l0 = lt * 64;
    const int w = tid >> 6, lane = tid & 63;
    const int q = lane >> 4, n15 = lane & 15;
    const int mw = (w & 1) * 48, lw = (w >> 1) * 32;

    floatx4 acc[3][2];
#pragma unroll
    for (int i = 0; i < 3; i++)
#pragma unroll
        for (int j = 0; j < 2; j++) acc[i][j] = (floatx4){0.f,0.f,0.f,0.f};

    const int ar0 = tid >> 2, ac = tid & 3;          // A stage: s = tid
    const int ar1 = (tid + 256) >> 2;                // A stage: s = tid+256 (tid<128)
    const int br = tid >> 2, bc = tid & 3;           // B stage
    const size_t wrow0 = (size_t)(mt*96 + ar0)*C_;
    const size_t wrow1 = (size_t)(mt*96 + ar1)*C_;
    const size_t brow  = ((size_t)tb*L_ + l0 + br)*C_;

    uint4 rA[3][2]; uint4 rB;
#pragma unroll
    for (int p = 0; p < 3; p++) {
        const unsigned short* wp = p == 0 ? whi : p == 1 ? wmi : wlo;
        rA[p][0] = *(const uint4*)(wp + wrow0 + ac*8);
        if (tid < 128) rA[p][1] = *(const uint4*)(wp + wrow1 + ac*8);
    }
    rB = *(const uint4*)(xsT + brow + bc*8);

    for (int ck = 0; ck < C_; ck += 32) {
#pragma unroll
        for (int p = 0; p < 3; p++) {
            unsigned short* ap = smem + p*4224;
            *(uint4*)&ap[ar0*44 + ac*8] = rA[p][0];
            if (tid < 128) *(uint4*)&ap[ar1*44 + ac*8] = rA[p][1];
        }
        *(uint4*)&smem[12672 + br*44 + bc*8] = rB;
        __syncthreads();
        if (ck + 32 < C_) {
            const int nk = ck + 32;
#pragma unroll
            for (int p = 0; p < 3; p++) {
                const unsigned short* wp = p == 0 ? whi : p == 1 ? wmi : wlo;
                rA[p][0] = *(const uint4*)(wp + wrow0 + nk + ac*8);
                if (tid < 128) rA[p][1] = *(const uint4*)(wp + wrow1 + nk + ac*8);
            }
            rB = *(const uint4*)(xsT + brow + nk + bc*8);
        }
        short8 bb[2];
#pragma unroll
        for (int in = 0; in < 2; in++)
            bb[in] = *(short8*)&smem[12672 + (lw + in*16 + n15)*44 + q*8];
#pragma unroll
        for (int im = 0; im < 3; im++) {
            short8 ah = *(short8*)&smem[       (mw + im*16 + n15)*44 + q*8];
            short8 am = *(short8*)&smem[4224 + (mw + im*16 + n15)*44 + q*8];
            short8 al = *(short8*)&smem[8448 + (mw + im*16 + n15)*44 + q*8];
#pragma unroll
            for (int in = 0; in < 2; in++) {
                acc[im][in] = __builtin_amdgcn_mfma_f32_16x16x32_bf16(ah, bb[in], acc[im][in], 0,0,0);
                acc[im][in] = __builtin_amdgcn_mfma_f32_16x16x32_bf16(am, bb[in], acc[im][in], 0,0,0);
                acc[im][in] = __builtin_amdgcn_mfma_f32_16x16x32_bf16(al, bb[in], acc[im][in], 0,0,0);
            }
        }
        __syncthreads();
    }

#pragma unroll
    for (int im = 0; im < 3; im++)
#pragma unroll
        for (int r = 0; r < 4; r++) {
            int o = mt*96 + mw + im*16 + q*4 + r;
            float inv = g[o] / sqrtf(vr[o] + 1e-5f);
            float sh = be[o] - mn[o]*inv;
#pragma unroll
            for (int in = 0; in < 2; in++)
                acc[im][in][r] = acc[im][in][r]*inv + sh;
        }
    const bool isY1 = ((w & 1) == 0);
#pragma unroll
    for (int p = 0; p < 3; p++) {
        if (isY1) {
#pragma unroll
            for (int im = 0; im < 3; im++)
#pragma unroll
                for (int in = 0; in < 2; in++) {
                    union { unsigned short us[4]; uint2 u2; } pk;
#pragma unroll
                    for (int r = 0; r < 4; r++) {
                        unsigned hh = bf16_rne(acc[im][in][r]);
                        pk.us[r] = (unsigned short)hh;
                        acc[im][in][r] -= bf16_to_f(hh);
                    }
                    *(uint2*)&smem[(lw + in*16 + n15)*56 + im*16 + q*4] = pk.u2;
                }
        } else {
#pragma unroll
            for (int im = 0; im < 3; im++)
#pragma unroll
                for (int in = 0; in < 2; in++)
#pragma unroll
                    for (int r = 0; r < 4; r++) {
                        unsigned hh = bf16_rne(acc[im][in][r]);
                        smem[3584 + (im*16 + q*4 + r)*72 + lw + in*16 + n15] = (unsigned short)hh;
                        acc[im][in][r] -= bf16_to_f(hh);
                    }
        }
        __syncthreads();
        unsigned short* y1p = p == 0 ? y1hi : p == 1 ? y1mi : y1lo;
        unsigned short* y2p = p == 0 ? y2hi : p == 1 ? y2mi : y2lo;
        for (int s = tid; s < 384; s += 256) {
            int c8 = s >> 6, r1 = s & 63;
            *(uint4*)(y1p + ((((size_t)tb*H_ + mt)*6 + c8)*L_ + l0 + r1)*8) =
                *(uint4*)&smem[r1*56 + c8*8];
        }
        for (int s = tid; s < 384; s += 256) {
            int cr = s >> 3, lq = s & 7;
            *(uint4*)(y2p + ((size_t)tb*C_ + mt*48 + cr)*L_ + l0 + lq*8) =
                *(uint4*)&smem[3584 + cr*72 + lq*8];
        }
        __syncthreads();
    }
}

// ============ K3: attn = y1^T @ xr, LDS-free, coalesced fragment loads =====
__global__ __launch_bounds__(256, 4) void attn_spike_mfma(
    const unsigned short* __restrict__ y1hi, const unsigned short* __restrict__ y1mi,
    const unsigned short* __restrict__ y1lo, const unsigned short* __restrict__ xsF,
    unsigned* __restrict__ bits) {
    const int tid = threadIdx.x;
    const int flat = blockIdx.x;
    const int xcd = flat & 7;
    const int ii = flat >> 3;            // 0..255
    const int bh = xcd*2 + (ii >> 7);
    const int rr = ii & 127;
    const int b = bh >> 3, h = bh & 7;
    const int lbase = (rr >> 3) * 64;
    const int mbase = (rr & 7) * 128;
    const int w = tid >> 6, lane = tid & 63;
    const int l31 = lane & 31, half = lane >> 5;
    const int mrow = mbase + w*32 + l31;

    float mem[2][16];
#pragma unroll
    for (int il = 0; il < 2; il++)
#pragma unroll
        for (int r = 0; r < 16; r++) mem[il][r] = 0.f;

    for (int t = 0; t < T_; t++) {
        const int tb = t*B_ + b;
        const size_t fb = ((size_t)tb*H_ + h)*6*L_*8;
        const unsigned short* ya_hi = y1hi + fb;
        const unsigned short* ya_mi = y1mi + fb;
        const unsigned short* ya_lo = y1lo + fb;
        const unsigned short* xf    = xsF  + fb;

        short8 bb[3];
#pragma unroll
        for (int ks = 0; ks < 3; ks++)
            bb[ks] = *(const short8*)(xf + ((size_t)(ks*2 + half)*L_ + mrow)*8);

        floatx16 acc[2];
#pragma unroll
        for (int il = 0; il < 2; il++)
#pragma unroll
            for (int r = 0; r < 16; r++) acc[il][r] = 0.f;

#pragma unroll
        for (int ks = 0; ks < 3; ks++) {
#pragma unroll
            for (int il = 0; il < 2; il++) {
                const size_t aoff = ((size_t)(ks*2 + half)*L_ + lbase + il*32 + l31)*8;
                short8 ah = *(const short8*)(ya_hi + aoff);
                short8 am = *(const short8*)(ya_mi + aoff);
                short8 al = *(const short8*)(ya_lo + aoff);
                acc[il] = __builtin_amdgcn_mfma_f32_32x32x16_bf16(ah, bb[ks], acc[il], 0,0,0);
                acc[il] = __builtin_amdgcn_mfma_f32_32x32x16_bf16(am, bb[ks], acc[il], 0,0,0);
                acc[il] = __builtin_amdgcn_mfma_f32_32x32x16_bf16(al, bb[ks], acc[il], 0,0,0);
            }
        }

        unsigned wds[2];
#pragma unroll
        for (int il = 0; il < 2; il++) {
            unsigned word = 0;
#pragma unroll
            for (int r = 0; r < 16; r++) {
                float m = (mem[il][r] > 0.5f ? 0.f : mem[il][r]*0.25f) + acc[il][r];
                mem[il][r] = m;
                int lloc = (r & 3) + 8*(r >> 2) + 4*half;
                word |= (m > 0.5f) ? (1u << lloc) : 0u;
            }
            wds[il] = word;
        }
        unsigned f0 = wds[0] | __shfl_xor(wds[0], 32);
        unsigned f1 = wds[1] | __shfl_xor(wds[1], 32);
        if (half == 0) {
            uint2 o; o.x = f0; o.y = f1;
            ((uint2*)bits)[((size_t)(tb*H_ + h)*16 + (lbase >> 6))*1024 + mrow] = o;
        }
    }
}

// ============ K4: outpre = y2 @ spikes, split-K over l (2 halves) ==========
__global__ __launch_bounds__(256) void attn_out_mfma(
    const unsigned short* __restrict__ y2hi, const unsigned short* __restrict__ y2mi,
    const unsigned short* __restrict__ y2lo,
    const unsigned* __restrict__ bits,
    float* __restrict__ outpre, float* __restrict__ outpre2) {
    __shared__ unsigned short A_hi[48][72], A_mi[48][72], A_lo[48][72];
    const int tid = threadIdx.x;
    const int flat = blockIdx.x;
    const int xcd = flat & 7;
    const int ii = flat >> 3;            // 0..127
    const int tbh = xcd*8 + (ii >> 4);
    const int mtile = (ii >> 1) & 7;
    const int ls = ii & 1;
    const int t = tbh >> 4, b = (tbh >> 3) & 1, h = tbh & 7;
    const int tb = t*B_ + b;
    const int w = tid >> 6, lane = tid & 63;
    const int q = lane >> 4, n15 = lane & 15;
    const int mb = mtile*128 + w*32;
    const int lt0 = ls * 512;

    floatx4 acc[3][2];
#pragma unroll
    for (int i = 0; i < 3; i++)
#pragma unroll
        for (int in = 0; in < 2; in++) acc[i][in] = (floatx4){0.f,0.f,0.f,0.f};

    const uint2* bvec = (const uint2*)bits;
    const size_t bbase = ((size_t)(tb*H_ + h)*16)*1024 + mb + n15;
    const size_t y2b = ((size_t)tb*C_ + h*48)*L_;

    const int r0 = tid >> 3, c0i = tid & 7;
    const int r1 = (tid + 256) >> 3, c1i = tid & 7;
    uint4 rh0, rm0, rl0, rh1, rm1, rl1;
    {
        size_t ro = y2b + (size_t)r0*L_ + lt0 + c0i*8;
        rh0 = *(const uint4*)(y2hi + ro); rm0 = *(const uint4*)(y2mi + ro); rl0 = *(const uint4*)(y2lo + ro);
        if (tid < 128) {
            size_t ro1 = y2b + (size_t)r1*L_ + lt0 + c1i*8;
            rh1 = *(const uint4*)(y2hi + ro1); rm1 = *(const uint4*)(y2mi + ro1); rl1 = *(const uint4*)(y2lo + ro1);
        }
    }

    for (int it = 0; it < 8; it++) {
        const int lt = lt0 + it*64;
        *(uint4*)&A_hi[r0][c0i*8] = rh0; *(uint4*)&A_mi[r0][c0i*8] = rm0; *(uint4*)&A_lo[r0][c0i*8] = rl0;
        if (tid < 128) {
            *(uint4*)&A_hi[r1][c1i*8] = rh1; *(uint4*)&A_mi[r1][c1i*8] = rm1; *(uint4*)&A_lo[r1][c1i*8] = rl1;
        }
        uint2 bw0 = bvec[bbase + (size_t)(lt >> 6)*1024];
        uint2 bw1 = bvec[bbase + (size_t)(lt >> 6)*1024 + 16];
        __syncthreads();
        if (it < 7) {
            size_t ro = y2b + (size_t)r0*L_ + (lt + 64) + c0i*8;
            rh0 = *(const uint4*)(y2hi + ro); rm0 = *(const uint4*)(y2mi + ro); rl0 = *(const uint4*)(y2lo + ro);
            if (tid < 128) {
                size_t ro1 = y2b + (size_t)r1*L_ + (lt + 64) + c1i*8;
                rh1 = *(const uint4*)(y2hi + ro1); rm1 = *(const uint4*)(y2mi + ro1); rl1 = *(const uint4*)(y2lo + ro1);
            }
        }
#pragma unroll
        for (int kc = 0; kc < 2; kc++) {
            unsigned word0 = kc ? bw0.y : bw0.x;
            unsigned word1 = kc ? bw1.y : bw1.x;
            unsigned byt0 = (word0 >> (q*8)) & 0xFFu;
            unsigned byt1 = (word1 >> (q*8)) & 0xFFu;
            union { unsigned u[4]; short8 v; } bu0, bu1;
#pragma unroll
            for (int p = 0; p < 4; p++) {
                bu0.u[p] = (((byt0 >> (2*p)) & 1u) ? 0x3F80u : 0u)
                         | (((byt0 >> (2*p+1)) & 1u) ? 0x3F800000u : 0u);
                bu1.u[p] = (((byt1 >> (2*p)) & 1u) ? 0x3F80u : 0u)
                         | (((byt1 >> (2*p+1)) & 1u) ? 0x3F800000u : 0u);
            }
            short8 bf0 = bu0.v, bf1 = bu1.v;
#pragma unroll
            for (int i = 0; i < 3; i++) {
                int ra = i*16 + n15;
                short8 ah = *(short8*)&A_hi[ra][kc*32 + q*8];
                short8 am = *(short8*)&A_mi[ra][kc*32 + q*8];
                short8 al = *(short8*)&A_lo[ra][kc*32 + q*8];
                acc[i][0] = __builtin_amdgcn_mfma_f32_16x16x32_bf16(ah, bf0, acc[i][0], 0,0,0);
                acc[i][0] = __builtin_amdgcn_mfma_f32_16x16x32_bf16(am, bf0, acc[i][0], 0,0,0);
                acc[i][0] = __builtin_amdgcn_mfma_f32_16x16x32_bf16(al, bf0, acc[i][0], 0,0,0);
                acc[i][1] = __builtin_amdgcn_mfma_f32_16x16x32_bf16(ah, bf1, acc[i][1], 0,0,0);
                acc[i][1] = __builtin_amdgcn_mfma_f32_16x16x32_bf16(am, bf1, acc[i][1], 0,0,0);
                acc[i][1] = __builtin_amdgcn_mfma_f32_16x16x32_bf16(al, bf1, acc[i][1], 0,0,0);
            }
        }
        __syncthreads();
    }
    float* outP = ls ? outpre2 : outpre;
#pragma unroll
    for (int i = 0; i < 3; i++)
#pragma unroll
        for (int r = 0; r < 4; r++) {
            int d = i*16 + q*4 + r;
#pragma unroll
            for (int in = 0; in < 2; in++)
                outP[((size_t)tb*C_ + h*48 + d)*L_ + mb + in*16 + n15] = acc[i][in][r];
        }
}

// ============ K6: out = BN2(proj @ outs) + x (MFMA, 96x64 tile) ============
__global__ __launch_bounds__(256) void gemm2_mfma(
    const unsigned short* __restrict__ whi, const unsigned short* __restrict__ wmi,
    const unsigned short* __restrict__ wlo, const unsigned short* __restrict__ xT,
    const float* __restrict__ g, const float* __restrict__ be,
    const float* __restrict__ mn, const float* __restrict__ vr,
    const float* __restrict__ res, float* __restrict__ out) {
    __shared__ unsigned short A_hi[96][40], A_mi[96][40], A_lo[96][40];
    __shared__ unsigned short B_s[64][40];
    const int tid = threadIdx.x;
    const int tb = blockIdx.y;
    const int mt = blockIdx.x >> 4, lt = blockIdx.x & 15;
    const int l0 = lt * 64;
    const int w = tid >> 6, lane = tid & 63;
    const int q = lane >> 4, n15 = lane & 15;
    const int mw = (w & 1) * 48, lw = (w >> 1) * 32;

    floatx4 acc[3][2];
#pragma unroll
    for (int i = 0; i < 3; i++)
#pragma unroll
        for (int j = 0; j < 2; j++) acc[i][j] = (floatx4){0.f,0.f,0.f,0.f};

    for (int ck = 0; ck < C_; ck += 32) {
#pragma unroll
        for (int p = 0; p < 3; p++) {
            const unsigned short* wp = p == 0 ? whi : p == 1 ? wmi : wlo;
            unsigned short (*ap)[40] = p == 0 ? A_hi : p == 1 ? A_mi : A_lo;
            for (int s = tid; s < 384; s += 256) {
                int r = s >> 2, c = s & 3;
                *(uint4*)&ap[r][c*8] = *(const uint4*)(wp + (size_t)(mt*96 + r)*C_ + ck + c*8);
            }
        }
        {
            int r = tid >> 2, c4 = tid & 3;
            *(uint4*)&B_s[r][c4*8] = *(const uint4*)(xT + ((size_t)tb*L_ + l0 + r)*C_ + ck + c4*8);
        }
        __syncthreads();
        short8 bb[2];
#pragma unroll
        for (int in = 0; in < 2; in++)
            bb[in] = *(short8*)&B_s[lw + in*16 + n15][q*8];
#pragma unroll
        for (int im = 0; im < 3; im++) {
            short8 ah = *(short8*)&A_hi[mw + im*16 + n15][q*8];
            short8 am = *(short8*)&A_mi[mw + im*16 + n15][q*8];
            short8 al = *(short8*)&A_lo[mw + im*16 + n15][q*8];
#pragma unroll
            for (int in = 0; in < 2; in++) {
                acc[im][in] = __builtin_amdgcn_mfma_f32_16x16x32_bf16(ah, bb[in], acc[im][in], 0,0,0);
                acc[im][in] = __builtin_amdgcn_mfma_f32_16x16x32_bf16(am, bb[in], acc[im][in], 0,0,0);
                acc[im][in] = __builtin_amdgcn_mfma_f32_16x16x32_bf16(al, bb[in], acc[im][in], 0,0,0);
            }
        }
        __syncthreads();
    }
#pragma unroll
    for (int im = 0; im < 3; im++)
#pragma unroll
        for (int r = 0; r < 4; r++) {
            int o = mt*96 + mw + im*16 + q*4 + r;
            float inv = g[o] / sqrtf(vr[o] + 1e-5f);
            float sh = be[o] - mn[o]*inv;
#pragma unroll
            for (int in = 0; in < 2; in++) {
                int l = l0 + lw + in*16 + n15;
                size_t idx = ((size_t)tb*C_ + o)*L_ + l;
                out[idx] = acc[im][in][r]*inv + sh + res[idx];
            }
        }
}

extern "C" void kernel_launch(void* const* d_in, const int* in_sizes, int n_in,
                              void* d_out, int out_size, void* d_ws, size_t ws_size,
                              hipStream_t stream) {
    const float* x   = (const float*)d_in[0];
    const float* W_w = (const float*)d_in[1];
    const float* g1  = (const float*)d_in[2];
    const float* b1  = (const float*)d_in[3];
    const float* m1  = (const float*)d_in[4];
    const float* v1  = (const float*)d_in[5];
    const float* pw  = (const float*)d_in[6];
    const float* g2  = (const float*)d_in[7];
    const float* b2  = (const float*)d_in[8];
    const float* m2  = (const float*)d_in[9];
    const float* v2  = (const float*)d_in[10];

    float* ws = (float*)d_ws;
    unsigned short* xsT  = (unsigned short*)ws;
    unsigned short* y1hi = (unsigned short*)(ws + 1572864);
    unsigned short* y1mi = (unsigned short*)(ws + 3145728);
    unsigned short* y1lo = (unsigned short*)(ws + 4718592);
    unsigned short* y2hi = (unsigned short*)(ws + 6291456);
    unsigned short* y2mi = (unsigned short*)(ws + 7864320);
    unsigned short* y2lo = (unsigned short*)(ws + 9437184);
    unsigned*       bits = (unsigned*)(ws + 11010048);
    unsigned short* wspl[3]  = {(unsigned short*)(ws + 13107200),
                                (unsigned short*)(ws + 13254656),
                                (unsigned short*)(ws + 13402112)};
    unsigned short* pwspl[3] = {(unsigned short*)(ws + 13549568),
                                (unsigned short*)(ws + 13623296),
                                (unsigned short*)(ws + 13697024)};
    unsigned short* xsF  = (unsigned short*)(ws + 13770752);
    float*          outpre  = (float*)(ws + 1572864);
    float*          outpre2 = (float*)(ws + 14557184);
    unsigned short* outsT   = (unsigned short*)(ws + 4718592);
    float* out = (float*)d_out;

    // 1) xs scan (both layouts, prefetched, 384 blocks) + weight split
    scan_and_split<<<dim3(816), 256, 0, stream>>>(x, xsT, xsF,
                                                  W_w, C2_*C_/4, wspl[0], wspl[1], wspl[2],
                                                  pw,  C_*C_/4, pwspl[0], pwspl[1], pwspl[2]);
    // 2) y = BN1(W @ xs): register-prefetched K-loop, stride-44 LDS
    gemm1_mfma<<<dim3(1024), 256, 0, stream>>>(wspl[0], wspl[1], wspl[2], xsT,
                                               g1, b1, m1, v1,
                                               y1hi, y1mi, y1lo, y2hi, y2mi, y2lo);
    // 3) attn spikes: LDS-free, coalesced; bits transposed layout
    attn_spike_mfma<<<dim3(2048), 256, 0, stream>>>(y1hi, y1mi, y1lo, xsF, bits);
    // 4) outpre(+outpre2) = y2 @ spikes: split-K over l, prefetched staging
    attn_out_mfma<<<dim3(1024), 256, 0, stream>>>(y2hi, y2mi, y2lo, bits, outpre, outpre2);
    // 5) outs spikes = scan(outpre + outpre2) -> bf16 transposed
    scan_transpose2<<<dim3(384), 256, 0, stream>>>(outpre, outpre2, outsT);
    // 6) out = BN2(proj @ outs) + x
    gemm2_mfma<<<dim3(64, 8), 256, 0, stream>>>(pwspl[0], pwspl[1], pwspl[2], outsT,
                                                g2, b2, m2, v2, x, out);
}

// Round 10
// 222.460 us; speedup vs baseline: 1.1307x; 1.1307x over previous
//
#include <hip/hip_runtime.h>

#define T_  4
#define B_  2
#define C_  384
#define L_  1024
#define H_  8
#define C2_ 768

typedef __attribute__((ext_vector_type(8))) short short8;
typedef __attribute__((ext_vector_type(4))) float floatx4;
typedef __attribute__((ext_vector_type(16))) float floatx16;

__device__ __forceinline__ unsigned bf16_rne(float v) {
    unsigned u = __float_as_uint(v);
    u += 0x7FFFu + ((u >> 16) & 1u);
    return u >> 16;
}
__device__ __forceinline__ float bf16_to_f(unsigned h) { return __uint_as_float(h << 16); }
__device__ __forceinline__ void split3(float v, unsigned& hi, unsigned& mi, unsigned& lo) {
    hi = bf16_rne(v);
    float r1 = v - bf16_to_f(hi);
    mi = bf16_rne(r1);
    float r2 = r1 - bf16_to_f(mi);
    lo = bf16_rne(r2);
}

// ==== K1+K0: blocks 0-383 run the xs scan (64l x 32c tiles, prefetched);
// blocks 384-815 split both fp32 weight tensors into 3 bf16 planes.
__global__ __launch_bounds__(256) void scan_and_split(
    const float* __restrict__ src, unsigned short* __restrict__ dstT,
    unsigned short* __restrict__ xsF,
    const float* __restrict__ Wa, int n4a,
    unsigned short* __restrict__ hia, unsigned short* __restrict__ mia,
    unsigned short* __restrict__ loa,
    const float* __restrict__ Wb, int n4b,
    unsigned short* __restrict__ hib, unsigned short* __restrict__ mib,
    unsigned short* __restrict__ lob) {
    __shared__ unsigned short tile[32][72];
    const int tid = threadIdx.x;
    if (blockIdx.x >= 384) {
        int i = (blockIdx.x - 384) * 256 + tid;
        const float* W; unsigned short *hi, *mi, *lo;
        if (i < n4a) { W = Wa; hi = hia; mi = mia; lo = loa; }
        else {
            i -= n4a;
            if (i >= n4b) return;
            W = Wb; hi = hib; mi = mib; lo = lob;
        }
        float4 v = ((const float4*)W)[i];
        float vv[4] = {v.x, v.y, v.z, v.w};
        union { unsigned short us[4]; uint2 u2; } h, m, l;
#pragma unroll
        for (int e = 0; e < 4; e++) {
            unsigned hh, mm, ll; split3(vv[e], hh, mm, ll);
            h.us[e] = (unsigned short)hh; m.us[e] = (unsigned short)mm; l.us[e] = (unsigned short)ll;
        }
        ((uint2*)hi)[i] = h.u2; ((uint2*)mi)[i] = m.u2; ((uint2*)lo)[i] = l.u2;
        return;
    }
    // ---- scan branch: job 0..383 = l0(16) x c0(12) x b(2) ----
    const int job = blockIdx.x;
    const int l0 = (job & 15) * 64;
    const int c0 = ((job >> 4) % 12) * 32;
    const int b  = job / 192;
    const int row = tid >> 3, seg = tid & 7;     // 32 c-rows x 8 l-segs
    float mem[8], sp[8];
#pragma unroll
    for (int e = 0; e < 8; e++) { mem[e] = 0.f; sp[e] = 0.f; }
    const size_t base0 = ((size_t)(b*C_ + c0 + row))*L_ + l0 + seg*8;
    float4 nx0 = *(const float4*)(src + base0);
    float4 nx1 = *(const float4*)(src + base0 + 4);
    for (int t = 0; t < T_; t++) {
        float4 v0 = nx0, v1 = nx1;
        if (t < 3) {
            const size_t nb = ((size_t)(((t+1)*B_ + b)*C_ + c0 + row))*L_ + l0 + seg*8;
            nx0 = *(const float4*)(src + nb);
            nx1 = *(const float4*)(src + nb + 4);
        }
        float vv[8] = {v0.x,v0.y,v0.z,v0.w,v1.x,v1.y,v1.z,v1.w};
        unsigned bs[8];
#pragma unroll
        for (int e = 0; e < 8; e++) {
            mem[e] = mem[e]*0.25f*(1.f - sp[e]) + vv[e];
            bool sb = mem[e] > 0.5f;
            sp[e] = sb ? 1.f : 0.f;
            bs[e] = sb ? 0x3F80u : 0u;
        }
#pragma unroll
        for (int p2 = 0; p2 < 4; p2++)
            *(unsigned*)&tile[row][seg*8 + p2*2] = bs[p2*2] | (bs[p2*2+1] << 16);
        __syncthreads();
        {
            const int lr = tid >> 2, cs = tid & 3;   // 64 l-rows x 4 c-chunks
            unsigned wv[4];
#pragma unroll
            for (int p = 0; p < 4; p++) {
                unsigned e0 = tile[cs*8 + p*2][lr];
                unsigned e1 = tile[cs*8 + p*2 + 1][lr];
                wv[p] = e0 | (e1 << 16);
            }
            uint4 o; o.x = wv[0]; o.y = wv[1]; o.z = wv[2]; o.w = wv[3];
            const int cc = c0 + cs*8;
            *(uint4*)(dstT + ((size_t)(t*B_ + b)*L_ + l0 + lr)*C_ + cc) = o;
            const int hh = cc / 48, kc = (cc % 48) >> 3;
            *(uint4*)(xsF + ((((size_t)(t*B_ + b)*H_ + hh)*6 + kc)*L_ + l0 + lr)*8) = o;
        }
        __syncthreads();
    }
}

// ============ K5: scan over T of (outpre + outpre2) + bf16 transpose =======
__global__ __launch_bounds__(256) void scan_transpose2(
    const float* __restrict__ srcA, const float* __restrict__ srcB,
    unsigned short* __restrict__ dstT) {
    __shared__ unsigned short tile[32][72];
    const int tid = threadIdx.x;
    const int job = blockIdx.x;
    const int l0 = (job & 15) * 64;
    const int c0 = ((job >> 4) % 12) * 32;
    const int b  = job / 192;
    const int row = tid >> 3, seg = tid & 7;
    float mem[8], sp[8];
#pragma unroll
    for (int e = 0; e < 8; e++) { mem[e] = 0.f; sp[e] = 0.f; }
    const size_t base0 = ((size_t)(b*C_ + c0 + row))*L_ + l0 + seg*8;
    float4 na0 = *(const float4*)(srcA + base0);
    float4 na1 = *(const float4*)(srcA + base0 + 4);
    float4 nb0 = *(const float4*)(srcB + base0);
    float4 nb1 = *(const float4*)(srcB + base0 + 4);
    for (int t = 0; t < T_; t++) {
        float4 a0 = na0, a1 = na1, b0 = nb0, b1 = nb1;
        if (t < 3) {
            const size_t nb = ((size_t)(((t+1)*B_ + b)*C_ + c0 + row))*L_ + l0 + seg*8;
            na0 = *(const float4*)(srcA + nb);
            na1 = *(const float4*)(srcA + nb + 4);
            nb0 = *(const float4*)(srcB + nb);
            nb1 = *(const float4*)(srcB + nb + 4);
        }
        float vv[8] = {a0.x+b0.x, a0.y+b0.y, a0.z+b0.z, a0.w+b0.w,
                       a1.x+b1.x, a1.y+b1.y, a1.z+b1.z, a1.w+b1.w};
        unsigned bs[8];
#pragma unroll
        for (int e = 0; e < 8; e++) {
            mem[e] = mem[e]*0.25f*(1.f - sp[e]) + vv[e];
            bool sb = mem[e] > 0.5f;
            sp[e] = sb ? 1.f : 0.f;
            bs[e] = sb ? 0x3F80u : 0u;
        }
#pragma unroll
        for (int p2 = 0; p2 < 4; p2++)
            *(unsigned*)&tile[row][seg*8 + p2*2] = bs[p2*2] | (bs[p2*2+1] << 16);
        __syncthreads();
        {
            const int lr = tid >> 2, cs = tid & 3;
            unsigned wv[4];
#pragma unroll
            for (int p = 0; p < 4; p++) {
                unsigned e0 = tile[cs*8 + p*2][lr];
                unsigned e1 = tile[cs*8 + p*2 + 1][lr];
                wv[p] = e0 | (e1 << 16);
            }
            uint4 o; o.x = wv[0]; o.y = wv[1]; o.z = wv[2]; o.w = wv[3];
            *(uint4*)(dstT + ((size_t)(t*B_ + b)*L_ + l0 + lr)*C_ + c0 + cs*8) = o;
        }
        __syncthreads();
    }
}

// ============ K2: y = BN1(W @ xs) via MFMA, 96m x 64l tile =================
// Round-8 staging structure (no register prefetch — conditional prefetch regs
// spilled to scratch in round 9: WRITE_SIZE 37->225MB). Only change kept:
// LDS row stride 40 -> 44 shorts (22 dwords, gcd(22,32)=2 -> free 2-way
// instead of 4-way read bank conflicts; measured 4.5M -> 0.6M conflicts).
__global__ __launch_bounds__(256) void gemm1_mfma(
    const unsigned short* __restrict__ whi, const unsigned short* __restrict__ wmi,
    const unsigned short* __restrict__ wlo, const unsigned short* __restrict__ xsT,
    const float* __restrict__ g, const float* __restrict__ be,
    const float* __restrict__ mn, const float* __restrict__ vr,
    unsigned short* __restrict__ y1hi, unsigned short* __restrict__ y1mi,
    unsigned short* __restrict__ y1lo,
    unsigned short* __restrict__ y2hi, unsigned short* __restrict__ y2mi,
    unsigned short* __restrict__ y2lo) {
    __shared__ unsigned short smem[15488];   // A: 3 x 96 x 44 @ {0,4224,8448}; B: 64 x 44 @ 12672
    const int tid = threadIdx.x;
    const int flat = blockIdx.x;
    const int tb = flat & 7;
    const int ii = flat >> 3;
    const int mt = ii >> 4, lt = ii & 15;
    const int l0 = lt * 64;
    const int w = tid >> 6, lane = tid & 63;
    const int q = lane >> 4, n15 = lane & 15;
    const int mw = (w & 1) * 48, lw = (w >> 1) * 32;

    floatx4 acc[3][2];
#pragma unroll
    for (int i = 0; i < 3; i++)
#pragma unroll
        for (int j = 0; j < 2; j++) acc[i][j] = (floatx4){0.f,0.f,0.f,0.f};

    for (int ck = 0; ck < C_; ck += 32) {
#pragma unroll
        for (int p = 0; p < 3; p++) {
            const unsigned short* wp = p == 0 ? whi : p == 1 ? wmi : wlo;
            unsigned short* ap = smem + p*4224;
            for (int s = tid; s < 384; s += 256) {
                int r = s >> 2, c = s & 3;
                *(uint4*)&ap[r*44 + c*8] = *(const uint4*)(wp + (size_t)(mt*96 + r)*C_ + ck + c*8);
            }
        }
        {
            int r = tid >> 2, c = tid & 3;
            *(uint4*)&smem[12672 + r*44 + c*8] =
                *(const uint4*)(xsT + ((size_t)tb*L_ + l0 + r)*C_ + ck + c*8);
        }
        __syncthreads();
        short8 bb[2];
#pragma unroll
        for (int in = 0; in < 2; in++)
            bb[in] = *(short8*)&smem[12672 + (lw + in*16 + n15)*44 + q*8];
#pragma unroll
        for (int im = 0; im < 3; im++) {
            short8 ah = *(short8*)&smem[       (mw + im*16 + n15)*44 + q*8];
            short8 am = *(short8*)&smem[4224 + (mw + im*16 + n15)*44 + q*8];
            short8 al = *(short8*)&smem[8448 + (mw + im*16 + n15)*44 + q*8];
#pragma unroll
            for (int in = 0; in < 2; in++) {
                acc[im][in] = __builtin_amdgcn_mfma_f32_16x16x32_bf16(ah, bb[in], acc[im][in], 0,0,0);
                acc[im][in] = __builtin_amdgcn_mfma_f32_16x16x32_bf16(am, bb[in], acc[im][in], 0,0,0);
                acc[im][in] = __builtin_amdgcn_mfma_f32_16x16x32_bf16(al, bb[in], acc[im][in], 0,0,0);
            }
        }
        __syncthreads();
    }

#pragma unroll
    for (int im = 0; im < 3; im++)
#pragma unroll
        for (int r = 0; r < 4; r++) {
            int o = mt*96 + mw + im*16 + q*4 + r;
            float inv = g[o] / sqrtf(vr[o] + 1e-5f);
            float sh = be[o] - mn[o]*inv;
#pragma unroll
            for (int in = 0; in < 2; in++)
                acc[im][in][r] = acc[im][in][r]*inv + sh;
        }
    const bool isY1 = ((w & 1) == 0);
#pragma unroll
    for (int p = 0; p < 3; p++) {
        if (isY1) {
#pragma unroll
            for (int im = 0; im < 3; im++)
#pragma unroll
                for (int in = 0; in < 2; in++) {
                    union { unsigned short us[4]; uint2 u2; } pk;
#pragma unroll
                    for (int r = 0; r < 4; r++) {
                        unsigned hh = bf16_rne(acc[im][in][r]);
                        pk.us[r] = (unsigned short)hh;
                        acc[im][in][r] -= bf16_to_f(hh);
                    }
                    *(uint2*)&smem[(lw + in*16 + n15)*56 + im*16 + q*4] = pk.u2;
                }
        } else {
#pragma unroll
            for (int im = 0; im < 3; im++)
#pragma unroll
                for (int in = 0; in < 2; in++)
#pragma unroll
                    for (int r = 0; r < 4; r++) {
                        unsigned hh = bf16_rne(acc[im][in][r]);
                        smem[3584 + (im*16 + q*4 + r)*72 + lw + in*16 + n15] = (unsigned short)hh;
                        acc[im][in][r] -= bf16_to_f(hh);
                    }
        }
        __syncthreads();
        unsigned short* y1p = p == 0 ? y1hi : p == 1 ? y1mi : y1lo;
        unsigned short* y2p = p == 0 ? y2hi : p == 1 ? y2mi : y2lo;
        for (int s = tid; s < 384; s += 256) {
            int c8 = s >> 6, r1 = s & 63;
            *(uint4*)(y1p + ((((size_t)tb*H_ + mt)*6 + c8)*L_ + l0 + r1)*8) =
                *(uint4*)&smem[r1*56 + c8*8];
        }
        for (int s = tid; s < 384; s += 256) {
            int cr = s >> 3, lq = s & 7;
            *(uint4*)(y2p + ((size_t)tb*C_ + mt*48 + cr)*L_ + l0 + lq*8) =
                *(uint4*)&smem[3584 + cr*72 + lq*8];
        }
        __syncthreads();
    }
}

// ============ K3: attn = y1^T @ xr, LDS-free, coalesced fragment loads =====
__global__ __launch_bounds__(256, 4) void attn_spike_mfma(
    const unsigned short* __restrict__ y1hi, const unsigned short* __restrict__ y1mi,
    const unsigned short* __restrict__ y1lo, const unsigned short* __restrict__ xsF,
    unsigned* __restrict__ bits) {
    const int tid = threadIdx.x;
    const int flat = blockIdx.x;
    const int xcd = flat & 7;
    const int ii = flat >> 3;            // 0..255
    const int bh = xcd*2 + (ii >> 7);
    const int rr = ii & 127;
    const int b = bh >> 3, h = bh & 7;
    const int lbase = (rr >> 3) * 64;
    const int mbase = (rr & 7) * 128;
    const int w = tid >> 6, lane = tid & 63;
    const int l31 = lane & 31, half = lane >> 5;
    const int mrow = mbase + w*32 + l31;

    float mem[2][16];
#pragma unroll
    for (int il = 0; il < 2; il++)
#pragma unroll
        for (int r = 0; r < 16; r++) mem[il][r] = 0.f;

    for (int t = 0; t < T_; t++) {
        const int tb = t*B_ + b;
        const size_t fb = ((size_t)tb*H_ + h)*6*L_*8;
        const unsigned short* ya_hi = y1hi + fb;
        const unsigned short* ya_mi = y1mi + fb;
        const unsigned short* ya_lo = y1lo + fb;
        const unsigned short* xf    = xsF  + fb;

        short8 bb[3];
#pragma unroll
        for (int ks = 0; ks < 3; ks++)
            bb[ks] = *(const short8*)(xf + ((size_t)(ks*2 + half)*L_ + mrow)*8);

        floatx16 acc[2];
#pragma unroll
        for (int il = 0; il < 2; il++)
#pragma unroll
            for (int r = 0; r < 16; r++) acc[il][r] = 0.f;

#pragma unroll
        for (int ks = 0; ks < 3; ks++) {
#pragma unroll
            for (int il = 0; il < 2; il++) {
                const size_t aoff = ((size_t)(ks*2 + half)*L_ + lbase + il*32 + l31)*8;
                short8 ah = *(const short8*)(ya_hi + aoff);
                short8 am = *(const short8*)(ya_mi + aoff);
                short8 al = *(const short8*)(ya_lo + aoff);
                acc[il] = __builtin_amdgcn_mfma_f32_32x32x16_bf16(ah, bb[ks], acc[il], 0,0,0);
                acc[il] = __builtin_amdgcn_mfma_f32_32x32x16_bf16(am, bb[ks], acc[il], 0,0,0);
                acc[il] = __builtin_amdgcn_mfma_f32_32x32x16_bf16(al, bb[ks], acc[il], 0,0,0);
            }
        }

        unsigned wds[2];
#pragma unroll
        for (int il = 0; il < 2; il++) {
            unsigned word = 0;
#pragma unroll
            for (int r = 0; r < 16; r++) {
                float m = (mem[il][r] > 0.5f ? 0.f : mem[il][r]*0.25f) + acc[il][r];
                mem[il][r] = m;
                int lloc = (r & 3) + 8*(r >> 2) + 4*half;
                word |= (m > 0.5f) ? (1u << lloc) : 0u;
            }
            wds[il] = word;
        }
        unsigned f0 = wds[0] | __shfl_xor(wds[0], 32);
        unsigned f1 = wds[1] | __shfl_xor(wds[1], 32);
        if (half == 0) {
            uint2 o; o.x = f0; o.y = f1;
            ((uint2*)bits)[((size_t)(tb*H_ + h)*16 + (lbase >> 6))*1024 + mrow] = o;
        }
    }
}

// ============ K4: outpre = y2 @ spikes, split-K over l (2 halves) ==========
__global__ __launch_bounds__(256) void attn_out_mfma(
    const unsigned short* __restrict__ y2hi, const unsigned short* __restrict__ y2mi,
    const unsigned short* __restrict__ y2lo,
    const unsigned* __restrict__ bits,
    float* __restrict__ outpre, float* __restrict__ outpre2) {
    __shared__ unsigned short A_hi[48][72], A_mi[48][72], A_lo[48][72];
    const int tid = threadIdx.x;
    const int flat = blockIdx.x;
    const int xcd = flat & 7;
    const int ii = flat >> 3;            // 0..127
    const int tbh = xcd*8 + (ii >> 4);
    const int mtile = (ii >> 1) & 7;
    const int ls = ii & 1;
    const int t = tbh >> 4, b = (tbh >> 3) & 1, h = tbh & 7;
    const int tb = t*B_ + b;
    const int w = tid >> 6, lane = tid & 63;
    const int q = lane >> 4, n15 = lane & 15;
    const int mb = mtile*128 + w*32;
    const int lt0 = ls * 512;

    floatx4 acc[3][2];
#pragma unroll
    for (int i = 0; i < 3; i++)
#pragma unroll
        for (int in = 0; in < 2; in++) acc[i][in] = (floatx4){0.f,0.f,0.f,0.f};

    const uint2* bvec = (const uint2*)bits;
    const size_t bbase = ((size_t)(tb*H_ + h)*16)*1024 + mb + n15;
    const size_t y2b = ((size_t)tb*C_ + h*48)*L_;

    const int r0 = tid >> 3, c0i = tid & 7;
    const int r1 = (tid + 256) >> 3, c1i = tid & 7;
    uint4 rh0, rm0, rl0, rh1, rm1, rl1;
    {
        size_t ro = y2b + (size_t)r0*L_ + lt0 + c0i*8;
        rh0 = *(const uint4*)(y2hi + ro); rm0 = *(const uint4*)(y2mi + ro); rl0 = *(const uint4*)(y2lo + ro);
        if (tid < 128) {
            size_t ro1 = y2b + (size_t)r1*L_ + lt0 + c1i*8;
            rh1 = *(const uint4*)(y2hi + ro1); rm1 = *(const uint4*)(y2mi + ro1); rl1 = *(const uint4*)(y2lo + ro1);
        }
    }

    for (int it = 0; it < 8; it++) {
        const int lt = lt0 + it*64;
        *(uint4*)&A_hi[r0][c0i*8] = rh0; *(uint4*)&A_mi[r0][c0i*8] = rm0; *(uint4*)&A_lo[r0][c0i*8] = rl0;
        if (tid < 128) {
            *(uint4*)&A_hi[r1][c1i*8] = rh1; *(uint4*)&A_mi[r1][c1i*8] = rm1; *(uint4*)&A_lo[r1][c1i*8] = rl1;
        }
        uint2 bw0 = bvec[bbase + (size_t)(lt >> 6)*1024];
        uint2 bw1 = bvec[bbase + (size_t)(lt >> 6)*1024 + 16];
        __syncthreads();
        if (it < 7) {
            size_t ro = y2b + (size_t)r0*L_ + (lt + 64) + c0i*8;
            rh0 = *(const uint4*)(y2hi + ro); rm0 = *(const uint4*)(y2mi + ro); rl0 = *(const uint4*)(y2lo + ro);
            if (tid < 128) {
                size_t ro1 = y2b + (size_t)r1*L_ + (lt + 64) + c1i*8;
                rh1 = *(const uint4*)(y2hi + ro1); rm1 = *(const uint4*)(y2mi + ro1); rl1 = *(const uint4*)(y2lo + ro1);
            }
        }
#pragma unroll
        for (int kc = 0; kc < 2; kc++) {
            unsigned word0 = kc ? bw0.y : bw0.x;
            unsigned word1 = kc ? bw1.y : bw1.x;
            unsigned byt0 = (word0 >> (q*8)) & 0xFFu;
            unsigned byt1 = (word1 >> (q*8)) & 0xFFu;
            union { unsigned u[4]; short8 v; } bu0, bu1;
#pragma unroll
            for (int p = 0; p < 4; p++) {
                bu0.u[p] = (((byt0 >> (2*p)) & 1u) ? 0x3F80u : 0u)
                         | (((byt0 >> (2*p+1)) & 1u) ? 0x3F800000u : 0u);
                bu1.u[p] = (((byt1 >> (2*p)) & 1u) ? 0x3F80u : 0u)
                         | (((byt1 >> (2*p+1)) & 1u) ? 0x3F800000u : 0u);
            }
            short8 bf0 = bu0.v, bf1 = bu1.v;
#pragma unroll
            for (int i = 0; i < 3; i++) {
                int ra = i*16 + n15;
                short8 ah = *(short8*)&A_hi[ra][kc*32 + q*8];
                short8 am = *(short8*)&A_mi[ra][kc*32 + q*8];
                short8 al = *(short8*)&A_lo[ra][kc*32 + q*8];
                acc[i][0] = __builtin_amdgcn_mfma_f32_16x16x32_bf16(ah, bf0, acc[i][0], 0,0,0);
                acc[i][0] = __builtin_amdgcn_mfma_f32_16x16x32_bf16(am, bf0, acc[i][0], 0,0,0);
                acc[i][0] = __builtin_amdgcn_mfma_f32_16x16x32_bf16(al, bf0, acc[i][0], 0,0,0);
                acc[i][1] = __builtin_amdgcn_mfma_f32_16x16x32_bf16(ah, bf1, acc[i][1], 0,0,0);
                acc[i][1] = __builtin_amdgcn_mfma_f32_16x16x32_bf16(am, bf1, acc[i][1], 0,0,0);
                acc[i][1] = __builtin_amdgcn_mfma_f32_16x16x32_bf16(al, bf1, acc[i][1], 0,0,0);
            }
        }
        __syncthreads();
    }
    float* outP = ls ? outpre2 : outpre;
#pragma unroll
    for (int i = 0; i < 3; i++)
#pragma unroll
        for (int r = 0; r < 4; r++) {
            int d = i*16 + q*4 + r;
#pragma unroll
            for (int in = 0; in < 2; in++)
                outP[((size_t)tb*C_ + h*48 + d)*L_ + mb + in*16 + n15] = acc[i][in][r];
        }
}

// ============ K6: out = BN2(proj @ outs) + x (MFMA, 96x64 tile) ============
__global__ __launch_bounds__(256) void gemm2_mfma(
    const unsigned short* __restrict__ whi, const unsigned short* __restrict__ wmi,
    const unsigned short* __restrict__ wlo, const unsigned short* __restrict__ xT,
    const float* __restrict__ g, const float* __restrict__ be,
    const float* __restrict__ mn, const float* __restrict__ vr,
    const float* __restrict__ res, float* __restrict__ out) {
    __shared__ unsigned short A_hi[96][40], A_mi[96][40], A_lo[96][40];
    __shared__ unsigned short B_s[64][40];
    const int tid = threadIdx.x;
    const int tb = blockIdx.y;
    const int mt = blockIdx.x >> 4, lt = blockIdx.x & 15;
    const int l0 = lt * 64;
    const int w = tid >> 6, lane = tid & 63;
    const int q = lane >> 4, n15 = lane & 15;
    const int mw = (w & 1) * 48, lw = (w >> 1) * 32;

    floatx4 acc[3][2];
#pragma unroll
    for (int i = 0; i < 3; i++)
#pragma unroll
        for (int j = 0; j < 2; j++) acc[i][j] = (floatx4){0.f,0.f,0.f,0.f};

    for (int ck = 0; ck < C_; ck += 32) {
#pragma unroll
        for (int p = 0; p < 3; p++) {
            const unsigned short* wp = p == 0 ? whi : p == 1 ? wmi : wlo;
            unsigned short (*ap)[40] = p == 0 ? A_hi : p == 1 ? A_mi : A_lo;
            for (int s = tid; s < 384; s += 256) {
                int r = s >> 2, c = s & 3;
                *(uint4*)&ap[r][c*8] = *(const uint4*)(wp + (size_t)(mt*96 + r)*C_ + ck + c*8);
            }
        }
        {
            int r = tid >> 2, c4 = tid & 3;
            *(uint4*)&B_s[r][c4*8] = *(const uint4*)(xT + ((size_t)tb*L_ + l0 + r)*C_ + ck + c4*8);
        }
        __syncthreads();
        short8 bb[2];
#pragma unroll
        for (int in = 0; in < 2; in++)
            bb[in] = *(short8*)&B_s[lw + in*16 + n15][q*8];
#pragma unroll
        for (int im = 0; im < 3; im++) {
            short8 ah = *(short8*)&A_hi[mw + im*16 + n15][q*8];
            short8 am = *(short8*)&A_mi[mw + im*16 + n15][q*8];
            short8 al = *(short8*)&A_lo[mw + im*16 + n15][q*8];
#pragma unroll
            for (int in = 0; in < 2; in++) {
                acc[im][in] = __builtin_amdgcn_mfma_f32_16x16x32_bf16(ah, bb[in], acc[im][in], 0,0,0);
                acc[im][in] = __builtin_amdgcn_mfma_f32_16x16x32_bf16(am, bb[in], acc[im][in], 0,0,0);
                acc[im][in] = __builtin_amdgcn_mfma_f32_16x16x32_bf16(al, bb[in], acc[im][in], 0,0,0);
            }
        }
        __syncthreads();
    }
#pragma unroll
    for (int im = 0; im < 3; im++)
#pragma unroll
        for (int r = 0; r < 4; r++) {
            int o = mt*96 + mw + im*16 + q*4 + r;
            float inv = g[o] / sqrtf(vr[o] + 1e-5f);
            float sh = be[o] - mn[o]*inv;
#pragma unroll
            for (int in = 0; in < 2; in++) {
                int l = l0 + lw + in*16 + n15;
                size_t idx = ((size_t)tb*C_ + o)*L_ + l;
                out[idx] = acc[im][in][r]*inv + sh + res[idx];
            }
        }
}

extern "C" void kernel_launch(void* const* d_in, const int* in_sizes, int n_in,
                              void* d_out, int out_size, void* d_ws, size_t ws_size,
                              hipStream_t stream) {
    const float* x   = (const float*)d_in[0];
    const float* W_w = (const float*)d_in[1];
    const float* g1  = (const float*)d_in[2];
    const float* b1  = (const float*)d_in[3];
    const float* m1  = (const float*)d_in[4];
    const float* v1  = (const float*)d_in[5];
    const float* pw  = (const float*)d_in[6];
    const float* g2  = (const float*)d_in[7];
    const float* b2  = (const float*)d_in[8];
    const float* m2  = (const float*)d_in[9];
    const float* v2  = (const float*)d_in[10];

    float* ws = (float*)d_ws;
    unsigned short* xsT  = (unsigned short*)ws;
    unsigned short* y1hi = (unsigned short*)(ws + 1572864);
    unsigned short* y1mi = (unsigned short*)(ws + 3145728);
    unsigned short* y1lo = (unsigned short*)(ws + 4718592);
    unsigned short* y2hi = (unsigned short*)(ws + 6291456);
    unsigned short* y2mi = (unsigned short*)(ws + 7864320);
    unsigned short* y2lo = (unsigned short*)(ws + 9437184);
    unsigned*       bits = (unsigned*)(ws + 11010048);
    unsigned short* wspl[3]  = {(unsigned short*)(ws + 13107200),
                                (unsigned short*)(ws + 13254656),
                                (unsigned short*)(ws + 13402112)};
    unsigned short* pwspl[3] = {(unsigned short*)(ws + 13549568),
                                (unsigned short*)(ws + 13623296),
                                (unsigned short*)(ws + 13697024)};
    unsigned short* xsF  = (unsigned short*)(ws + 13770752);
    float*          outpre  = (float*)(ws + 1572864);
    float*          outpre2 = (float*)(ws + 14557184);
    unsigned short* outsT   = (unsigned short*)(ws + 4718592);
    float* out = (float*)d_out;

    // 1) xs scan (both layouts, prefetched, 384 blocks) + weight split
    scan_and_split<<<dim3(816), 256, 0, stream>>>(x, xsT, xsF,
                                                  W_w, C2_*C_/4, wspl[0], wspl[1], wspl[2],
                                                  pw,  C_*C_/4, pwspl[0], pwspl[1], pwspl[2]);
    // 2) y = BN1(W @ xs): round-8 staging, stride-44 LDS (conflict fix only)
    gemm1_mfma<<<dim3(1024), 256, 0, stream>>>(wspl[0], wspl[1], wspl[2], xsT,
                                               g1, b1, m1, v1,
                                               y1hi, y1mi, y1lo, y2hi, y2mi, y2lo);
    // 3) attn spikes: LDS-free, coalesced; bits transposed layout
    attn_spike_mfma<<<dim3(2048), 256, 0, stream>>>(y1hi, y1mi, y1lo, xsF, bits);
    // 4) outpre(+outpre2) = y2 @ spikes: split-K over l, prefetched staging
    attn_out_mfma<<<dim3(1024), 256, 0, stream>>>(y2hi, y2mi, y2lo, bits, outpre, outpre2);
    // 5) outs spikes = scan(outpre + outpre2) -> bf16 transposed
    scan_transpose2<<<dim3(384), 256, 0, stream>>>(outpre, outpre2, outsT);
    // 6) out = BN2(proj @ outs) + x
    gemm2_mfma<<<dim3(64, 8), 256, 0, stream>>>(pwspl[0], pwspl[1], pwspl[2], outsT,
                                                g2, b2, m2, v2, x, out);
}

// Round 11
// 204.821 us; speedup vs baseline: 1.2281x; 1.0861x over previous
//
#include <hip/hip_runtime.h>

#define T_  4
#define B_  2
#define C_  384
#define L_  1024
#define H_  8
#define C2_ 768

typedef __attribute__((ext_vector_type(8))) short short8;
typedef __attribute__((ext_vector_type(4))) float floatx4;
typedef __attribute__((ext_vector_type(16))) float floatx16;

__device__ __forceinline__ unsigned bf16_rne(float v) {
    unsigned u = __float_as_uint(v);
    u += 0x7FFFu + ((u >> 16) & 1u);
    return u >> 16;
}
__device__ __forceinline__ float bf16_to_f(unsigned h) { return __uint_as_float(h << 16); }
__device__ __forceinline__ void split3(float v, unsigned& hi, unsigned& mi, unsigned& lo) {
    hi = bf16_rne(v);
    float r1 = v - bf16_to_f(hi);
    mi = bf16_rne(r1);
    float r2 = r1 - bf16_to_f(mi);
    lo = bf16_rne(r2);
}

// ==== K1+K0: blocks 0-383 run the xs scan (64l x 32c tiles, prefetched);
// blocks 384-815 split both fp32 weight tensors into 3 bf16 planes.
__global__ __launch_bounds__(256) void scan_and_split(
    const float* __restrict__ src, unsigned short* __restrict__ dstT,
    unsigned short* __restrict__ xsF,
    const float* __restrict__ Wa, int n4a,
    unsigned short* __restrict__ hia, unsigned short* __restrict__ mia,
    unsigned short* __restrict__ loa,
    const float* __restrict__ Wb, int n4b,
    unsigned short* __restrict__ hib, unsigned short* __restrict__ mib,
    unsigned short* __restrict__ lob) {
    __shared__ unsigned short tile[32][72];
    const int tid = threadIdx.x;
    if (blockIdx.x >= 384) {
        int i = (blockIdx.x - 384) * 256 + tid;
        const float* W; unsigned short *hi, *mi, *lo;
        if (i < n4a) { W = Wa; hi = hia; mi = mia; lo = loa; }
        else {
            i -= n4a;
            if (i >= n4b) return;
            W = Wb; hi = hib; mi = mib; lo = lob;
        }
        float4 v = ((const float4*)W)[i];
        float vv[4] = {v.x, v.y, v.z, v.w};
        union { unsigned short us[4]; uint2 u2; } h, m, l;
#pragma unroll
        for (int e = 0; e < 4; e++) {
            unsigned hh, mm, ll; split3(vv[e], hh, mm, ll);
            h.us[e] = (unsigned short)hh; m.us[e] = (unsigned short)mm; l.us[e] = (unsigned short)ll;
        }
        ((uint2*)hi)[i] = h.u2; ((uint2*)mi)[i] = m.u2; ((uint2*)lo)[i] = l.u2;
        return;
    }
    // ---- scan branch: job 0..383 = l0(16) x c0(12) x b(2) ----
    const int job = blockIdx.x;
    const int l0 = (job & 15) * 64;
    const int c0 = ((job >> 4) % 12) * 32;
    const int b  = job / 192;
    const int row = tid >> 3, seg = tid & 7;     // 32 c-rows x 8 l-segs
    float mem[8], sp[8];
#pragma unroll
    for (int e = 0; e < 8; e++) { mem[e] = 0.f; sp[e] = 0.f; }
    const size_t base0 = ((size_t)(b*C_ + c0 + row))*L_ + l0 + seg*8;
    float4 nx0 = *(const float4*)(src + base0);
    float4 nx1 = *(const float4*)(src + base0 + 4);
    for (int t = 0; t < T_; t++) {
        float4 v0 = nx0, v1 = nx1;
        if (t < 3) {
            const size_t nb = ((size_t)(((t+1)*B_ + b)*C_ + c0 + row))*L_ + l0 + seg*8;
            nx0 = *(const float4*)(src + nb);
            nx1 = *(const float4*)(src + nb + 4);
        }
        float vv[8] = {v0.x,v0.y,v0.z,v0.w,v1.x,v1.y,v1.z,v1.w};
        unsigned bs[8];
#pragma unroll
        for (int e = 0; e < 8; e++) {
            mem[e] = mem[e]*0.25f*(1.f - sp[e]) + vv[e];
            bool sb = mem[e] > 0.5f;
            sp[e] = sb ? 1.f : 0.f;
            bs[e] = sb ? 0x3F80u : 0u;
        }
#pragma unroll
        for (int p2 = 0; p2 < 4; p2++)
            *(unsigned*)&tile[row][seg*8 + p2*2] = bs[p2*2] | (bs[p2*2+1] << 16);
        __syncthreads();
        {
            const int lr = tid >> 2, cs = tid & 3;   // 64 l-rows x 4 c-chunks
            unsigned wv[4];
#pragma unroll
            for (int p = 0; p < 4; p++) {
                unsigned e0 = tile[cs*8 + p*2][lr];
                unsigned e1 = tile[cs*8 + p*2 + 1][lr];
                wv[p] = e0 | (e1 << 16);
            }
            uint4 o; o.x = wv[0]; o.y = wv[1]; o.z = wv[2]; o.w = wv[3];
            const int cc = c0 + cs*8;
            *(uint4*)(dstT + ((size_t)(t*B_ + b)*L_ + l0 + lr)*C_ + cc) = o;
            const int hh = cc / 48, kc = (cc % 48) >> 3;
            *(uint4*)(xsF + ((((size_t)(t*B_ + b)*H_ + hh)*6 + kc)*L_ + l0 + lr)*8) = o;
        }
        __syncthreads();
    }
}

// ============ K5: scan over T of (outpre + outpre2) + bf16 transpose =======
__global__ __launch_bounds__(256) void scan_transpose2(
    const float* __restrict__ srcA, const float* __restrict__ srcB,
    unsigned short* __restrict__ dstT) {
    __shared__ unsigned short tile[32][72];
    const int tid = threadIdx.x;
    const int job = blockIdx.x;
    const int l0 = (job & 15) * 64;
    const int c0 = ((job >> 4) % 12) * 32;
    const int b  = job / 192;
    const int row = tid >> 3, seg = tid & 7;
    float mem[8], sp[8];
#pragma unroll
    for (int e = 0; e < 8; e++) { mem[e] = 0.f; sp[e] = 0.f; }
    const size_t base0 = ((size_t)(b*C_ + c0 + row))*L_ + l0 + seg*8;
    float4 na0 = *(const float4*)(srcA + base0);
    float4 na1 = *(const float4*)(srcA + base0 + 4);
    float4 nb0 = *(const float4*)(srcB + base0);
    float4 nb1 = *(const float4*)(srcB + base0 + 4);
    for (int t = 0; t < T_; t++) {
        float4 a0 = na0, a1 = na1, b0 = nb0, b1 = nb1;
        if (t < 3) {
            const size_t nb = ((size_t)(((t+1)*B_ + b)*C_ + c0 + row))*L_ + l0 + seg*8;
            na0 = *(const float4*)(srcA + nb);
            na1 = *(const float4*)(srcA + nb + 4);
            nb0 = *(const float4*)(srcB + nb);
            nb1 = *(const float4*)(srcB + nb + 4);
        }
        float vv[8] = {a0.x+b0.x, a0.y+b0.y, a0.z+b0.z, a0.w+b0.w,
                       a1.x+b1.x, a1.y+b1.y, a1.z+b1.z, a1.w+b1.w};
        unsigned bs[8];
#pragma unroll
        for (int e = 0; e < 8; e++) {
            mem[e] = mem[e]*0.25f*(1.f - sp[e]) + vv[e];
            bool sb = mem[e] > 0.5f;
            sp[e] = sb ? 1.f : 0.f;
            bs[e] = sb ? 0x3F80u : 0u;
        }
#pragma unroll
        for (int p2 = 0; p2 < 4; p2++)
            *(unsigned*)&tile[row][seg*8 + p2*2] = bs[p2*2] | (bs[p2*2+1] << 16);
        __syncthreads();
        {
            const int lr = tid >> 2, cs = tid & 3;
            unsigned wv[4];
#pragma unroll
            for (int p = 0; p < 4; p++) {
                unsigned e0 = tile[cs*8 + p*2][lr];
                unsigned e1 = tile[cs*8 + p*2 + 1][lr];
                wv[p] = e0 | (e1 << 16);
            }
            uint4 o; o.x = wv[0]; o.y = wv[1]; o.z = wv[2]; o.w = wv[3];
            *(uint4*)(dstT + ((size_t)(t*B_ + b)*L_ + l0 + lr)*C_ + c0 + cs*8) = o;
        }
        __syncthreads();
    }
}

// ============ K2: y = BN1(W @ xs) via MFMA, 96m x 64l tile =================
// Round-8 LDS layout (stride 40, 16B-aligned b128 reads — stride 44 split
// them into b64 pairs and regressed). NEW: uniform register prefetch —
// A staged as uint2 chunks (96x8 = 768 = exactly 3/thread), B as uint4
// (exactly 1/thread). All prefetch regs unconditionally defined every
// iteration (only wave-uniform scalar guard), so none demote to scratch
// (round-9 bug: lane-conditional defs -> 225MB scratch writes).
__global__ __launch_bounds__(256) void gemm1_mfma(
    const unsigned short* __restrict__ whi, const unsigned short* __restrict__ wmi,
    const unsigned short* __restrict__ wlo, const unsigned short* __restrict__ xsT,
    const float* __restrict__ g, const float* __restrict__ be,
    const float* __restrict__ mn, const float* __restrict__ vr,
    unsigned short* __restrict__ y1hi, unsigned short* __restrict__ y1mi,
    unsigned short* __restrict__ y1lo,
    unsigned short* __restrict__ y2hi, unsigned short* __restrict__ y2mi,
    unsigned short* __restrict__ y2lo) {
    __shared__ unsigned short smem[14080];   // A: 3 x 96 x 40 @ {0,3840,7680}; B: 64 x 40 @ 11520
    const int tid = threadIdx.x;
    const int flat = blockIdx.x;
    const int tb = flat & 7;
    const int ii = flat >> 3;
    const int mt = ii >> 4, lt = ii & 15;
    const int l0 = lt * 64;
    const int w = tid >> 6, lane = tid & 63;
    const int q = lane >> 4, n15 = lane & 15;
    const int mw = (w & 1) * 48, lw = (w >> 1) * 32;

    floatx4 acc[3][2];
#pragma unroll
    for (int i = 0; i < 3; i++)
#pragma unroll
        for (int j = 0; j < 2; j++) acc[i][j] = (floatx4){0.f,0.f,0.f,0.f};

    // uniform staging decomposition: A chunk = 4 shorts (uint2), s = tid + j*256
    const int a_r0 = tid >> 3;          // j=0: rows 0..31
    const int a_r1 = (tid + 256) >> 3;  // j=1: rows 32..63
    const int a_r2 = (tid + 512) >> 3;  // j=2: rows 64..95
    const int a_c  = tid & 7;           // chunk col (4 shorts), same for all j
    const int br = tid >> 2, bc = tid & 3;
    const size_t aro0 = (size_t)(mt*96 + a_r0)*C_;
    const size_t aro1 = (size_t)(mt*96 + a_r1)*C_;
    const size_t aro2 = (size_t)(mt*96 + a_r2)*C_;
    const size_t brow = ((size_t)tb*L_ + l0 + br)*C_;

    uint2 rA[3][3];   // [plane][j] — all unconditionally defined
    uint4 rB;
#pragma unroll
    for (int p = 0; p < 3; p++) {
        const unsigned short* wp = p == 0 ? whi : p == 1 ? wmi : wlo;
        rA[p][0] = *(const uint2*)(wp + aro0 + a_c*4);
        rA[p][1] = *(const uint2*)(wp + aro1 + a_c*4);
        rA[p][2] = *(const uint2*)(wp + aro2 + a_c*4);
    }
    rB = *(const uint4*)(xsT + brow + bc*8);

    for (int ck = 0; ck < C_; ck += 32) {
#pragma unroll
        for (int p = 0; p < 3; p++) {
            unsigned short* ap = smem + p*3840;
            *(uint2*)&ap[a_r0*40 + a_c*4] = rA[p][0];
            *(uint2*)&ap[a_r1*40 + a_c*4] = rA[p][1];
            *(uint2*)&ap[a_r2*40 + a_c*4] = rA[p][2];
        }
        *(uint4*)&smem[11520 + br*40 + bc*8] = rB;
        __syncthreads();
        if (ck + 32 < C_) {   // wave-uniform scalar guard
            const int nk = ck + 32;
#pragma unroll
            for (int p = 0; p < 3; p++) {
                const unsigned short* wp = p == 0 ? whi : p == 1 ? wmi : wlo;
                rA[p][0] = *(const uint2*)(wp + aro0 + nk + a_c*4);
                rA[p][1] = *(const uint2*)(wp + aro1 + nk + a_c*4);
                rA[p][2] = *(const uint2*)(wp + aro2 + nk + a_c*4);
            }
            rB = *(const uint4*)(xsT + brow + nk + bc*8);
        }
        short8 bb[2];
#pragma unroll
        for (int in = 0; in < 2; in++)
            bb[in] = *(short8*)&smem[11520 + (lw + in*16 + n15)*40 + q*8];
#pragma unroll
        for (int im = 0; im < 3; im++) {
            short8 ah = *(short8*)&smem[       (mw + im*16 + n15)*40 + q*8];
            short8 am = *(short8*)&smem[3840 + (mw + im*16 + n15)*40 + q*8];
            short8 al = *(short8*)&smem[7680 + (mw + im*16 + n15)*40 + q*8];
#pragma unroll
            for (int in = 0; in < 2; in++) {
                acc[im][in] = __builtin_amdgcn_mfma_f32_16x16x32_bf16(ah, bb[in], acc[im][in], 0,0,0);
                acc[im][in] = __builtin_amdgcn_mfma_f32_16x16x32_bf16(am, bb[in], acc[im][in], 0,0,0);
                acc[im][in] = __builtin_amdgcn_mfma_f32_16x16x32_bf16(al, bb[in], acc[im][in], 0,0,0);
            }
        }
        __syncthreads();
    }

#pragma unroll
    for (int im = 0; im < 3; im++)
#pragma unroll
        for (int r = 0; r < 4; r++) {
            int o = mt*96 + mw + im*16 + q*4 + r;
            float inv = g[o] / sqrtf(vr[o] + 1e-5f);
            float sh = be[o] - mn[o]*inv;
#pragma unroll
            for (int in = 0; in < 2; in++)
                acc[im][in][r] = acc[im][in][r]*inv + sh;
        }
    const bool isY1 = ((w & 1) == 0);
#pragma unroll
    for (int p = 0; p < 3; p++) {
        if (isY1) {
#pragma unroll
            for (int im = 0; im < 3; im++)
#pragma unroll
                for (int in = 0; in < 2; in++) {
                    union { unsigned short us[4]; uint2 u2; } pk;
#pragma unroll
                    for (int r = 0; r < 4; r++) {
                        unsigned hh = bf16_rne(acc[im][in][r]);
                        pk.us[r] = (unsigned short)hh;
                        acc[im][in][r] -= bf16_to_f(hh);
                    }
                    *(uint2*)&smem[(lw + in*16 + n15)*56 + im*16 + q*4] = pk.u2;
                }
        } else {
#pragma unroll
            for (int im = 0; im < 3; im++)
#pragma unroll
                for (int in = 0; in < 2; in++)
#pragma unroll
                    for (int r = 0; r < 4; r++) {
                        unsigned hh = bf16_rne(acc[im][in][r]);
                        smem[3584 + (im*16 + q*4 + r)*72 + lw + in*16 + n15] = (unsigned short)hh;
                        acc[im][in][r] -= bf16_to_f(hh);
                    }
        }
        __syncthreads();
        unsigned short* y1p = p == 0 ? y1hi : p == 1 ? y1mi : y1lo;
        unsigned short* y2p = p == 0 ? y2hi : p == 1 ? y2mi : y2lo;
        for (int s = tid; s < 384; s += 256) {
            int c8 = s >> 6, r1 = s & 63;
            *(uint4*)(y1p + ((((size_t)tb*H_ + mt)*6 + c8)*L_ + l0 + r1)*8) =
                *(uint4*)&smem[r1*56 + c8*8];
        }
        for (int s = tid; s < 384; s += 256) {
            int cr = s >> 3, lq = s & 7;
            *(uint4*)(y2p + ((size_t)tb*C_ + mt*48 + cr)*L_ + l0 + lq*8) =
                *(uint4*)&smem[3584 + cr*72 + lq*8];
        }
        __syncthreads();
    }
}

// ============ K3: attn = y1^T @ xr, LDS-free, coalesced fragment loads =====
__global__ __launch_bounds__(256, 4) void attn_spike_mfma(
    const unsigned short* __restrict__ y1hi, const unsigned short* __restrict__ y1mi,
    const unsigned short* __restrict__ y1lo, const unsigned short* __restrict__ xsF,
    unsigned* __restrict__ bits) {
    const int tid = threadIdx.x;
    const int flat = blockIdx.x;
    const int xcd = flat & 7;
    const int ii = flat >> 3;            // 0..255
    const int bh = xcd*2 + (ii >> 7);
    const int rr = ii & 127;
    const int b = bh >> 3, h = bh & 7;
    const int lbase = (rr >> 3) * 64;
    const int mbase = (rr & 7) * 128;
    const int w = tid >> 6, lane = tid & 63;
    const int l31 = lane & 31, half = lane >> 5;
    const int mrow = mbase + w*32 + l31;

    float mem[2][16];
#pragma unroll
    for (int il = 0; il < 2; il++)
#pragma unroll
        for (int r = 0; r < 16; r++) mem[il][r] = 0.f;

    for (int t = 0; t < T_; t++) {
        const int tb = t*B_ + b;
        const size_t fb = ((size_t)tb*H_ + h)*6*L_*8;
        const unsigned short* ya_hi = y1hi + fb;
        const unsigned short* ya_mi = y1mi + fb;
        const unsigned short* ya_lo = y1lo + fb;
        const unsigned short* xf    = xsF  + fb;

        short8 bb[3];
#pragma unroll
        for (int ks = 0; ks < 3; ks++)
            bb[ks] = *(const short8*)(xf + ((size_t)(ks*2 + half)*L_ + mrow)*8);

        floatx16 acc[2];
#pragma unroll
        for (int il = 0; il < 2; il++)
#pragma unroll
            for (int r = 0; r < 16; r++) acc[il][r] = 0.f;

#pragma unroll
        for (int ks = 0; ks < 3; ks++) {
#pragma unroll
            for (int il = 0; il < 2; il++) {
                const size_t aoff = ((size_t)(ks*2 + half)*L_ + lbase + il*32 + l31)*8;
                short8 ah = *(const short8*)(ya_hi + aoff);
                short8 am = *(const short8*)(ya_mi + aoff);
                short8 al = *(const short8*)(ya_lo + aoff);
                acc[il] = __builtin_amdgcn_mfma_f32_32x32x16_bf16(ah, bb[ks], acc[il], 0,0,0);
                acc[il] = __builtin_amdgcn_mfma_f32_32x32x16_bf16(am, bb[ks], acc[il], 0,0,0);
                acc[il] = __builtin_amdgcn_mfma_f32_32x32x16_bf16(al, bb[ks], acc[il], 0,0,0);
            }
        }

        unsigned wds[2];
#pragma unroll
        for (int il = 0; il < 2; il++) {
            unsigned word = 0;
#pragma unroll
            for (int r = 0; r < 16; r++) {
                float m = (mem[il][r] > 0.5f ? 0.f : mem[il][r]*0.25f) + acc[il][r];
                mem[il][r] = m;
                int lloc = (r & 3) + 8*(r >> 2) + 4*half;
                word |= (m > 0.5f) ? (1u << lloc) : 0u;
            }
            wds[il] = word;
        }
        unsigned f0 = wds[0] | __shfl_xor(wds[0], 32);
        unsigned f1 = wds[1] | __shfl_xor(wds[1], 32);
        if (half == 0) {
            uint2 o; o.x = f0; o.y = f1;
            ((uint2*)bits)[((size_t)(tb*H_ + h)*16 + (lbase >> 6))*1024 + mrow] = o;
        }
    }
}

// ============ K4: outpre = y2 @ spikes, split-K over l (2 halves) ==========
__global__ __launch_bounds__(256) void attn_out_mfma(
    const unsigned short* __restrict__ y2hi, const unsigned short* __restrict__ y2mi,
    const unsigned short* __restrict__ y2lo,
    const unsigned* __restrict__ bits,
    float* __restrict__ outpre, float* __restrict__ outpre2) {
    __shared__ unsigned short A_hi[48][72], A_mi[48][72], A_lo[48][72];
    const int tid = threadIdx.x;
    const int flat = blockIdx.x;
    const int xcd = flat & 7;
    const int ii = flat >> 3;            // 0..127
    const int tbh = xcd*8 + (ii >> 4);
    const int mtile = (ii >> 1) & 7;
    const int ls = ii & 1;
    const int t = tbh >> 4, b = (tbh >> 3) & 1, h = tbh & 7;
    const int tb = t*B_ + b;
    const int w = tid >> 6, lane = tid & 63;
    const int q = lane >> 4, n15 = lane & 15;
    const int mb = mtile*128 + w*32;
    const int lt0 = ls * 512;

    floatx4 acc[3][2];
#pragma unroll
    for (int i = 0; i < 3; i++)
#pragma unroll
        for (int in = 0; in < 2; in++) acc[i][in] = (floatx4){0.f,0.f,0.f,0.f};

    const uint2* bvec = (const uint2*)bits;
    const size_t bbase = ((size_t)(tb*H_ + h)*16)*1024 + mb + n15;
    const size_t y2b = ((size_t)tb*C_ + h*48)*L_;

    const int r0 = tid >> 3, c0i = tid & 7;
    const int r1 = (tid + 256) >> 3, c1i = tid & 7;
    uint4 rh0, rm0, rl0, rh1, rm1, rl1;
    {
        size_t ro = y2b + (size_t)r0*L_ + lt0 + c0i*8;
        rh0 = *(const uint4*)(y2hi + ro); rm0 = *(const uint4*)(y2mi + ro); rl0 = *(const uint4*)(y2lo + ro);
        if (tid < 128) {
            size_t ro1 = y2b + (size_t)r1*L_ + lt0 + c1i*8;
            rh1 = *(const uint4*)(y2hi + ro1); rm1 = *(const uint4*)(y2mi + ro1); rl1 = *(const uint4*)(y2lo + ro1);
        }
    }

    for (int it = 0; it < 8; it++) {
        const int lt = lt0 + it*64;
        *(uint4*)&A_hi[r0][c0i*8] = rh0; *(uint4*)&A_mi[r0][c0i*8] = rm0; *(uint4*)&A_lo[r0][c0i*8] = rl0;
        if (tid < 128) {
            *(uint4*)&A_hi[r1][c1i*8] = rh1; *(uint4*)&A_mi[r1][c1i*8] = rm1; *(uint4*)&A_lo[r1][c1i*8] = rl1;
        }
        uint2 bw0 = bvec[bbase + (size_t)(lt >> 6)*1024];
        uint2 bw1 = bvec[bbase + (size_t)(lt >> 6)*1024 + 16];
        __syncthreads();
        if (it < 7) {
            size_t ro = y2b + (size_t)r0*L_ + (lt + 64) + c0i*8;
            rh0 = *(const uint4*)(y2hi + ro); rm0 = *(const uint4*)(y2mi + ro); rl0 = *(const uint4*)(y2lo + ro);
            if (tid < 128) {
                size_t ro1 = y2b + (size_t)r1*L_ + (lt + 64) + c1i*8;
                rh1 = *(const uint4*)(y2hi + ro1); rm1 = *(const uint4*)(y2mi + ro1); rl1 = *(const uint4*)(y2lo + ro1);
            }
        }
#pragma unroll
        for (int kc = 0; kc < 2; kc++) {
            unsigned word0 = kc ? bw0.y : bw0.x;
            unsigned word1 = kc ? bw1.y : bw1.x;
            unsigned byt0 = (word0 >> (q*8)) & 0xFFu;
            unsigned byt1 = (word1 >> (q*8)) & 0xFFu;
            union { unsigned u[4]; short8 v; } bu0, bu1;
#pragma unroll
            for (int p = 0; p < 4; p++) {
                bu0.u[p] = (((byt0 >> (2*p)) & 1u) ? 0x3F80u : 0u)
                         | (((byt0 >> (2*p+1)) & 1u) ? 0x3F800000u : 0u);
                bu1.u[p] = (((byt1 >> (2*p)) & 1u) ? 0x3F80u : 0u)
                         | (((byt1 >> (2*p+1)) & 1u) ? 0x3F800000u : 0u);
            }
            short8 bf0 = bu0.v, bf1 = bu1.v;
#pragma unroll
            for (int i = 0; i < 3; i++) {
                int ra = i*16 + n15;
                short8 ah = *(short8*)&A_hi[ra][kc*32 + q*8];
                short8 am = *(short8*)&A_mi[ra][kc*32 + q*8];
                short8 al = *(short8*)&A_lo[ra][kc*32 + q*8];
                acc[i][0] = __builtin_amdgcn_mfma_f32_16x16x32_bf16(ah, bf0, acc[i][0], 0,0,0);
                acc[i][0] = __builtin_amdgcn_mfma_f32_16x16x32_bf16(am, bf0, acc[i][0], 0,0,0);
                acc[i][0] = __builtin_amdgcn_mfma_f32_16x16x32_bf16(al, bf0, acc[i][0], 0,0,0);
                acc[i][1] = __builtin_amdgcn_mfma_f32_16x16x32_bf16(ah, bf1, acc[i][1], 0,0,0);
                acc[i][1] = __builtin_amdgcn_mfma_f32_16x16x32_bf16(am, bf1, acc[i][1], 0,0,0);
                acc[i][1] = __builtin_amdgcn_mfma_f32_16x16x32_bf16(al, bf1, acc[i][1], 0,0,0);
            }
        }
        __syncthreads();
    }
    float* outP = ls ? outpre2 : outpre;
#pragma unroll
    for (int i = 0; i < 3; i++)
#pragma unroll
        for (int r = 0; r < 4; r++) {
            int d = i*16 + q*4 + r;
#pragma unroll
            for (int in = 0; in < 2; in++)
                outP[((size_t)tb*C_ + h*48 + d)*L_ + mb + in*16 + n15] = acc[i][in][r];
        }
}

// ============ K6: out = BN2(proj @ outs) + x (MFMA, 96x64 tile) ============
__global__ __launch_bounds__(256) void gemm2_mfma(
    const unsigned short* __restrict__ whi, const unsigned short* __restrict__ wmi,
    const unsigned short* __restrict__ wlo, const unsigned short* __restrict__ xT,
    const float* __restrict__ g, const float* __restrict__ be,
    const float* __restrict__ mn, const float* __restrict__ vr,
    const float* __restrict__ res, float* __restrict__ out) {
    __shared__ unsigned short A_hi[96][40], A_mi[96][40], A_lo[96][40];
    __shared__ unsigned short B_s[64][40];
    const int tid = threadIdx.x;
    const int tb = blockIdx.y;
    const int mt = blockIdx.x >> 4, lt = blockIdx.x & 15;
    const int l0 = lt * 64;
    const int w = tid >> 6, lane = tid & 63;
    const int q = lane >> 4, n15 = lane & 15;
    const int mw = (w & 1) * 48, lw = (w >> 1) * 32;

    floatx4 acc[3][2];
#pragma unroll
    for (int i = 0; i < 3; i++)
#pragma unroll
        for (int j = 0; j < 2; j++) acc[i][j] = (floatx4){0.f,0.f,0.f,0.f};

    for (int ck = 0; ck < C_; ck += 32) {
#pragma unroll
        for (int p = 0; p < 3; p++) {
            const unsigned short* wp = p == 0 ? whi : p == 1 ? wmi : wlo;
            unsigned short (*ap)[40] = p == 0 ? A_hi : p == 1 ? A_mi : A_lo;
            for (int s = tid; s < 384; s += 256) {
                int r = s >> 2, c = s & 3;
                *(uint4*)&ap[r][c*8] = *(const uint4*)(wp + (size_t)(mt*96 + r)*C_ + ck + c*8);
            }
        }
        {
            int r = tid >> 2, c4 = tid & 3;
            *(uint4*)&B_s[r][c4*8] = *(const uint4*)(xT + ((size_t)tb*L_ + l0 + r)*C_ + ck + c4*8);
        }
        __syncthreads();
        short8 bb[2];
#pragma unroll
        for (int in = 0; in < 2; in++)
            bb[in] = *(short8*)&B_s[lw + in*16 + n15][q*8];
#pragma unroll
        for (int im = 0; im < 3; im++) {
            short8 ah = *(short8*)&A_hi[mw + im*16 + n15][q*8];
            short8 am = *(short8*)&A_mi[mw + im*16 + n15][q*8];
            short8 al = *(short8*)&A_lo[mw + im*16 + n15][q*8];
#pragma unroll
            for (int in = 0; in < 2; in++) {
                acc[im][in] = __builtin_amdgcn_mfma_f32_16x16x32_bf16(ah, bb[in], acc[im][in], 0,0,0);
                acc[im][in] = __builtin_amdgcn_mfma_f32_16x16x32_bf16(am, bb[in], acc[im][in], 0,0,0);
                acc[im][in] = __builtin_amdgcn_mfma_f32_16x16x32_bf16(al, bb[in], acc[im][in], 0,0,0);
            }
        }
        __syncthreads();
    }
#pragma unroll
    for (int im = 0; im < 3; im++)
#pragma unroll
        for (int r = 0; r < 4; r++) {
            int o = mt*96 + mw + im*16 + q*4 + r;
            float inv = g[o] / sqrtf(vr[o] + 1e-5f);
            float sh = be[o] - mn[o]*inv;
#pragma unroll
            for (int in = 0; in < 2; in++) {
                int l = l0 + lw + in*16 + n15;
                size_t idx = ((size_t)tb*C_ + o)*L_ + l;
                out[idx] = acc[im][in][r]*inv + sh + res[idx];
            }
        }
}

extern "C" void kernel_launch(void* const* d_in, const int* in_sizes, int n_in,
                              void* d_out, int out_size, void* d_ws, size_t ws_size,
                              hipStream_t stream) {
    const float* x   = (const float*)d_in[0];
    const float* W_w = (const float*)d_in[1];
    const float* g1  = (const float*)d_in[2];
    const float* b1  = (const float*)d_in[3];
    const float* m1  = (const float*)d_in[4];
    const float* v1  = (const float*)d_in[5];
    const float* pw  = (const float*)d_in[6];
    const float* g2  = (const float*)d_in[7];
    const float* b2  = (const float*)d_in[8];
    const float* m2  = (const float*)d_in[9];
    const float* v2  = (const float*)d_in[10];

    float* ws = (float*)d_ws;
    unsigned short* xsT  = (unsigned short*)ws;
    unsigned short* y1hi = (unsigned short*)(ws + 1572864);
    unsigned short* y1mi = (unsigned short*)(ws + 3145728);
    unsigned short* y1lo = (unsigned short*)(ws + 4718592);
    unsigned short* y2hi = (unsigned short*)(ws + 6291456);
    unsigned short* y2mi = (unsigned short*)(ws + 7864320);
    unsigned short* y2lo = (unsigned short*)(ws + 9437184);
    unsigned*       bits = (unsigned*)(ws + 11010048);
    unsigned short* wspl[3]  = {(unsigned short*)(ws + 13107200),
                                (unsigned short*)(ws + 13254656),
                                (unsigned short*)(ws + 13402112)};
    unsigned short* pwspl[3] = {(unsigned short*)(ws + 13549568),
                                (unsigned short*)(ws + 13623296),
                                (unsigned short*)(ws + 13697024)};
    unsigned short* xsF  = (unsigned short*)(ws + 13770752);
    float*          outpre  = (float*)(ws + 1572864);
    float*          outpre2 = (float*)(ws + 14557184);
    unsigned short* outsT   = (unsigned short*)(ws + 4718592);
    float* out = (float*)d_out;

    // 1) xs scan (both layouts, prefetched, 384 blocks) + weight split
    scan_and_split<<<dim3(816), 256, 0, stream>>>(x, xsT, xsF,
                                                  W_w, C2_*C_/4, wspl[0], wspl[1], wspl[2],
                                                  pw,  C_*C_/4, pwspl[0], pwspl[1], pwspl[2]);
    // 2) y = BN1(W @ xs): stride-40 LDS + uniform register prefetch
    gemm1_mfma<<<dim3(1024), 256, 0, stream>>>(wspl[0], wspl[1], wspl[2], xsT,
                                               g1, b1, m1, v1,
                                               y1hi, y1mi, y1lo, y2hi, y2mi, y2lo);
    // 3) attn spikes: LDS-free, coalesced; bits transposed layout
    attn_spike_mfma<<<dim3(2048), 256, 0, stream>>>(y1hi, y1mi, y1lo, xsF, bits);
    // 4) outpre(+outpre2) = y2 @ spikes: split-K over l, prefetched staging
    attn_out_mfma<<<dim3(1024), 256, 0, stream>>>(y2hi, y2mi, y2lo, bits, outpre, outpre2);
    // 5) outs spikes = scan(outpre + outpre2) -> bf16 transposed
    scan_transpose2<<<dim3(384), 256, 0, stream>>>(outpre, outpre2, outsT);
    // 6) out = BN2(proj @ outs) + x
    gemm2_mfma<<<dim3(64, 8), 256, 0, stream>>>(pwspl[0], pwspl[1], pwspl[2], outsT,
                                                g2, b2, m2, v2, x, out);
}

// Round 12
// 193.263 us; speedup vs baseline: 1.3015x; 1.0598x over previous
//
#include <hip/hip_runtime.h>

#define T_  4
#define B_  2
#define C_  384
#define L_  1024
#define H_  8
#define C2_ 768

typedef __attribute__((ext_vector_type(8))) short short8;
typedef __attribute__((ext_vector_type(4))) float floatx4;
typedef __attribute__((ext_vector_type(16))) float floatx16;

__device__ __forceinline__ unsigned bf16_rne(float v) {
    unsigned u = __float_as_uint(v);
    u += 0x7FFFu + ((u >> 16) & 1u);
    return u >> 16;
}
__device__ __forceinline__ float bf16_to_f(unsigned h) { return __uint_as_float(h << 16); }
__device__ __forceinline__ void split3(float v, unsigned& hi, unsigned& mi, unsigned& lo) {
    hi = bf16_rne(v);
    float r1 = v - bf16_to_f(hi);
    mi = bf16_rne(r1);
    float r2 = r1 - bf16_to_f(mi);
    lo = bf16_rne(r2);
}

// ==== K1+K0: blocks 0-383 run the xs scan (64l x 32c tiles, prefetched);
// blocks 384-815 split both fp32 weight tensors into 3 bf16 planes.
__global__ __launch_bounds__(256) void scan_and_split(
    const float* __restrict__ src, unsigned short* __restrict__ dstT,
    unsigned short* __restrict__ xsF,
    const float* __restrict__ Wa, int n4a,
    unsigned short* __restrict__ hia, unsigned short* __restrict__ mia,
    unsigned short* __restrict__ loa,
    const float* __restrict__ Wb, int n4b,
    unsigned short* __restrict__ hib, unsigned short* __restrict__ mib,
    unsigned short* __restrict__ lob) {
    __shared__ unsigned short tile[32][72];
    const int tid = threadIdx.x;
    if (blockIdx.x >= 384) {
        int i = (blockIdx.x - 384) * 256 + tid;
        const float* W; unsigned short *hi, *mi, *lo;
        if (i < n4a) { W = Wa; hi = hia; mi = mia; lo = loa; }
        else {
            i -= n4a;
            if (i >= n4b) return;
            W = Wb; hi = hib; mi = mib; lo = lob;
        }
        float4 v = ((const float4*)W)[i];
        float vv[4] = {v.x, v.y, v.z, v.w};
        union { unsigned short us[4]; uint2 u2; } h, m, l;
#pragma unroll
        for (int e = 0; e < 4; e++) {
            unsigned hh, mm, ll; split3(vv[e], hh, mm, ll);
            h.us[e] = (unsigned short)hh; m.us[e] = (unsigned short)mm; l.us[e] = (unsigned short)ll;
        }
        ((uint2*)hi)[i] = h.u2; ((uint2*)mi)[i] = m.u2; ((uint2*)lo)[i] = l.u2;
        return;
    }
    // ---- scan branch: job 0..383 = l0(16) x c0(12) x b(2) ----
    const int job = blockIdx.x;
    const int l0 = (job & 15) * 64;
    const int c0 = ((job >> 4) % 12) * 32;
    const int b  = job / 192;
    const int row = tid >> 3, seg = tid & 7;     // 32 c-rows x 8 l-segs
    float mem[8], sp[8];
#pragma unroll
    for (int e = 0; e < 8; e++) { mem[e] = 0.f; sp[e] = 0.f; }
    const size_t base0 = ((size_t)(b*C_ + c0 + row))*L_ + l0 + seg*8;
    float4 nx0 = *(const float4*)(src + base0);
    float4 nx1 = *(const float4*)(src + base0 + 4);
    for (int t = 0; t < T_; t++) {
        float4 v0 = nx0, v1 = nx1;
        if (t < 3) {
            const size_t nb = ((size_t)(((t+1)*B_ + b)*C_ + c0 + row))*L_ + l0 + seg*8;
            nx0 = *(const float4*)(src + nb);
            nx1 = *(const float4*)(src + nb + 4);
        }
        float vv[8] = {v0.x,v0.y,v0.z,v0.w,v1.x,v1.y,v1.z,v1.w};
        unsigned bs[8];
#pragma unroll
        for (int e = 0; e < 8; e++) {
            mem[e] = mem[e]*0.25f*(1.f - sp[e]) + vv[e];
            bool sb = mem[e] > 0.5f;
            sp[e] = sb ? 1.f : 0.f;
            bs[e] = sb ? 0x3F80u : 0u;
        }
#pragma unroll
        for (int p2 = 0; p2 < 4; p2++)
            *(unsigned*)&tile[row][seg*8 + p2*2] = bs[p2*2] | (bs[p2*2+1] << 16);
        __syncthreads();
        {
            const int lr = tid >> 2, cs = tid & 3;   // 64 l-rows x 4 c-chunks
            unsigned wv[4];
#pragma unroll
            for (int p = 0; p < 4; p++) {
                unsigned e0 = tile[cs*8 + p*2][lr];
                unsigned e1 = tile[cs*8 + p*2 + 1][lr];
                wv[p] = e0 | (e1 << 16);
            }
            uint4 o; o.x = wv[0]; o.y = wv[1]; o.z = wv[2]; o.w = wv[3];
            const int cc = c0 + cs*8;
            *(uint4*)(dstT + ((size_t)(t*B_ + b)*L_ + l0 + lr)*C_ + cc) = o;
            const int hh = cc / 48, kc = (cc % 48) >> 3;
            *(uint4*)(xsF + ((((size_t)(t*B_ + b)*H_ + hh)*6 + kc)*L_ + l0 + lr)*8) = o;
        }
        __syncthreads();
    }
}

// ============ K5: scan over T of (outpre + outpre2) + bf16 transpose =======
__global__ __launch_bounds__(256) void scan_transpose2(
    const float* __restrict__ srcA, const float* __restrict__ srcB,
    unsigned short* __restrict__ dstT) {
    __shared__ unsigned short tile[32][72];
    const int tid = threadIdx.x;
    const int job = blockIdx.x;
    const int l0 = (job & 15) * 64;
    const int c0 = ((job >> 4) % 12) * 32;
    const int b  = job / 192;
    const int row = tid >> 3, seg = tid & 7;
    float mem[8], sp[8];
#pragma unroll
    for (int e = 0; e < 8; e++) { mem[e] = 0.f; sp[e] = 0.f; }
    const size_t base0 = ((size_t)(b*C_ + c0 + row))*L_ + l0 + seg*8;
    float4 na0 = *(const float4*)(srcA + base0);
    float4 na1 = *(const float4*)(srcA + base0 + 4);
    float4 nb0 = *(const float4*)(srcB + base0);
    float4 nb1 = *(const float4*)(srcB + base0 + 4);
    for (int t = 0; t < T_; t++) {
        float4 a0 = na0, a1 = na1, b0 = nb0, b1 = nb1;
        if (t < 3) {
            const size_t nb = ((size_t)(((t+1)*B_ + b)*C_ + c0 + row))*L_ + l0 + seg*8;
            na0 = *(const float4*)(srcA + nb);
            na1 = *(const float4*)(srcA + nb + 4);
            nb0 = *(const float4*)(srcB + nb);
            nb1 = *(const float4*)(srcB + nb + 4);
        }
        float vv[8] = {a0.x+b0.x, a0.y+b0.y, a0.z+b0.z, a0.w+b0.w,
                       a1.x+b1.x, a1.y+b1.y, a1.z+b1.z, a1.w+b1.w};
        unsigned bs[8];
#pragma unroll
        for (int e = 0; e < 8; e++) {
            mem[e] = mem[e]*0.25f*(1.f - sp[e]) + vv[e];
            bool sb = mem[e] > 0.5f;
            sp[e] = sb ? 1.f : 0.f;
            bs[e] = sb ? 0x3F80u : 0u;
        }
#pragma unroll
        for (int p2 = 0; p2 < 4; p2++)
            *(unsigned*)&tile[row][seg*8 + p2*2] = bs[p2*2] | (bs[p2*2+1] << 16);
        __syncthreads();
        {
            const int lr = tid >> 2, cs = tid & 3;
            unsigned wv[4];
#pragma unroll
            for (int p = 0; p < 4; p++) {
                unsigned e0 = tile[cs*8 + p*2][lr];
                unsigned e1 = tile[cs*8 + p*2 + 1][lr];
                wv[p] = e0 | (e1 << 16);
            }
            uint4 o; o.x = wv[0]; o.y = wv[1]; o.z = wv[2]; o.w = wv[3];
            *(uint4*)(dstT + ((size_t)(t*B_ + b)*L_ + l0 + lr)*C_ + c0 + cs*8) = o;
        }
        __syncthreads();
    }
}

// ============ K2: y = BN1(W @ xs) via MFMA, 96m x 64l tile =================
// Stride-40 LDS + uniform register prefetch (round-11 verified: all prefetch
// regs unconditionally defined -> no scratch demotion).
__global__ __launch_bounds__(256) void gemm1_mfma(
    const unsigned short* __restrict__ whi, const unsigned short* __restrict__ wmi,
    const unsigned short* __restrict__ wlo, const unsigned short* __restrict__ xsT,
    const float* __restrict__ g, const float* __restrict__ be,
    const float* __restrict__ mn, const float* __restrict__ vr,
    unsigned short* __restrict__ y1hi, unsigned short* __restrict__ y1mi,
    unsigned short* __restrict__ y1lo,
    unsigned short* __restrict__ y2hi, unsigned short* __restrict__ y2mi,
    unsigned short* __restrict__ y2lo) {
    __shared__ unsigned short smem[14080];   // A: 3 x 96 x 40 @ {0,3840,7680}; B: 64 x 40 @ 11520
    const int tid = threadIdx.x;
    const int flat = blockIdx.x;
    const int tb = flat & 7;
    const int ii = flat >> 3;
    const int mt = ii >> 4, lt = ii & 15;
    const int l0 = lt * 64;
    const int w = tid >> 6, lane = tid & 63;
    const int q = lane >> 4, n15 = lane & 15;
    const int mw = (w & 1) * 48, lw = (w >> 1) * 32;

    floatx4 acc[3][2];
#pragma unroll
    for (int i = 0; i < 3; i++)
#pragma unroll
        for (int j = 0; j < 2; j++) acc[i][j] = (floatx4){0.f,0.f,0.f,0.f};

    const int a_r0 = tid >> 3;
    const int a_r1 = (tid + 256) >> 3;
    const int a_r2 = (tid + 512) >> 3;
    const int a_c  = tid & 7;
    const int br = tid >> 2, bc = tid & 3;
    const size_t aro0 = (size_t)(mt*96 + a_r0)*C_;
    const size_t aro1 = (size_t)(mt*96 + a_r1)*C_;
    const size_t aro2 = (size_t)(mt*96 + a_r2)*C_;
    const size_t brow = ((size_t)tb*L_ + l0 + br)*C_;

    uint2 rA[3][3];
    uint4 rB;
#pragma unroll
    for (int p = 0; p < 3; p++) {
        const unsigned short* wp = p == 0 ? whi : p == 1 ? wmi : wlo;
        rA[p][0] = *(const uint2*)(wp + aro0 + a_c*4);
        rA[p][1] = *(const uint2*)(wp + aro1 + a_c*4);
        rA[p][2] = *(const uint2*)(wp + aro2 + a_c*4);
    }
    rB = *(const uint4*)(xsT + brow + bc*8);

    for (int ck = 0; ck < C_; ck += 32) {
#pragma unroll
        for (int p = 0; p < 3; p++) {
            unsigned short* ap = smem + p*3840;
            *(uint2*)&ap[a_r0*40 + a_c*4] = rA[p][0];
            *(uint2*)&ap[a_r1*40 + a_c*4] = rA[p][1];
            *(uint2*)&ap[a_r2*40 + a_c*4] = rA[p][2];
        }
        *(uint4*)&smem[11520 + br*40 + bc*8] = rB;
        __syncthreads();
        if (ck + 32 < C_) {
            const int nk = ck + 32;
#pragma unroll
            for (int p = 0; p < 3; p++) {
                const unsigned short* wp = p == 0 ? whi : p == 1 ? wmi : wlo;
                rA[p][0] = *(const uint2*)(wp + aro0 + nk + a_c*4);
                rA[p][1] = *(const uint2*)(wp + aro1 + nk + a_c*4);
                rA[p][2] = *(const uint2*)(wp + aro2 + nk + a_c*4);
            }
            rB = *(const uint4*)(xsT + brow + nk + bc*8);
        }
        short8 bb[2];
#pragma unroll
        for (int in = 0; in < 2; in++)
            bb[in] = *(short8*)&smem[11520 + (lw + in*16 + n15)*40 + q*8];
#pragma unroll
        for (int im = 0; im < 3; im++) {
            short8 ah = *(short8*)&smem[       (mw + im*16 + n15)*40 + q*8];
            short8 am = *(short8*)&smem[3840 + (mw + im*16 + n15)*40 + q*8];
            short8 al = *(short8*)&smem[7680 + (mw + im*16 + n15)*40 + q*8];
#pragma unroll
            for (int in = 0; in < 2; in++) {
                acc[im][in] = __builtin_amdgcn_mfma_f32_16x16x32_bf16(ah, bb[in], acc[im][in], 0,0,0);
                acc[im][in] = __builtin_amdgcn_mfma_f32_16x16x32_bf16(am, bb[in], acc[im][in], 0,0,0);
                acc[im][in] = __builtin_amdgcn_mfma_f32_16x16x32_bf16(al, bb[in], acc[im][in], 0,0,0);
            }
        }
        __syncthreads();
    }

#pragma unroll
    for (int im = 0; im < 3; im++)
#pragma unroll
        for (int r = 0; r < 4; r++) {
            int o = mt*96 + mw + im*16 + q*4 + r;
            float inv = g[o] / sqrtf(vr[o] + 1e-5f);
            float sh = be[o] - mn[o]*inv;
#pragma unroll
            for (int in = 0; in < 2; in++)
                acc[im][in][r] = acc[im][in][r]*inv + sh;
        }
    const bool isY1 = ((w & 1) == 0);
#pragma unroll
    for (int p = 0; p < 3; p++) {
        if (isY1) {
#pragma unroll
            for (int im = 0; im < 3; im++)
#pragma unroll
                for (int in = 0; in < 2; in++) {
                    union { unsigned short us[4]; uint2 u2; } pk;
#pragma unroll
                    for (int r = 0; r < 4; r++) {
                        unsigned hh = bf16_rne(acc[im][in][r]);
                        pk.us[r] = (unsigned short)hh;
                        acc[im][in][r] -= bf16_to_f(hh);
                    }
                    *(uint2*)&smem[(lw + in*16 + n15)*56 + im*16 + q*4] = pk.u2;
                }
        } else {
#pragma unroll
            for (int im = 0; im < 3; im++)
#pragma unroll
                for (int in = 0; in < 2; in++)
#pragma unroll
                    for (int r = 0; r < 4; r++) {
                        unsigned hh = bf16_rne(acc[im][in][r]);
                        smem[3584 + (im*16 + q*4 + r)*72 + lw + in*16 + n15] = (unsigned short)hh;
                        acc[im][in][r] -= bf16_to_f(hh);
                    }
        }
        __syncthreads();
        unsigned short* y1p = p == 0 ? y1hi : p == 1 ? y1mi : y1lo;
        unsigned short* y2p = p == 0 ? y2hi : p == 1 ? y2mi : y2lo;
        for (int s = tid; s < 384; s += 256) {
            int c8 = s >> 6, r1 = s & 63;
            *(uint4*)(y1p + ((((size_t)tb*H_ + mt)*6 + c8)*L_ + l0 + r1)*8) =
                *(uint4*)&smem[r1*56 + c8*8];
        }
        for (int s = tid; s < 384; s += 256) {
            int cr = s >> 3, lq = s & 7;
            *(uint4*)(y2p + ((size_t)tb*C_ + mt*48 + cr)*L_ + l0 + lq*8) =
                *(uint4*)&smem[3584 + cr*72 + lq*8];
        }
        __syncthreads();
    }
}

// ============ K3: attn = y1^T @ xr, LDS-free, coalesced fragment loads =====
__global__ __launch_bounds__(256, 4) void attn_spike_mfma(
    const unsigned short* __restrict__ y1hi, const unsigned short* __restrict__ y1mi,
    const unsigned short* __restrict__ y1lo, const unsigned short* __restrict__ xsF,
    unsigned* __restrict__ bits) {
    const int tid = threadIdx.x;
    const int flat = blockIdx.x;
    const int xcd = flat & 7;
    const int ii = flat >> 3;            // 0..255
    const int bh = xcd*2 + (ii >> 7);
    const int rr = ii & 127;
    const int b = bh >> 3, h = bh & 7;
    const int lbase = (rr >> 3) * 64;
    const int mbase = (rr & 7) * 128;
    const int w = tid >> 6, lane = tid & 63;
    const int l31 = lane & 31, half = lane >> 5;
    const int mrow = mbase + w*32 + l31;

    float mem[2][16];
#pragma unroll
    for (int il = 0; il < 2; il++)
#pragma unroll
        for (int r = 0; r < 16; r++) mem[il][r] = 0.f;

    for (int t = 0; t < T_; t++) {
        const int tb = t*B_ + b;
        const size_t fb = ((size_t)tb*H_ + h)*6*L_*8;
        const unsigned short* ya_hi = y1hi + fb;
        const unsigned short* ya_mi = y1mi + fb;
        const unsigned short* ya_lo = y1lo + fb;
        const unsigned short* xf    = xsF  + fb;

        short8 bb[3];
#pragma unroll
        for (int ks = 0; ks < 3; ks++)
            bb[ks] = *(const short8*)(xf + ((size_t)(ks*2 + half)*L_ + mrow)*8);

        floatx16 acc[2];
#pragma unroll
        for (int il = 0; il < 2; il++)
#pragma unroll
            for (int r = 0; r < 16; r++) acc[il][r] = 0.f;

#pragma unroll
        for (int ks = 0; ks < 3; ks++) {
#pragma unroll
            for (int il = 0; il < 2; il++) {
                const size_t aoff = ((size_t)(ks*2 + half)*L_ + lbase + il*32 + l31)*8;
                short8 ah = *(const short8*)(ya_hi + aoff);
                short8 am = *(const short8*)(ya_mi + aoff);
                short8 al = *(const short8*)(ya_lo + aoff);
                acc[il] = __builtin_amdgcn_mfma_f32_32x32x16_bf16(ah, bb[ks], acc[il], 0,0,0);
                acc[il] = __builtin_amdgcn_mfma_f32_32x32x16_bf16(am, bb[ks], acc[il], 0,0,0);
                acc[il] = __builtin_amdgcn_mfma_f32_32x32x16_bf16(al, bb[ks], acc[il], 0,0,0);
            }
        }

        unsigned wds[2];
#pragma unroll
        for (int il = 0; il < 2; il++) {
            unsigned word = 0;
#pragma unroll
            for (int r = 0; r < 16; r++) {
                float m = (mem[il][r] > 0.5f ? 0.f : mem[il][r]*0.25f) + acc[il][r];
                mem[il][r] = m;
                int lloc = (r & 3) + 8*(r >> 2) + 4*half;
                word |= (m > 0.5f) ? (1u << lloc) : 0u;
            }
            wds[il] = word;
        }
        unsigned f0 = wds[0] | __shfl_xor(wds[0], 32);
        unsigned f1 = wds[1] | __shfl_xor(wds[1], 32);
        if (half == 0) {
            uint2 o; o.x = f0; o.y = f1;
            ((uint2*)bits)[((size_t)(tb*H_ + h)*16 + (lbase >> 6))*1024 + mrow] = o;
        }
    }
}

// ============ K4: outpre = y2 @ spikes, split-K over l (2 halves) ==========
// Uniform register prefetch (round-11 pattern): A staged as uint2 chunks,
// 48 rows x 16 chunks = 768 = exactly 3/thread/plane, ALL unconditionally
// defined (old version's if(tid<128) prefetch regs = round-9 spill pattern).
__global__ __launch_bounds__(256) void attn_out_mfma(
    const unsigned short* __restrict__ y2hi, const unsigned short* __restrict__ y2mi,
    const unsigned short* __restrict__ y2lo,
    const unsigned* __restrict__ bits,
    float* __restrict__ outpre, float* __restrict__ outpre2) {
    __shared__ unsigned short A_hi[48][72], A_mi[48][72], A_lo[48][72];
    const int tid = threadIdx.x;
    const int flat = blockIdx.x;
    const int xcd = flat & 7;
    const int ii = flat >> 3;            // 0..127
    const int tbh = xcd*8 + (ii >> 4);
    const int mtile = (ii >> 1) & 7;
    const int ls = ii & 1;
    const int t = tbh >> 4, b = (tbh >> 3) & 1, h = tbh & 7;
    const int tb = t*B_ + b;
    const int w = tid >> 6, lane = tid & 63;
    const int q = lane >> 4, n15 = lane & 15;
    const int mb = mtile*128 + w*32;
    const int lt0 = ls * 512;

    floatx4 acc[3][2];
#pragma unroll
    for (int i = 0; i < 3; i++)
#pragma unroll
        for (int in = 0; in < 2; in++) acc[i][in] = (floatx4){0.f,0.f,0.f,0.f};

    const uint2* bvec = (const uint2*)bits;
    const size_t bbase = ((size_t)(tb*H_ + h)*16)*1024 + mb + n15;
    const size_t y2b = ((size_t)tb*C_ + h*48)*L_;

    // uniform staging: uint2 chunk s = tid + j*256, row = s>>4, chunk col = tid&15
    const int s_r0 = tid >> 4;           // rows 0..15
    const int s_r1 = (tid + 256) >> 4;   // rows 16..31
    const int s_r2 = (tid + 512) >> 4;   // rows 32..47
    const int s_c  = tid & 15;           // 4-short chunk
    const size_t ro0 = y2b + (size_t)s_r0*L_ + s_c*4;
    const size_t ro1 = y2b + (size_t)s_r1*L_ + s_c*4;
    const size_t ro2 = y2b + (size_t)s_r2*L_ + s_c*4;

    uint2 rA[3][3];   // [plane][j] — all unconditionally defined
#pragma unroll
    for (int p = 0; p < 3; p++) {
        const unsigned short* yp = p == 0 ? y2hi : p == 1 ? y2mi : y2lo;
        rA[p][0] = *(const uint2*)(yp + ro0 + lt0);
        rA[p][1] = *(const uint2*)(yp + ro1 + lt0);
        rA[p][2] = *(const uint2*)(yp + ro2 + lt0);
    }

    for (int it = 0; it < 8; it++) {
        const int lt = lt0 + it*64;
        *(uint2*)&A_hi[s_r0][s_c*4] = rA[0][0];
        *(uint2*)&A_hi[s_r1][s_c*4] = rA[0][1];
        *(uint2*)&A_hi[s_r2][s_c*4] = rA[0][2];
        *(uint2*)&A_mi[s_r0][s_c*4] = rA[1][0];
        *(uint2*)&A_mi[s_r1][s_c*4] = rA[1][1];
        *(uint2*)&A_mi[s_r2][s_c*4] = rA[1][2];
        *(uint2*)&A_lo[s_r0][s_c*4] = rA[2][0];
        *(uint2*)&A_lo[s_r1][s_c*4] = rA[2][1];
        *(uint2*)&A_lo[s_r2][s_c*4] = rA[2][2];
        uint2 bw0 = bvec[bbase + (size_t)(lt >> 6)*1024];
        uint2 bw1 = bvec[bbase + (size_t)(lt >> 6)*1024 + 16];
        __syncthreads();
        if (it < 7) {   // wave-uniform scalar guard
            const int nlt = lt + 64;
#pragma unroll
            for (int p = 0; p < 3; p++) {
                const unsigned short* yp = p == 0 ? y2hi : p == 1 ? y2mi : y2lo;
                rA[p][0] = *(const uint2*)(yp + ro0 + nlt);
                rA[p][1] = *(const uint2*)(yp + ro1 + nlt);
                rA[p][2] = *(const uint2*)(yp + ro2 + nlt);
            }
        }
#pragma unroll
        for (int kc = 0; kc < 2; kc++) {
            unsigned word0 = kc ? bw0.y : bw0.x;
            unsigned word1 = kc ? bw1.y : bw1.x;
            unsigned byt0 = (word0 >> (q*8)) & 0xFFu;
            unsigned byt1 = (word1 >> (q*8)) & 0xFFu;
            union { unsigned u[4]; short8 v; } bu0, bu1;
#pragma unroll
            for (int p = 0; p < 4; p++) {
                bu0.u[p] = (((byt0 >> (2*p)) & 1u) ? 0x3F80u : 0u)
                         | (((byt0 >> (2*p+1)) & 1u) ? 0x3F800000u : 0u);
                bu1.u[p] = (((byt1 >> (2*p)) & 1u) ? 0x3F80u : 0u)
                         | (((byt1 >> (2*p+1)) & 1u) ? 0x3F800000u : 0u);
            }
            short8 bf0 = bu0.v, bf1 = bu1.v;
#pragma unroll
            for (int i = 0; i < 3; i++) {
                int ra = i*16 + n15;
                short8 ah = *(short8*)&A_hi[ra][kc*32 + q*8];
                short8 am = *(short8*)&A_mi[ra][kc*32 + q*8];
                short8 al = *(short8*)&A_lo[ra][kc*32 + q*8];
                acc[i][0] = __builtin_amdgcn_mfma_f32_16x16x32_bf16(ah, bf0, acc[i][0], 0,0,0);
                acc[i][0] = __builtin_amdgcn_mfma_f32_16x16x32_bf16(am, bf0, acc[i][0], 0,0,0);
                acc[i][0] = __builtin_amdgcn_mfma_f32_16x16x32_bf16(al, bf0, acc[i][0], 0,0,0);
                acc[i][1] = __builtin_amdgcn_mfma_f32_16x16x32_bf16(ah, bf1, acc[i][1], 0,0,0);
                acc[i][1] = __builtin_amdgcn_mfma_f32_16x16x32_bf16(am, bf1, acc[i][1], 0,0,0);
                acc[i][1] = __builtin_amdgcn_mfma_f32_16x16x32_bf16(al, bf1, acc[i][1], 0,0,0);
            }
        }
        __syncthreads();
    }
    float* outP = ls ? outpre2 : outpre;
#pragma unroll
    for (int i = 0; i < 3; i++)
#pragma unroll
        for (int r = 0; r < 4; r++) {
            int d = i*16 + q*4 + r;
#pragma unroll
            for (int in = 0; in < 2; in++)
                outP[((size_t)tb*C_ + h*48 + d)*L_ + mb + in*16 + n15] = acc[i][in][r];
        }
}

// ============ K6: out = BN2(proj @ outs) + x (MFMA, 96x64 tile) ============
// K2's round-11 uniform register-prefetch K-loop ported verbatim.
__global__ __launch_bounds__(256) void gemm2_mfma(
    const unsigned short* __restrict__ whi, const unsigned short* __restrict__ wmi,
    const unsigned short* __restrict__ wlo, const unsigned short* __restrict__ xT,
    const float* __restrict__ g, const float* __restrict__ be,
    const float* __restrict__ mn, const float* __restrict__ vr,
    const float* __restrict__ res, float* __restrict__ out) {
    __shared__ unsigned short A_hi[96][40], A_mi[96][40], A_lo[96][40];
    __shared__ unsigned short B_s[64][40];
    const int tid = threadIdx.x;
    const int tb = blockIdx.y;
    const int mt = blockIdx.x >> 4, lt = blockIdx.x & 15;
    const int l0 = lt * 64;
    const int w = tid >> 6, lane = tid & 63;
    const int q = lane >> 4, n15 = lane & 15;
    const int mw = (w & 1) * 48, lw = (w >> 1) * 32;

    floatx4 acc[3][2];
#pragma unroll
    for (int i = 0; i < 3; i++)
#pragma unroll
        for (int j = 0; j < 2; j++) acc[i][j] = (floatx4){0.f,0.f,0.f,0.f};

    const int a_r0 = tid >> 3;
    const int a_r1 = (tid + 256) >> 3;
    const int a_r2 = (tid + 512) >> 3;
    const int a_c  = tid & 7;
    const int br = tid >> 2, bc = tid & 3;
    const size_t aro0 = (size_t)(mt*96 + a_r0)*C_;
    const size_t aro1 = (size_t)(mt*96 + a_r1)*C_;
    const size_t aro2 = (size_t)(mt*96 + a_r2)*C_;
    const size_t brow = ((size_t)tb*L_ + l0 + br)*C_;

    uint2 rA[3][3];
    uint4 rB;
#pragma unroll
    for (int p = 0; p < 3; p++) {
        const unsigned short* wp = p == 0 ? whi : p == 1 ? wmi : wlo;
        rA[p][0] = *(const uint2*)(wp + aro0 + a_c*4);
        rA[p][1] = *(const uint2*)(wp + aro1 + a_c*4);
        rA[p][2] = *(const uint2*)(wp + aro2 + a_c*4);
    }
    rB = *(const uint4*)(xT + brow + bc*8);

    for (int ck = 0; ck < C_; ck += 32) {
        {
            *(uint2*)&A_hi[a_r0][a_c*4] = rA[0][0];
            *(uint2*)&A_hi[a_r1][a_c*4] = rA[0][1];
            *(uint2*)&A_hi[a_r2][a_c*4] = rA[0][2];
            *(uint2*)&A_mi[a_r0][a_c*4] = rA[1][0];
            *(uint2*)&A_mi[a_r1][a_c*4] = rA[1][1];
            *(uint2*)&A_mi[a_r2][a_c*4] = rA[1][2];
            *(uint2*)&A_lo[a_r0][a_c*4] = rA[2][0];
            *(uint2*)&A_lo[a_r1][a_c*4] = rA[2][1];
            *(uint2*)&A_lo[a_r2][a_c*4] = rA[2][2];
        }
        *(uint4*)&B_s[br][bc*8] = rB;
        __syncthreads();
        if (ck + 32 < C_) {
            const int nk = ck + 32;
#pragma unroll
            for (int p = 0; p < 3; p++) {
                const unsigned short* wp = p == 0 ? whi : p == 1 ? wmi : wlo;
                rA[p][0] = *(const uint2*)(wp + aro0 + nk + a_c*4);
                rA[p][1] = *(const uint2*)(wp + aro1 + nk + a_c*4);
                rA[p][2] = *(const uint2*)(wp + aro2 + nk + a_c*4);
            }
            rB = *(const uint4*)(xT + brow + nk + bc*8);
        }
        short8 bb[2];
#pragma unroll
        for (int in = 0; in < 2; in++)
            bb[in] = *(short8*)&B_s[lw + in*16 + n15][q*8];
#pragma unroll
        for (int im = 0; im < 3; im++) {
            short8 ah = *(short8*)&A_hi[mw + im*16 + n15][q*8];
            short8 am = *(short8*)&A_mi[mw + im*16 + n15][q*8];
            short8 al = *(short8*)&A_lo[mw + im*16 + n15][q*8];
#pragma unroll
            for (int in = 0; in < 2; in++) {
                acc[im][in] = __builtin_amdgcn_mfma_f32_16x16x32_bf16(ah, bb[in], acc[im][in], 0,0,0);
                acc[im][in] = __builtin_amdgcn_mfma_f32_16x16x32_bf16(am, bb[in], acc[im][in], 0,0,0);
                acc[im][in] = __builtin_amdgcn_mfma_f32_16x16x32_bf16(al, bb[in], acc[im][in], 0,0,0);
            }
        }
        __syncthreads();
    }
#pragma unroll
    for (int im = 0; im < 3; im++)
#pragma unroll
        for (int r = 0; r < 4; r++) {
            int o = mt*96 + mw + im*16 + q*4 + r;
            float inv = g[o] / sqrtf(vr[o] + 1e-5f);
            float sh = be[o] - mn[o]*inv;
#pragma unroll
            for (int in = 0; in < 2; in++) {
                int l = l0 + lw + in*16 + n15;
                size_t idx = ((size_t)tb*C_ + o)*L_ + l;
                out[idx] = acc[im][in][r]*inv + sh + res[idx];
            }
        }
}

extern "C" void kernel_launch(void* const* d_in, const int* in_sizes, int n_in,
                              void* d_out, int out_size, void* d_ws, size_t ws_size,
                              hipStream_t stream) {
    const float* x   = (const float*)d_in[0];
    const float* W_w = (const float*)d_in[1];
    const float* g1  = (const float*)d_in[2];
    const float* b1  = (const float*)d_in[3];
    const float* m1  = (const float*)d_in[4];
    const float* v1  = (const float*)d_in[5];
    const float* pw  = (const float*)d_in[6];
    const float* g2  = (const float*)d_in[7];
    const float* b2  = (const float*)d_in[8];
    const float* m2  = (const float*)d_in[9];
    const float* v2  = (const float*)d_in[10];

    float* ws = (float*)d_ws;
    unsigned short* xsT  = (unsigned short*)ws;
    unsigned short* y1hi = (unsigned short*)(ws + 1572864);
    unsigned short* y1mi = (unsigned short*)(ws + 3145728);
    unsigned short* y1lo = (unsigned short*)(ws + 4718592);
    unsigned short* y2hi = (unsigned short*)(ws + 6291456);
    unsigned short* y2mi = (unsigned short*)(ws + 7864320);
    unsigned short* y2lo = (unsigned short*)(ws + 9437184);
    unsigned*       bits = (unsigned*)(ws + 11010048);
    unsigned short* wspl[3]  = {(unsigned short*)(ws + 13107200),
                                (unsigned short*)(ws + 13254656),
                                (unsigned short*)(ws + 13402112)};
    unsigned short* pwspl[3] = {(unsigned short*)(ws + 13549568),
                                (unsigned short*)(ws + 13623296),
                                (unsigned short*)(ws + 13697024)};
    unsigned short* xsF  = (unsigned short*)(ws + 13770752);
    float*          outpre  = (float*)(ws + 1572864);
    float*          outpre2 = (float*)(ws + 14557184);
    unsigned short* outsT   = (unsigned short*)(ws + 4718592);
    float* out = (float*)d_out;

    // 1) xs scan (both layouts, prefetched, 384 blocks) + weight split
    scan_and_split<<<dim3(816), 256, 0, stream>>>(x, xsT, xsF,
                                                  W_w, C2_*C_/4, wspl[0], wspl[1], wspl[2],
                                                  pw,  C_*C_/4, pwspl[0], pwspl[1], pwspl[2]);
    // 2) y = BN1(W @ xs): stride-40 LDS + uniform register prefetch
    gemm1_mfma<<<dim3(1024), 256, 0, stream>>>(wspl[0], wspl[1], wspl[2], xsT,
                                               g1, b1, m1, v1,
                                               y1hi, y1mi, y1lo, y2hi, y2mi, y2lo);
    // 3) attn spikes: LDS-free, coalesced; bits transposed layout
    attn_spike_mfma<<<dim3(2048), 256, 0, stream>>>(y1hi, y1mi, y1lo, xsF, bits);
    // 4) outpre(+outpre2) = y2 @ spikes: uniform-prefetch staging
    attn_out_mfma<<<dim3(1024), 256, 0, stream>>>(y2hi, y2mi, y2lo, bits, outpre, outpre2);
    // 5) outs spikes = scan(outpre + outpre2) -> bf16 transposed
    scan_transpose2<<<dim3(384), 256, 0, stream>>>(outpre, outpre2, outsT);
    // 6) out = BN2(proj @ outs) + x: uniform-prefetch K-loop
    gemm2_mfma<<<dim3(64, 8), 256, 0, stream>>>(pwspl[0], pwspl[1], pwspl[2], outsT,
                                                g2, b2, m2, v2, x, out);
}

// Round 13
// 188.076 us; speedup vs baseline: 1.3374x; 1.0276x over previous
//
#include <hip/hip_runtime.h>

#define T_  4
#define B_  2
#define C_  384
#define L_  1024
#define H_  8
#define C2_ 768

typedef __attribute__((ext_vector_type(8))) short short8;
typedef __attribute__((ext_vector_type(4))) float floatx4;
typedef __attribute__((ext_vector_type(16))) float floatx16;

__device__ __forceinline__ unsigned bf16_rne(float v) {
    unsigned u = __float_as_uint(v);
    u += 0x7FFFu + ((u >> 16) & 1u);
    return u >> 16;
}
__device__ __forceinline__ float bf16_to_f(unsigned h) { return __uint_as_float(h << 16); }
__device__ __forceinline__ void split3(float v, unsigned& hi, unsigned& mi, unsigned& lo) {
    hi = bf16_rne(v);
    float r1 = v - bf16_to_f(hi);
    mi = bf16_rne(r1);
    float r2 = r1 - bf16_to_f(mi);
    lo = bf16_rne(r2);
}

// ==== K1+K0: blocks 0-383 run the xs scan (64l x 32c tiles, prefetched);
// blocks 384-815 split both fp32 weight tensors into 3 bf16 planes.
__global__ __launch_bounds__(256) void scan_and_split(
    const float* __restrict__ src, unsigned short* __restrict__ dstT,
    unsigned short* __restrict__ xsF,
    const float* __restrict__ Wa, int n4a,
    unsigned short* __restrict__ hia, unsigned short* __restrict__ mia,
    unsigned short* __restrict__ loa,
    const float* __restrict__ Wb, int n4b,
    unsigned short* __restrict__ hib, unsigned short* __restrict__ mib,
    unsigned short* __restrict__ lob) {
    __shared__ unsigned short tile[32][72];
    const int tid = threadIdx.x;
    if (blockIdx.x >= 384) {
        int i = (blockIdx.x - 384) * 256 + tid;
        const float* W; unsigned short *hi, *mi, *lo;
        if (i < n4a) { W = Wa; hi = hia; mi = mia; lo = loa; }
        else {
            i -= n4a;
            if (i >= n4b) return;
            W = Wb; hi = hib; mi = mib; lo = lob;
        }
        float4 v = ((const float4*)W)[i];
        float vv[4] = {v.x, v.y, v.z, v.w};
        union { unsigned short us[4]; uint2 u2; } h, m, l;
#pragma unroll
        for (int e = 0; e < 4; e++) {
            unsigned hh, mm, ll; split3(vv[e], hh, mm, ll);
            h.us[e] = (unsigned short)hh; m.us[e] = (unsigned short)mm; l.us[e] = (unsigned short)ll;
        }
        ((uint2*)hi)[i] = h.u2; ((uint2*)mi)[i] = m.u2; ((uint2*)lo)[i] = l.u2;
        return;
    }
    // ---- scan branch: job 0..383 = l0(16) x c0(12) x b(2) ----
    const int job = blockIdx.x;
    const int l0 = (job & 15) * 64;
    const int c0 = ((job >> 4) % 12) * 32;
    const int b  = job / 192;
    const int row = tid >> 3, seg = tid & 7;     // 32 c-rows x 8 l-segs
    float mem[8], sp[8];
#pragma unroll
    for (int e = 0; e < 8; e++) { mem[e] = 0.f; sp[e] = 0.f; }
    const size_t base0 = ((size_t)(b*C_ + c0 + row))*L_ + l0 + seg*8;
    float4 nx0 = *(const float4*)(src + base0);
    float4 nx1 = *(const float4*)(src + base0 + 4);
    for (int t = 0; t < T_; t++) {
        float4 v0 = nx0, v1 = nx1;
        if (t < 3) {
            const size_t nb = ((size_t)(((t+1)*B_ + b)*C_ + c0 + row))*L_ + l0 + seg*8;
            nx0 = *(const float4*)(src + nb);
            nx1 = *(const float4*)(src + nb + 4);
        }
        float vv[8] = {v0.x,v0.y,v0.z,v0.w,v1.x,v1.y,v1.z,v1.w};
        unsigned bs[8];
#pragma unroll
        for (int e = 0; e < 8; e++) {
            mem[e] = mem[e]*0.25f*(1.f - sp[e]) + vv[e];
            bool sb = mem[e] > 0.5f;
            sp[e] = sb ? 1.f : 0.f;
            bs[e] = sb ? 0x3F80u : 0u;
        }
#pragma unroll
        for (int p2 = 0; p2 < 4; p2++)
            *(unsigned*)&tile[row][seg*8 + p2*2] = bs[p2*2] | (bs[p2*2+1] << 16);
        __syncthreads();
        {
            const int lr = tid >> 2, cs = tid & 3;   // 64 l-rows x 4 c-chunks
            unsigned wv[4];
#pragma unroll
            for (int p = 0; p < 4; p++) {
                unsigned e0 = tile[cs*8 + p*2][lr];
                unsigned e1 = tile[cs*8 + p*2 + 1][lr];
                wv[p] = e0 | (e1 << 16);
            }
            uint4 o; o.x = wv[0]; o.y = wv[1]; o.z = wv[2]; o.w = wv[3];
            const int cc = c0 + cs*8;
            *(uint4*)(dstT + ((size_t)(t*B_ + b)*L_ + l0 + lr)*C_ + cc) = o;
            const int hh = cc / 48, kc = (cc % 48) >> 3;
            *(uint4*)(xsF + ((((size_t)(t*B_ + b)*H_ + hh)*6 + kc)*L_ + l0 + lr)*8) = o;
        }
        __syncthreads();
    }
}

// ============ K5: scan over T of (outpre + outpre2) + bf16 transpose =======
__global__ __launch_bounds__(256) void scan_transpose2(
    const float* __restrict__ srcA, const float* __restrict__ srcB,
    unsigned short* __restrict__ dstT) {
    __shared__ unsigned short tile[32][72];
    const int tid = threadIdx.x;
    const int job = blockIdx.x;
    const int l0 = (job & 15) * 64;
    const int c0 = ((job >> 4) % 12) * 32;
    const int b  = job / 192;
    const int row = tid >> 3, seg = tid & 7;
    float mem[8], sp[8];
#pragma unroll
    for (int e = 0; e < 8; e++) { mem[e] = 0.f; sp[e] = 0.f; }
    const size_t base0 = ((size_t)(b*C_ + c0 + row))*L_ + l0 + seg*8;
    float4 na0 = *(const float4*)(srcA + base0);
    float4 na1 = *(const float4*)(srcA + base0 + 4);
    float4 nb0 = *(const float4*)(srcB + base0);
    float4 nb1 = *(const float4*)(srcB + base0 + 4);
    for (int t = 0; t < T_; t++) {
        float4 a0 = na0, a1 = na1, b0 = nb0, b1 = nb1;
        if (t < 3) {
            const size_t nb = ((size_t)(((t+1)*B_ + b)*C_ + c0 + row))*L_ + l0 + seg*8;
            na0 = *(const float4*)(srcA + nb);
            na1 = *(const float4*)(srcA + nb + 4);
            nb0 = *(const float4*)(srcB + nb);
            nb1 = *(const float4*)(srcB + nb + 4);
        }
        float vv[8] = {a0.x+b0.x, a0.y+b0.y, a0.z+b0.z, a0.w+b0.w,
                       a1.x+b1.x, a1.y+b1.y, a1.z+b1.z, a1.w+b1.w};
        unsigned bs[8];
#pragma unroll
        for (int e = 0; e < 8; e++) {
            mem[e] = mem[e]*0.25f*(1.f - sp[e]) + vv[e];
            bool sb = mem[e] > 0.5f;
            sp[e] = sb ? 1.f : 0.f;
            bs[e] = sb ? 0x3F80u : 0u;
        }
#pragma unroll
        for (int p2 = 0; p2 < 4; p2++)
            *(unsigned*)&tile[row][seg*8 + p2*2] = bs[p2*2] | (bs[p2*2+1] << 16);
        __syncthreads();
        {
            const int lr = tid >> 2, cs = tid & 3;
            unsigned wv[4];
#pragma unroll
            for (int p = 0; p < 4; p++) {
                unsigned e0 = tile[cs*8 + p*2][lr];
                unsigned e1 = tile[cs*8 + p*2 + 1][lr];
                wv[p] = e0 | (e1 << 16);
            }
            uint4 o; o.x = wv[0]; o.y = wv[1]; o.z = wv[2]; o.w = wv[3];
            *(uint4*)(dstT + ((size_t)(t*B_ + b)*L_ + l0 + lr)*C_ + c0 + cs*8) = o;
        }
        __syncthreads();
    }
}

// ============ K2: y = BN1(W @ xs) via MFMA, 96m x 64l tile =================
__global__ __launch_bounds__(256) void gemm1_mfma(
    const unsigned short* __restrict__ whi, const unsigned short* __restrict__ wmi,
    const unsigned short* __restrict__ wlo, const unsigned short* __restrict__ xsT,
    const float* __restrict__ g, const float* __restrict__ be,
    const float* __restrict__ mn, const float* __restrict__ vr,
    unsigned short* __restrict__ y1hi, unsigned short* __restrict__ y1mi,
    unsigned short* __restrict__ y1lo,
    unsigned short* __restrict__ y2hi, unsigned short* __restrict__ y2mi,
    unsigned short* __restrict__ y2lo) {
    __shared__ unsigned short smem[14080];   // A: 3 x 96 x 40 @ {0,3840,7680}; B: 64 x 40 @ 11520
    const int tid = threadIdx.x;
    const int flat = blockIdx.x;
    const int tb = flat & 7;
    const int ii = flat >> 3;
    const int mt = ii >> 4, lt = ii & 15;
    const int l0 = lt * 64;
    const int w = tid >> 6, lane = tid & 63;
    const int q = lane >> 4, n15 = lane & 15;
    const int mw = (w & 1) * 48, lw = (w >> 1) * 32;

    floatx4 acc[3][2];
#pragma unroll
    for (int i = 0; i < 3; i++)
#pragma unroll
        for (int j = 0; j < 2; j++) acc[i][j] = (floatx4){0.f,0.f,0.f,0.f};

    const int a_r0 = tid >> 3;
    const int a_r1 = (tid + 256) >> 3;
    const int a_r2 = (tid + 512) >> 3;
    const int a_c  = tid & 7;
    const int br = tid >> 2, bc = tid & 3;
    const size_t aro0 = (size_t)(mt*96 + a_r0)*C_;
    const size_t aro1 = (size_t)(mt*96 + a_r1)*C_;
    const size_t aro2 = (size_t)(mt*96 + a_r2)*C_;
    const size_t brow = ((size_t)tb*L_ + l0 + br)*C_;

    uint2 rA[3][3];
    uint4 rB;
#pragma unroll
    for (int p = 0; p < 3; p++) {
        const unsigned short* wp = p == 0 ? whi : p == 1 ? wmi : wlo;
        rA[p][0] = *(const uint2*)(wp + aro0 + a_c*4);
        rA[p][1] = *(const uint2*)(wp + aro1 + a_c*4);
        rA[p][2] = *(const uint2*)(wp + aro2 + a_c*4);
    }
    rB = *(const uint4*)(xsT + brow + bc*8);

    for (int ck = 0; ck < C_; ck += 32) {
#pragma unroll
        for (int p = 0; p < 3; p++) {
            unsigned short* ap = smem + p*3840;
            *(uint2*)&ap[a_r0*40 + a_c*4] = rA[p][0];
            *(uint2*)&ap[a_r1*40 + a_c*4] = rA[p][1];
            *(uint2*)&ap[a_r2*40 + a_c*4] = rA[p][2];
        }
        *(uint4*)&smem[11520 + br*40 + bc*8] = rB;
        __syncthreads();
        if (ck + 32 < C_) {
            const int nk = ck + 32;
#pragma unroll
            for (int p = 0; p < 3; p++) {
                const unsigned short* wp = p == 0 ? whi : p == 1 ? wmi : wlo;
                rA[p][0] = *(const uint2*)(wp + aro0 + nk + a_c*4);
                rA[p][1] = *(const uint2*)(wp + aro1 + nk + a_c*4);
                rA[p][2] = *(const uint2*)(wp + aro2 + nk + a_c*4);
            }
            rB = *(const uint4*)(xsT + brow + nk + bc*8);
        }
        short8 bb[2];
#pragma unroll
        for (int in = 0; in < 2; in++)
            bb[in] = *(short8*)&smem[11520 + (lw + in*16 + n15)*40 + q*8];
#pragma unroll
        for (int im = 0; im < 3; im++) {
            short8 ah = *(short8*)&smem[       (mw + im*16 + n15)*40 + q*8];
            short8 am = *(short8*)&smem[3840 + (mw + im*16 + n15)*40 + q*8];
            short8 al = *(short8*)&smem[7680 + (mw + im*16 + n15)*40 + q*8];
#pragma unroll
            for (int in = 0; in < 2; in++) {
                acc[im][in] = __builtin_amdgcn_mfma_f32_16x16x32_bf16(ah, bb[in], acc[im][in], 0,0,0);
                acc[im][in] = __builtin_amdgcn_mfma_f32_16x16x32_bf16(am, bb[in], acc[im][in], 0,0,0);
                acc[im][in] = __builtin_amdgcn_mfma_f32_16x16x32_bf16(al, bb[in], acc[im][in], 0,0,0);
            }
        }
        __syncthreads();
    }

#pragma unroll
    for (int im = 0; im < 3; im++)
#pragma unroll
        for (int r = 0; r < 4; r++) {
            int o = mt*96 + mw + im*16 + q*4 + r;
            float inv = g[o] / sqrtf(vr[o] + 1e-5f);
            float sh = be[o] - mn[o]*inv;
#pragma unroll
            for (int in = 0; in < 2; in++)
                acc[im][in][r] = acc[im][in][r]*inv + sh;
        }
    const bool isY1 = ((w & 1) == 0);
#pragma unroll
    for (int p = 0; p < 3; p++) {
        if (isY1) {
#pragma unroll
            for (int im = 0; im < 3; im++)
#pragma unroll
                for (int in = 0; in < 2; in++) {
                    union { unsigned short us[4]; uint2 u2; } pk;
#pragma unroll
                    for (int r = 0; r < 4; r++) {
                        unsigned hh = bf16_rne(acc[im][in][r]);
                        pk.us[r] = (unsigned short)hh;
                        acc[im][in][r] -= bf16_to_f(hh);
                    }
                    *(uint2*)&smem[(lw + in*16 + n15)*56 + im*16 + q*4] = pk.u2;
                }
        } else {
#pragma unroll
            for (int im = 0; im < 3; im++)
#pragma unroll
                for (int in = 0; in < 2; in++)
#pragma unroll
                    for (int r = 0; r < 4; r++) {
                        unsigned hh = bf16_rne(acc[im][in][r]);
                        smem[3584 + (im*16 + q*4 + r)*72 + lw + in*16 + n15] = (unsigned short)hh;
                        acc[im][in][r] -= bf16_to_f(hh);
                    }
        }
        __syncthreads();
        unsigned short* y1p = p == 0 ? y1hi : p == 1 ? y1mi : y1lo;
        unsigned short* y2p = p == 0 ? y2hi : p == 1 ? y2mi : y2lo;
        for (int s = tid; s < 384; s += 256) {
            int c8 = s >> 6, r1 = s & 63;
            *(uint4*)(y1p + ((((size_t)tb*H_ + mt)*6 + c8)*L_ + l0 + r1)*8) =
                *(uint4*)&smem[r1*56 + c8*8];
        }
        for (int s = tid; s < 384; s += 256) {
            int cr = s >> 3, lq = s & 7;
            *(uint4*)(y2p + ((size_t)tb*C_ + mt*48 + cr)*L_ + l0 + lq*8) =
                *(uint4*)&smem[3584 + cr*72 + lq*8];
        }
        __syncthreads();
    }
}

// ============ K3: attn = y1^T @ xr (32x32x16 MFMA, K=48) ===================
// A (y1, 3 planes) staged in LDS ONCE per block (was loaded 4x redundantly,
// once per wave: all waves share the same l-rows -> ~700MB L2 traffic).
// Uniform staging: 2304 8B-chunks = exactly 9 uint2/thread, unconditional
// defs, t+1 chunks register-prefetched under t's MFMAs. B stays direct
// per-lane (true zero reuse). bits via shfl (unchanged).
__global__ __launch_bounds__(256, 4) void attn_spike_mfma(
    const unsigned short* __restrict__ y1hi, const unsigned short* __restrict__ y1mi,
    const unsigned short* __restrict__ y1lo, const unsigned short* __restrict__ xsF,
    unsigned* __restrict__ bits) {
    __shared__ unsigned short A_s[10752];   // 3 planes x 64 l x 56 (48 + 8 pad)
    const int tid = threadIdx.x;
    const int flat = blockIdx.x;
    const int xcd = flat & 7;
    const int ii = flat >> 3;            // 0..255
    const int bh = xcd*2 + (ii >> 7);
    const int rr = ii & 127;
    const int b = bh >> 3, h = bh & 7;
    const int lbase = (rr >> 3) * 64;
    const int mbase = (rr & 7) * 128;
    const int w = tid >> 6, lane = tid & 63;
    const int l31 = lane & 31, half = lane >> 5;
    const int mrow = mbase + w*32 + l31;

    // staging chunk (p, jj): linear i = tid + jj*256 within plane (jj = j%3,
    // p = j/3 share the same i); h = i&1, dl = (i>>1)&63, kc = i>>7
    const int h0 = tid & 1;
    const int dl0 = (tid >> 1) & 63,         kc0 = tid >> 7;
    const int dl1 = ((tid + 256) >> 1) & 63, kc1 = (tid + 256) >> 7;
    const int dl2 = ((tid + 512) >> 1) & 63, kc2 = (tid + 512) >> 7;
    const int go0 = (kc0*L_ + lbase + dl0)*8 + h0*4;   // global offset (shorts, rel. plane base)
    const int go1 = (kc1*L_ + lbase + dl1)*8 + h0*4;
    const int go2 = (kc2*L_ + lbase + dl2)*8 + h0*4;
    const int ld0 = dl0*56 + kc0*8 + h0*4;             // LDS offset (shorts, rel. plane base)
    const int ld1 = dl1*56 + kc1*8 + h0*4;
    const int ld2 = dl2*56 + kc2*8 + h0*4;

    float mem[2][16];
#pragma unroll
    for (int il = 0; il < 2; il++)
#pragma unroll
        for (int r = 0; r < 16; r++) mem[il][r] = 0.f;

    // initial A prefetch (t = 0)
    uint2 pf[3][3];
    {
        const int fb0 = ((b*H_) + h)*6*L_*8;
        const unsigned short* bp0 = y1hi + fb0;
        const unsigned short* bp1 = y1mi + fb0;
        const unsigned short* bp2 = y1lo + fb0;
        pf[0][0] = *(const uint2*)(bp0 + go0); pf[0][1] = *(const uint2*)(bp0 + go1); pf[0][2] = *(const uint2*)(bp0 + go2);
        pf[1][0] = *(const uint2*)(bp1 + go0); pf[1][1] = *(const uint2*)(bp1 + go1); pf[1][2] = *(const uint2*)(bp1 + go2);
        pf[2][0] = *(const uint2*)(bp2 + go0); pf[2][1] = *(const uint2*)(bp2 + go1); pf[2][2] = *(const uint2*)(bp2 + go2);
    }

    for (int t = 0; t < T_; t++) {
        const int tb = t*B_ + b;
        const int fbt = ((tb*H_) + h)*6*L_*8;
        const unsigned short* xf = xsF + fbt;

        // B fragments first: latency overlaps LDS staging + barrier
        short8 bb[3];
#pragma unroll
        for (int ks = 0; ks < 3; ks++)
            bb[ks] = *(const short8*)(xf + ((size_t)(ks*2 + half)*L_ + mrow)*8);

        // write prefetched A chunks to LDS
        *(uint2*)&A_s[       ld0] = pf[0][0]; *(uint2*)&A_s[       ld1] = pf[0][1]; *(uint2*)&A_s[       ld2] = pf[0][2];
        *(uint2*)&A_s[3584 + ld0] = pf[1][0]; *(uint2*)&A_s[3584 + ld1] = pf[1][1]; *(uint2*)&A_s[3584 + ld2] = pf[1][2];
        *(uint2*)&A_s[7168 + ld0] = pf[2][0]; *(uint2*)&A_s[7168 + ld1] = pf[2][1]; *(uint2*)&A_s[7168 + ld2] = pf[2][2];
        __syncthreads();

        if (t < 3) {   // wave-uniform scalar guard; all pf defs unconditional
            const int fbn = (((t+1)*B_ + b)*H_ + h)*6*L_*8;
            const unsigned short* bp0 = y1hi + fbn;
            const unsigned short* bp1 = y1mi + fbn;
            const unsigned short* bp2 = y1lo + fbn;
            pf[0][0] = *(const uint2*)(bp0 + go0); pf[0][1] = *(const uint2*)(bp0 + go1); pf[0][2] = *(const uint2*)(bp0 + go2);
            pf[1][0] = *(const uint2*)(bp1 + go0); pf[1][1] = *(const uint2*)(bp1 + go1); pf[1][2] = *(const uint2*)(bp1 + go2);
            pf[2][0] = *(const uint2*)(bp2 + go0); pf[2][1] = *(const uint2*)(bp2 + go1); pf[2][2] = *(const uint2*)(bp2 + go2);
        }

        floatx16 acc[2];
#pragma unroll
        for (int il = 0; il < 2; il++)
#pragma unroll
            for (int r = 0; r < 16; r++) acc[il][r] = 0.f;

#pragma unroll
        for (int ks = 0; ks < 3; ks++) {
#pragma unroll
            for (int il = 0; il < 2; il++) {
                const int ro = (il*32 + l31)*56 + ks*16 + half*8;
                short8 ah = *(short8*)&A_s[       ro];
                short8 am = *(short8*)&A_s[3584 + ro];
                short8 al = *(short8*)&A_s[7168 + ro];
                acc[il] = __builtin_amdgcn_mfma_f32_32x32x16_bf16(ah, bb[ks], acc[il], 0,0,0);
                acc[il] = __builtin_amdgcn_mfma_f32_32x32x16_bf16(am, bb[ks], acc[il], 0,0,0);
                acc[il] = __builtin_amdgcn_mfma_f32_32x32x16_bf16(al, bb[ks], acc[il], 0,0,0);
            }
        }

        unsigned wds[2];
#pragma unroll
        for (int il = 0; il < 2; il++) {
            unsigned word = 0;
#pragma unroll
            for (int r = 0; r < 16; r++) {
                float m = (mem[il][r] > 0.5f ? 0.f : mem[il][r]*0.25f) + acc[il][r];
                mem[il][r] = m;
                int lloc = (r & 3) + 8*(r >> 2) + 4*half;
                word |= (m > 0.5f) ? (1u << lloc) : 0u;
            }
            wds[il] = word;
        }
        unsigned f0 = wds[0] | __shfl_xor(wds[0], 32);
        unsigned f1 = wds[1] | __shfl_xor(wds[1], 32);
        if (half == 0) {
            uint2 o; o.x = f0; o.y = f1;
            ((uint2*)bits)[((size_t)(tb*H_ + h)*16 + (lbase >> 6))*1024 + mrow] = o;
        }
        __syncthreads();   // protect LDS reads from next-t staging writes
    }
}

// ============ K4: outpre = y2 @ spikes, split-K over l (2 halves) ==========
__global__ __launch_bounds__(256) void attn_out_mfma(
    const unsigned short* __restrict__ y2hi, const unsigned short* __restrict__ y2mi,
    const unsigned short* __restrict__ y2lo,
    const unsigned* __restrict__ bits,
    float* __restrict__ outpre, float* __restrict__ outpre2) {
    __shared__ unsigned short A_hi[48][72], A_mi[48][72], A_lo[48][72];
    const int tid = threadIdx.x;
    const int flat = blockIdx.x;
    const int xcd = flat & 7;
    const int ii = flat >> 3;            // 0..127
    const int tbh = xcd*8 + (ii >> 4);
    const int mtile = (ii >> 1) & 7;
    const int ls = ii & 1;
    const int t = tbh >> 4, b = (tbh >> 3) & 1, h = tbh & 7;
    const int tb = t*B_ + b;
    const int w = tid >> 6, lane = tid & 63;
    const int q = lane >> 4, n15 = lane & 15;
    const int mb = mtile*128 + w*32;
    const int lt0 = ls * 512;

    floatx4 acc[3][2];
#pragma unroll
    for (int i = 0; i < 3; i++)
#pragma unroll
        for (int in = 0; in < 2; in++) acc[i][in] = (floatx4){0.f,0.f,0.f,0.f};

    const uint2* bvec = (const uint2*)bits;
    const size_t bbase = ((size_t)(tb*H_ + h)*16)*1024 + mb + n15;
    const size_t y2b = ((size_t)tb*C_ + h*48)*L_;

    const int s_r0 = tid >> 4;
    const int s_r1 = (tid + 256) >> 4;
    const int s_r2 = (tid + 512) >> 4;
    const int s_c  = tid & 15;
    const size_t ro0 = y2b + (size_t)s_r0*L_ + s_c*4;
    const size_t ro1 = y2b + (size_t)s_r1*L_ + s_c*4;
    const size_t ro2 = y2b + (size_t)s_r2*L_ + s_c*4;

    uint2 rA[3][3];
#pragma unroll
    for (int p = 0; p < 3; p++) {
        const unsigned short* yp = p == 0 ? y2hi : p == 1 ? y2mi : y2lo;
        rA[p][0] = *(const uint2*)(yp + ro0 + lt0);
        rA[p][1] = *(const uint2*)(yp + ro1 + lt0);
        rA[p][2] = *(const uint2*)(yp + ro2 + lt0);
    }

    for (int it = 0; it < 8; it++) {
        const int lt = lt0 + it*64;
        *(uint2*)&A_hi[s_r0][s_c*4] = rA[0][0];
        *(uint2*)&A_hi[s_r1][s_c*4] = rA[0][1];
        *(uint2*)&A_hi[s_r2][s_c*4] = rA[0][2];
        *(uint2*)&A_mi[s_r0][s_c*4] = rA[1][0];
        *(uint2*)&A_mi[s_r1][s_c*4] = rA[1][1];
        *(uint2*)&A_mi[s_r2][s_c*4] = rA[1][2];
        *(uint2*)&A_lo[s_r0][s_c*4] = rA[2][0];
        *(uint2*)&A_lo[s_r1][s_c*4] = rA[2][1];
        *(uint2*)&A_lo[s_r2][s_c*4] = rA[2][2];
        uint2 bw0 = bvec[bbase + (size_t)(lt >> 6)*1024];
        uint2 bw1 = bvec[bbase + (size_t)(lt >> 6)*1024 + 16];
        __syncthreads();
        if (it < 7) {
            const int nlt = lt + 64;
#pragma unroll
            for (int p = 0; p < 3; p++) {
                const unsigned short* yp = p == 0 ? y2hi : p == 1 ? y2mi : y2lo;
                rA[p][0] = *(const uint2*)(yp + ro0 + nlt);
                rA[p][1] = *(const uint2*)(yp + ro1 + nlt);
                rA[p][2] = *(const uint2*)(yp + ro2 + nlt);
            }
        }
#pragma unroll
        for (int kc = 0; kc < 2; kc++) {
            unsigned word0 = kc ? bw0.y : bw0.x;
            unsigned word1 = kc ? bw1.y : bw1.x;
            unsigned byt0 = (word0 >> (q*8)) & 0xFFu;
            unsigned byt1 = (word1 >> (q*8)) & 0xFFu;
            union { unsigned u[4]; short8 v; } bu0, bu1;
#pragma unroll
            for (int p = 0; p < 4; p++) {
                bu0.u[p] = (((byt0 >> (2*p)) & 1u) ? 0x3F80u : 0u)
                         | (((byt0 >> (2*p+1)) & 1u) ? 0x3F800000u : 0u);
                bu1.u[p] = (((byt1 >> (2*p)) & 1u) ? 0x3F80u : 0u)
                         | (((byt1 >> (2*p+1)) & 1u) ? 0x3F800000u : 0u);
            }
            short8 bf0 = bu0.v, bf1 = bu1.v;
#pragma unroll
            for (int i = 0; i < 3; i++) {
                int ra = i*16 + n15;
                short8 ah = *(short8*)&A_hi[ra][kc*32 + q*8];
                short8 am = *(short8*)&A_mi[ra][kc*32 + q*8];
                short8 al = *(short8*)&A_lo[ra][kc*32 + q*8];
                acc[i][0] = __builtin_amdgcn_mfma_f32_16x16x32_bf16(ah, bf0, acc[i][0], 0,0,0);
                acc[i][0] = __builtin_amdgcn_mfma_f32_16x16x32_bf16(am, bf0, acc[i][0], 0,0,0);
                acc[i][0] = __builtin_amdgcn_mfma_f32_16x16x32_bf16(al, bf0, acc[i][0], 0,0,0);
                acc[i][1] = __builtin_amdgcn_mfma_f32_16x16x32_bf16(ah, bf1, acc[i][1], 0,0,0);
                acc[i][1] = __builtin_amdgcn_mfma_f32_16x16x32_bf16(am, bf1, acc[i][1], 0,0,0);
                acc[i][1] = __builtin_amdgcn_mfma_f32_16x16x32_bf16(al, bf1, acc[i][1], 0,0,0);
            }
        }
        __syncthreads();
    }
    float* outP = ls ? outpre2 : outpre;
#pragma unroll
    for (int i = 0; i < 3; i++)
#pragma unroll
        for (int r = 0; r < 4; r++) {
            int d = i*16 + q*4 + r;
#pragma unroll
            for (int in = 0; in < 2; in++)
                outP[((size_t)tb*C_ + h*48 + d)*L_ + mb + in*16 + n15] = acc[i][in][r];
        }
}

// ============ K6: out = BN2(proj @ outs) + x (MFMA, 96x64 tile) ============
__global__ __launch_bounds__(256) void gemm2_mfma(
    const unsigned short* __restrict__ whi, const unsigned short* __restrict__ wmi,
    const unsigned short* __restrict__ wlo, const unsigned short* __restrict__ xT,
    const float* __restrict__ g, const float* __restrict__ be,
    const float* __restrict__ mn, const float* __restrict__ vr,
    const float* __restrict__ res, float* __restrict__ out) {
    __shared__ unsigned short A_hi[96][40], A_mi[96][40], A_lo[96][40];
    __shared__ unsigned short B_s[64][40];
    const int tid = threadIdx.x;
    const int tb = blockIdx.y;
    const int mt = blockIdx.x >> 4, lt = blockIdx.x & 15;
    const int l0 = lt * 64;
    const int w = tid >> 6, lane = tid & 63;
    const int q = lane >> 4, n15 = lane & 15;
    const int mw = (w & 1) * 48, lw = (w >> 1) * 32;

    floatx4 acc[3][2];
#pragma unroll
    for (int i = 0; i < 3; i++)
#pragma unroll
        for (int j = 0; j < 2; j++) acc[i][j] = (floatx4){0.f,0.f,0.f,0.f};

    const int a_r0 = tid >> 3;
    const int a_r1 = (tid + 256) >> 3;
    const int a_r2 = (tid + 512) >> 3;
    const int a_c  = tid & 7;
    const int br = tid >> 2, bc = tid & 3;
    const size_t aro0 = (size_t)(mt*96 + a_r0)*C_;
    const size_t aro1 = (size_t)(mt*96 + a_r1)*C_;
    const size_t aro2 = (size_t)(mt*96 + a_r2)*C_;
    const size_t brow = ((size_t)tb*L_ + l0 + br)*C_;

    uint2 rA[3][3];
    uint4 rB;
#pragma unroll
    for (int p = 0; p < 3; p++) {
        const unsigned short* wp = p == 0 ? whi : p == 1 ? wmi : wlo;
        rA[p][0] = *(const uint2*)(wp + aro0 + a_c*4);
        rA[p][1] = *(const uint2*)(wp + aro1 + a_c*4);
        rA[p][2] = *(const uint2*)(wp + aro2 + a_c*4);
    }
    rB = *(const uint4*)(xT + brow + bc*8);

    for (int ck = 0; ck < C_; ck += 32) {
        {
            *(uint2*)&A_hi[a_r0][a_c*4] = rA[0][0];
            *(uint2*)&A_hi[a_r1][a_c*4] = rA[0][1];
            *(uint2*)&A_hi[a_r2][a_c*4] = rA[0][2];
            *(uint2*)&A_mi[a_r0][a_c*4] = rA[1][0];
            *(uint2*)&A_mi[a_r1][a_c*4] = rA[1][1];
            *(uint2*)&A_mi[a_r2][a_c*4] = rA[1][2];
            *(uint2*)&A_lo[a_r0][a_c*4] = rA[2][0];
            *(uint2*)&A_lo[a_r1][a_c*4] = rA[2][1];
            *(uint2*)&A_lo[a_r2][a_c*4] = rA[2][2];
        }
        *(uint4*)&B_s[br][bc*8] = rB;
        __syncthreads();
        if (ck + 32 < C_) {
            const int nk = ck + 32;
#pragma unroll
            for (int p = 0; p < 3; p++) {
                const unsigned short* wp = p == 0 ? whi : p == 1 ? wmi : wlo;
                rA[p][0] = *(const uint2*)(wp + aro0 + nk + a_c*4);
                rA[p][1] = *(const uint2*)(wp + aro1 + nk + a_c*4);
                rA[p][2] = *(const uint2*)(wp + aro2 + nk + a_c*4);
            }
            rB = *(const uint4*)(xT + brow + nk + bc*8);
        }
        short8 bb[2];
#pragma unroll
        for (int in = 0; in < 2; in++)
            bb[in] = *(short8*)&B_s[lw + in*16 + n15][q*8];
#pragma unroll
        for (int im = 0; im < 3; im++) {
            short8 ah = *(short8*)&A_hi[mw + im*16 + n15][q*8];
            short8 am = *(short8*)&A_mi[mw + im*16 + n15][q*8];
            short8 al = *(short8*)&A_lo[mw + im*16 + n15][q*8];
#pragma unroll
            for (int in = 0; in < 2; in++) {
                acc[im][in] = __builtin_amdgcn_mfma_f32_16x16x32_bf16(ah, bb[in], acc[im][in], 0,0,0);
                acc[im][in] = __builtin_amdgcn_mfma_f32_16x16x32_bf16(am, bb[in], acc[im][in], 0,0,0);
                acc[im][in] = __builtin_amdgcn_mfma_f32_16x16x32_bf16(al, bb[in], acc[im][in], 0,0,0);
            }
        }
        __syncthreads();
    }
#pragma unroll
    for (int im = 0; im < 3; im++)
#pragma unroll
        for (int r = 0; r < 4; r++) {
            int o = mt*96 + mw + im*16 + q*4 + r;
            float inv = g[o] / sqrtf(vr[o] + 1e-5f);
            float sh = be[o] - mn[o]*inv;
#pragma unroll
            for (int in = 0; in < 2; in++) {
                int l = l0 + lw + in*16 + n15;
                size_t idx = ((size_t)tb*C_ + o)*L_ + l;
                out[idx] = acc[im][in][r]*inv + sh + res[idx];
            }
        }
}

extern "C" void kernel_launch(void* const* d_in, const int* in_sizes, int n_in,
                              void* d_out, int out_size, void* d_ws, size_t ws_size,
                              hipStream_t stream) {
    const float* x   = (const float*)d_in[0];
    const float* W_w = (const float*)d_in[1];
    const float* g1  = (const float*)d_in[2];
    const float* b1  = (const float*)d_in[3];
    const float* m1  = (const float*)d_in[4];
    const float* v1  = (const float*)d_in[5];
    const float* pw  = (const float*)d_in[6];
    const float* g2  = (const float*)d_in[7];
    const float* b2  = (const float*)d_in[8];
    const float* m2  = (const float*)d_in[9];
    const float* v2  = (const float*)d_in[10];

    float* ws = (float*)d_ws;
    unsigned short* xsT  = (unsigned short*)ws;
    unsigned short* y1hi = (unsigned short*)(ws + 1572864);
    unsigned short* y1mi = (unsigned short*)(ws + 3145728);
    unsigned short* y1lo = (unsigned short*)(ws + 4718592);
    unsigned short* y2hi = (unsigned short*)(ws + 6291456);
    unsigned short* y2mi = (unsigned short*)(ws + 7864320);
    unsigned short* y2lo = (unsigned short*)(ws + 9437184);
    unsigned*       bits = (unsigned*)(ws + 11010048);
    unsigned short* wspl[3]  = {(unsigned short*)(ws + 13107200),
                                (unsigned short*)(ws + 13254656),
                                (unsigned short*)(ws + 13402112)};
    unsigned short* pwspl[3] = {(unsigned short*)(ws + 13549568),
                                (unsigned short*)(ws + 13623296),
                                (unsigned short*)(ws + 13697024)};
    unsigned short* xsF  = (unsigned short*)(ws + 13770752);
    float*          outpre  = (float*)(ws + 1572864);
    float*          outpre2 = (float*)(ws + 14557184);
    unsigned short* outsT   = (unsigned short*)(ws + 4718592);
    float* out = (float*)d_out;

    // 1) xs scan (both layouts, prefetched, 384 blocks) + weight split
    scan_and_split<<<dim3(816), 256, 0, stream>>>(x, xsT, xsF,
                                                  W_w, C2_*C_/4, wspl[0], wspl[1], wspl[2],
                                                  pw,  C_*C_/4, pwspl[0], pwspl[1], pwspl[2]);
    // 2) y = BN1(W @ xs): stride-40 LDS + uniform register prefetch
    gemm1_mfma<<<dim3(1024), 256, 0, stream>>>(wspl[0], wspl[1], wspl[2], xsT,
                                               g1, b1, m1, v1,
                                               y1hi, y1mi, y1lo, y2hi, y2mi, y2lo);
    // 3) attn spikes: LDS-staged A (shared across waves), prefetched; B direct
    attn_spike_mfma<<<dim3(2048), 256, 0, stream>>>(y1hi, y1mi, y1lo, xsF, bits);
    // 4) outpre(+outpre2) = y2 @ spikes: uniform-prefetch staging
    attn_out_mfma<<<dim3(1024), 256, 0, stream>>>(y2hi, y2mi, y2lo, bits, outpre, outpre2);
    // 5) outs spikes = scan(outpre + outpre2) -> bf16 transposed
    scan_transpose2<<<dim3(384), 256, 0, stream>>>(outpre, outpre2, outsT);
    // 6) out = BN2(proj @ outs) + x: uniform-prefetch K-loop
    gemm2_mfma<<<dim3(64, 8), 256, 0, stream>>>(pwspl[0], pwspl[1], pwspl[2], outsT,
                                                g2, b2, m2, v2, x, out);
}

// Round 14
// 185.286 us; speedup vs baseline: 1.3575x; 1.0151x over previous
//
#include <hip/hip_runtime.h>

#define T_  4
#define B_  2
#define C_  384
#define L_  1024
#define H_  8
#define C2_ 768

typedef __attribute__((ext_vector_type(8))) short short8;
typedef __attribute__((ext_vector_type(4))) float floatx4;
typedef __attribute__((ext_vector_type(16))) float floatx16;

__device__ __forceinline__ unsigned bf16_rne(float v) {
    unsigned u = __float_as_uint(v);
    u += 0x7FFFu + ((u >> 16) & 1u);
    return u >> 16;
}
__device__ __forceinline__ float bf16_to_f(unsigned h) { return __uint_as_float(h << 16); }
__device__ __forceinline__ void split3(float v, unsigned& hi, unsigned& mi, unsigned& lo) {
    hi = bf16_rne(v);
    float r1 = v - bf16_to_f(hi);
    mi = bf16_rne(r1);
    float r2 = r1 - bf16_to_f(mi);
    lo = bf16_rne(r2);
}

// ==== K1+K0: blocks 0-383 run the xs scan (64l x 32c tiles, prefetched);
// blocks 384-815 split both fp32 weight tensors into 3 bf16 planes.
__global__ __launch_bounds__(256) void scan_and_split(
    const float* __restrict__ src, unsigned short* __restrict__ dstT,
    unsigned short* __restrict__ xsF,
    const float* __restrict__ Wa, int n4a,
    unsigned short* __restrict__ hia, unsigned short* __restrict__ mia,
    unsigned short* __restrict__ loa,
    const float* __restrict__ Wb, int n4b,
    unsigned short* __restrict__ hib, unsigned short* __restrict__ mib,
    unsigned short* __restrict__ lob) {
    __shared__ unsigned short tile[32][72];
    const int tid = threadIdx.x;
    if (blockIdx.x >= 384) {
        int i = (blockIdx.x - 384) * 256 + tid;
        const float* W; unsigned short *hi, *mi, *lo;
        if (i < n4a) { W = Wa; hi = hia; mi = mia; lo = loa; }
        else {
            i -= n4a;
            if (i >= n4b) return;
            W = Wb; hi = hib; mi = mib; lo = lob;
        }
        float4 v = ((const float4*)W)[i];
        float vv[4] = {v.x, v.y, v.z, v.w};
        union { unsigned short us[4]; uint2 u2; } h, m, l;
#pragma unroll
        for (int e = 0; e < 4; e++) {
            unsigned hh, mm, ll; split3(vv[e], hh, mm, ll);
            h.us[e] = (unsigned short)hh; m.us[e] = (unsigned short)mm; l.us[e] = (unsigned short)ll;
        }
        ((uint2*)hi)[i] = h.u2; ((uint2*)mi)[i] = m.u2; ((uint2*)lo)[i] = l.u2;
        return;
    }
    // ---- scan branch: job 0..383 = l0(16) x c0(12) x b(2) ----
    const int job = blockIdx.x;
    const int l0 = (job & 15) * 64;
    const int c0 = ((job >> 4) % 12) * 32;
    const int b  = job / 192;
    const int row = tid >> 3, seg = tid & 7;     // 32 c-rows x 8 l-segs
    float mem[8], sp[8];
#pragma unroll
    for (int e = 0; e < 8; e++) { mem[e] = 0.f; sp[e] = 0.f; }
    const size_t base0 = ((size_t)(b*C_ + c0 + row))*L_ + l0 + seg*8;
    float4 nx0 = *(const float4*)(src + base0);
    float4 nx1 = *(const float4*)(src + base0 + 4);
    for (int t = 0; t < T_; t++) {
        float4 v0 = nx0, v1 = nx1;
        if (t < 3) {
            const size_t nb = ((size_t)(((t+1)*B_ + b)*C_ + c0 + row))*L_ + l0 + seg*8;
            nx0 = *(const float4*)(src + nb);
            nx1 = *(const float4*)(src + nb + 4);
        }
        float vv[8] = {v0.x,v0.y,v0.z,v0.w,v1.x,v1.y,v1.z,v1.w};
        unsigned bs[8];
#pragma unroll
        for (int e = 0; e < 8; e++) {
            mem[e] = mem[e]*0.25f*(1.f - sp[e]) + vv[e];
            bool sb = mem[e] > 0.5f;
            sp[e] = sb ? 1.f : 0.f;
            bs[e] = sb ? 0x3F80u : 0u;
        }
#pragma unroll
        for (int p2 = 0; p2 < 4; p2++)
            *(unsigned*)&tile[row][seg*8 + p2*2] = bs[p2*2] | (bs[p2*2+1] << 16);
        __syncthreads();
        {
            const int lr = tid >> 2, cs = tid & 3;   // 64 l-rows x 4 c-chunks
            unsigned wv[4];
#pragma unroll
            for (int p = 0; p < 4; p++) {
                unsigned e0 = tile[cs*8 + p*2][lr];
                unsigned e1 = tile[cs*8 + p*2 + 1][lr];
                wv[p] = e0 | (e1 << 16);
            }
            uint4 o; o.x = wv[0]; o.y = wv[1]; o.z = wv[2]; o.w = wv[3];
            const int cc = c0 + cs*8;
            *(uint4*)(dstT + ((size_t)(t*B_ + b)*L_ + l0 + lr)*C_ + cc) = o;
            const int hh = cc / 48, kc = (cc % 48) >> 3;
            *(uint4*)(xsF + ((((size_t)(t*B_ + b)*H_ + hh)*6 + kc)*L_ + l0 + lr)*8) = o;
        }
        __syncthreads();
    }
}

// ============ K5: scan over T of (p1+p2+p3+p4) + bf16 transpose ============
// 4 fp32 partial streams (K4's 4-way split-K), next-t loads prefetched.
__global__ __launch_bounds__(256) void scan_transpose4(
    const float* __restrict__ sA, const float* __restrict__ sB,
    const float* __restrict__ sC, const float* __restrict__ sD,
    unsigned short* __restrict__ dstT) {
    __shared__ unsigned short tile[32][72];
    const int tid = threadIdx.x;
    const int job = blockIdx.x;
    const int l0 = (job & 15) * 64;
    const int c0 = ((job >> 4) % 12) * 32;
    const int b  = job / 192;
    const int row = tid >> 3, seg = tid & 7;
    float mem[8], sp[8];
#pragma unroll
    for (int e = 0; e < 8; e++) { mem[e] = 0.f; sp[e] = 0.f; }
    const size_t base0 = ((size_t)(b*C_ + c0 + row))*L_ + l0 + seg*8;
    float4 na0 = *(const float4*)(sA + base0), na1 = *(const float4*)(sA + base0 + 4);
    float4 nb0 = *(const float4*)(sB + base0), nb1 = *(const float4*)(sB + base0 + 4);
    float4 nc0 = *(const float4*)(sC + base0), nc1 = *(const float4*)(sC + base0 + 4);
    float4 nd0 = *(const float4*)(sD + base0), nd1 = *(const float4*)(sD + base0 + 4);
    for (int t = 0; t < T_; t++) {
        float4 a0 = na0, a1 = na1, b0 = nb0, b1 = nb1;
        float4 c0v = nc0, c1 = nc1, d0 = nd0, d1 = nd1;
        if (t < 3) {
            const size_t nb = ((size_t)(((t+1)*B_ + b)*C_ + c0 + row))*L_ + l0 + seg*8;
            na0 = *(const float4*)(sA + nb); na1 = *(const float4*)(sA + nb + 4);
            nb0 = *(const float4*)(sB + nb); nb1 = *(const float4*)(sB + nb + 4);
            nc0 = *(const float4*)(sC + nb); nc1 = *(const float4*)(sC + nb + 4);
            nd0 = *(const float4*)(sD + nb); nd1 = *(const float4*)(sD + nb + 4);
        }
        float vv[8] = {a0.x+b0.x+c0v.x+d0.x, a0.y+b0.y+c0v.y+d0.y,
                       a0.z+b0.z+c0v.z+d0.z, a0.w+b0.w+c0v.w+d0.w,
                       a1.x+b1.x+c1.x+d1.x, a1.y+b1.y+c1.y+d1.y,
                       a1.z+b1.z+c1.z+d1.z, a1.w+b1.w+c1.w+d1.w};
        unsigned bs[8];
#pragma unroll
        for (int e = 0; e < 8; e++) {
            mem[e] = mem[e]*0.25f*(1.f - sp[e]) + vv[e];
            bool sb = mem[e] > 0.5f;
            sp[e] = sb ? 1.f : 0.f;
            bs[e] = sb ? 0x3F80u : 0u;
        }
#pragma unroll
        for (int p2 = 0; p2 < 4; p2++)
            *(unsigned*)&tile[row][seg*8 + p2*2] = bs[p2*2] | (bs[p2*2+1] << 16);
        __syncthreads();
        {
            const int lr = tid >> 2, cs = tid & 3;
            unsigned wv[4];
#pragma unroll
            for (int p = 0; p < 4; p++) {
                unsigned e0 = tile[cs*8 + p*2][lr];
                unsigned e1 = tile[cs*8 + p*2 + 1][lr];
                wv[p] = e0 | (e1 << 16);
            }
            uint4 o; o.x = wv[0]; o.y = wv[1]; o.z = wv[2]; o.w = wv[3];
            *(uint4*)(dstT + ((size_t)(t*B_ + b)*L_ + l0 + lr)*C_ + c0 + cs*8) = o;
        }
        __syncthreads();
    }
}

// ============ K2: y = BN1(W @ xs) via MFMA, 96m x 64l tile =================
__global__ __launch_bounds__(256) void gemm1_mfma(
    const unsigned short* __restrict__ whi, const unsigned short* __restrict__ wmi,
    const unsigned short* __restrict__ wlo, const unsigned short* __restrict__ xsT,
    const float* __restrict__ g, const float* __restrict__ be,
    const float* __restrict__ mn, const float* __restrict__ vr,
    unsigned short* __restrict__ y1hi, unsigned short* __restrict__ y1mi,
    unsigned short* __restrict__ y1lo,
    unsigned short* __restrict__ y2hi, unsigned short* __restrict__ y2mi,
    unsigned short* __restrict__ y2lo) {
    __shared__ unsigned short smem[14080];   // A: 3 x 96 x 40 @ {0,3840,7680}; B: 64 x 40 @ 11520
    const int tid = threadIdx.x;
    const int flat = blockIdx.x;
    const int tb = flat & 7;
    const int ii = flat >> 3;
    const int mt = ii >> 4, lt = ii & 15;
    const int l0 = lt * 64;
    const int w = tid >> 6, lane = tid & 63;
    const int q = lane >> 4, n15 = lane & 15;
    const int mw = (w & 1) * 48, lw = (w >> 1) * 32;

    floatx4 acc[3][2];
#pragma unroll
    for (int i = 0; i < 3; i++)
#pragma unroll
        for (int j = 0; j < 2; j++) acc[i][j] = (floatx4){0.f,0.f,0.f,0.f};

    const int a_r0 = tid >> 3;
    const int a_r1 = (tid + 256) >> 3;
    const int a_r2 = (tid + 512) >> 3;
    const int a_c  = tid & 7;
    const int br = tid >> 2, bc = tid & 3;
    const size_t aro0 = (size_t)(mt*96 + a_r0)*C_;
    const size_t aro1 = (size_t)(mt*96 + a_r1)*C_;
    const size_t aro2 = (size_t)(mt*96 + a_r2)*C_;
    const size_t brow = ((size_t)tb*L_ + l0 + br)*C_;

    uint2 rA[3][3];
    uint4 rB;
#pragma unroll
    for (int p = 0; p < 3; p++) {
        const unsigned short* wp = p == 0 ? whi : p == 1 ? wmi : wlo;
        rA[p][0] = *(const uint2*)(wp + aro0 + a_c*4);
        rA[p][1] = *(const uint2*)(wp + aro1 + a_c*4);
        rA[p][2] = *(const uint2*)(wp + aro2 + a_c*4);
    }
    rB = *(const uint4*)(xsT + brow + bc*8);

    for (int ck = 0; ck < C_; ck += 32) {
#pragma unroll
        for (int p = 0; p < 3; p++) {
            unsigned short* ap = smem + p*3840;
            *(uint2*)&ap[a_r0*40 + a_c*4] = rA[p][0];
            *(uint2*)&ap[a_r1*40 + a_c*4] = rA[p][1];
            *(uint2*)&ap[a_r2*40 + a_c*4] = rA[p][2];
        }
        *(uint4*)&smem[11520 + br*40 + bc*8] = rB;
        __syncthreads();
        if (ck + 32 < C_) {
            const int nk = ck + 32;
#pragma unroll
            for (int p = 0; p < 3; p++) {
                const unsigned short* wp = p == 0 ? whi : p == 1 ? wmi : wlo;
                rA[p][0] = *(const uint2*)(wp + aro0 + nk + a_c*4);
                rA[p][1] = *(const uint2*)(wp + aro1 + nk + a_c*4);
                rA[p][2] = *(const uint2*)(wp + aro2 + nk + a_c*4);
            }
            rB = *(const uint4*)(xsT + brow + nk + bc*8);
        }
        short8 bb[2];
#pragma unroll
        for (int in = 0; in < 2; in++)
            bb[in] = *(short8*)&smem[11520 + (lw + in*16 + n15)*40 + q*8];
#pragma unroll
        for (int im = 0; im < 3; im++) {
            short8 ah = *(short8*)&smem[       (mw + im*16 + n15)*40 + q*8];
            short8 am = *(short8*)&smem[3840 + (mw + im*16 + n15)*40 + q*8];
            short8 al = *(short8*)&smem[7680 + (mw + im*16 + n15)*40 + q*8];
#pragma unroll
            for (int in = 0; in < 2; in++) {
                acc[im][in] = __builtin_amdgcn_mfma_f32_16x16x32_bf16(ah, bb[in], acc[im][in], 0,0,0);
                acc[im][in] = __builtin_amdgcn_mfma_f32_16x16x32_bf16(am, bb[in], acc[im][in], 0,0,0);
                acc[im][in] = __builtin_amdgcn_mfma_f32_16x16x32_bf16(al, bb[in], acc[im][in], 0,0,0);
            }
        }
        __syncthreads();
    }

#pragma unroll
    for (int im = 0; im < 3; im++)
#pragma unroll
        for (int r = 0; r < 4; r++) {
            int o = mt*96 + mw + im*16 + q*4 + r;
            float inv = g[o] / sqrtf(vr[o] + 1e-5f);
            float sh = be[o] - mn[o]*inv;
#pragma unroll
            for (int in = 0; in < 2; in++)
                acc[im][in][r] = acc[im][in][r]*inv + sh;
        }
    const bool isY1 = ((w & 1) == 0);
#pragma unroll
    for (int p = 0; p < 3; p++) {
        if (isY1) {
#pragma unroll
            for (int im = 0; im < 3; im++)
#pragma unroll
                for (int in = 0; in < 2; in++) {
                    union { unsigned short us[4]; uint2 u2; } pk;
#pragma unroll
                    for (int r = 0; r < 4; r++) {
                        unsigned hh = bf16_rne(acc[im][in][r]);
                        pk.us[r] = (unsigned short)hh;
                        acc[im][in][r] -= bf16_to_f(hh);
                    }
                    *(uint2*)&smem[(lw + in*16 + n15)*56 + im*16 + q*4] = pk.u2;
                }
        } else {
#pragma unroll
            for (int im = 0; im < 3; im++)
#pragma unroll
                for (int in = 0; in < 2; in++)
#pragma unroll
                    for (int r = 0; r < 4; r++) {
                        unsigned hh = bf16_rne(acc[im][in][r]);
                        smem[3584 + (im*16 + q*4 + r)*72 + lw + in*16 + n15] = (unsigned short)hh;
                        acc[im][in][r] -= bf16_to_f(hh);
                    }
        }
        __syncthreads();
        unsigned short* y1p = p == 0 ? y1hi : p == 1 ? y1mi : y1lo;
        unsigned short* y2p = p == 0 ? y2hi : p == 1 ? y2mi : y2lo;
        for (int s = tid; s < 384; s += 256) {
            int c8 = s >> 6, r1 = s & 63;
            *(uint4*)(y1p + ((((size_t)tb*H_ + mt)*6 + c8)*L_ + l0 + r1)*8) =
                *(uint4*)&smem[r1*56 + c8*8];
        }
        for (int s = tid; s < 384; s += 256) {
            int cr = s >> 3, lq = s & 7;
            *(uint4*)(y2p + ((size_t)tb*C_ + mt*48 + cr)*L_ + l0 + lq*8) =
                *(uint4*)&smem[3584 + cr*72 + lq*8];
        }
        __syncthreads();
    }
}

// ============ K3: attn = y1^T @ xr (32x32x16 MFMA, K=48) ===================
// A (y1, 3 planes) staged in LDS once per block, uniform register prefetch.
__global__ __launch_bounds__(256, 4) void attn_spike_mfma(
    const unsigned short* __restrict__ y1hi, const unsigned short* __restrict__ y1mi,
    const unsigned short* __restrict__ y1lo, const unsigned short* __restrict__ xsF,
    unsigned* __restrict__ bits) {
    __shared__ unsigned short A_s[10752];   // 3 planes x 64 l x 56 (48 + 8 pad)
    const int tid = threadIdx.x;
    const int flat = blockIdx.x;
    const int xcd = flat & 7;
    const int ii = flat >> 3;            // 0..255
    const int bh = xcd*2 + (ii >> 7);
    const int rr = ii & 127;
    const int b = bh >> 3, h = bh & 7;
    const int lbase = (rr >> 3) * 64;
    const int mbase = (rr & 7) * 128;
    const int w = tid >> 6, lane = tid & 63;
    const int l31 = lane & 31, half = lane >> 5;
    const int mrow = mbase + w*32 + l31;

    const int h0 = tid & 1;
    const int dl0 = (tid >> 1) & 63,         kc0 = tid >> 7;
    const int dl1 = ((tid + 256) >> 1) & 63, kc1 = (tid + 256) >> 7;
    const int dl2 = ((tid + 512) >> 1) & 63, kc2 = (tid + 512) >> 7;
    const int go0 = (kc0*L_ + lbase + dl0)*8 + h0*4;
    const int go1 = (kc1*L_ + lbase + dl1)*8 + h0*4;
    const int go2 = (kc2*L_ + lbase + dl2)*8 + h0*4;
    const int ld0 = dl0*56 + kc0*8 + h0*4;
    const int ld1 = dl1*56 + kc1*8 + h0*4;
    const int ld2 = dl2*56 + kc2*8 + h0*4;

    float mem[2][16];
#pragma unroll
    for (int il = 0; il < 2; il++)
#pragma unroll
        for (int r = 0; r < 16; r++) mem[il][r] = 0.f;

    uint2 pf[3][3];
    {
        const int fb0 = ((b*H_) + h)*6*L_*8;
        const unsigned short* bp0 = y1hi + fb0;
        const unsigned short* bp1 = y1mi + fb0;
        const unsigned short* bp2 = y1lo + fb0;
        pf[0][0] = *(const uint2*)(bp0 + go0); pf[0][1] = *(const uint2*)(bp0 + go1); pf[0][2] = *(const uint2*)(bp0 + go2);
        pf[1][0] = *(const uint2*)(bp1 + go0); pf[1][1] = *(const uint2*)(bp1 + go1); pf[1][2] = *(const uint2*)(bp1 + go2);
        pf[2][0] = *(const uint2*)(bp2 + go0); pf[2][1] = *(const uint2*)(bp2 + go1); pf[2][2] = *(const uint2*)(bp2 + go2);
    }

    for (int t = 0; t < T_; t++) {
        const int tb = t*B_ + b;
        const int fbt = ((tb*H_) + h)*6*L_*8;
        const unsigned short* xf = xsF + fbt;

        short8 bb[3];
#pragma unroll
        for (int ks = 0; ks < 3; ks++)
            bb[ks] = *(const short8*)(xf + ((size_t)(ks*2 + half)*L_ + mrow)*8);

        *(uint2*)&A_s[       ld0] = pf[0][0]; *(uint2*)&A_s[       ld1] = pf[0][1]; *(uint2*)&A_s[       ld2] = pf[0][2];
        *(uint2*)&A_s[3584 + ld0] = pf[1][0]; *(uint2*)&A_s[3584 + ld1] = pf[1][1]; *(uint2*)&A_s[3584 + ld2] = pf[1][2];
        *(uint2*)&A_s[7168 + ld0] = pf[2][0]; *(uint2*)&A_s[7168 + ld1] = pf[2][1]; *(uint2*)&A_s[7168 + ld2] = pf[2][2];
        __syncthreads();

        if (t < 3) {
            const int fbn = (((t+1)*B_ + b)*H_ + h)*6*L_*8;
            const unsigned short* bp0 = y1hi + fbn;
            const unsigned short* bp1 = y1mi + fbn;
            const unsigned short* bp2 = y1lo + fbn;
            pf[0][0] = *(const uint2*)(bp0 + go0); pf[0][1] = *(const uint2*)(bp0 + go1); pf[0][2] = *(const uint2*)(bp0 + go2);
            pf[1][0] = *(const uint2*)(bp1 + go0); pf[1][1] = *(const uint2*)(bp1 + go1); pf[1][2] = *(const uint2*)(bp1 + go2);
            pf[2][0] = *(const uint2*)(bp2 + go0); pf[2][1] = *(const uint2*)(bp2 + go1); pf[2][2] = *(const uint2*)(bp2 + go2);
        }

        floatx16 acc[2];
#pragma unroll
        for (int il = 0; il < 2; il++)
#pragma unroll
            for (int r = 0; r < 16; r++) acc[il][r] = 0.f;

#pragma unroll
        for (int ks = 0; ks < 3; ks++) {
#pragma unroll
            for (int il = 0; il < 2; il++) {
                const int ro = (il*32 + l31)*56 + ks*16 + half*8;
                short8 ah = *(short8*)&A_s[       ro];
                short8 am = *(short8*)&A_s[3584 + ro];
                short8 al = *(short8*)&A_s[7168 + ro];
                acc[il] = __builtin_amdgcn_mfma_f32_32x32x16_bf16(ah, bb[ks], acc[il], 0,0,0);
                acc[il] = __builtin_amdgcn_mfma_f32_32x32x16_bf16(am, bb[ks], acc[il], 0,0,0);
                acc[il] = __builtin_amdgcn_mfma_f32_32x32x16_bf16(al, bb[ks], acc[il], 0,0,0);
            }
        }

        unsigned wds[2];
#pragma unroll
        for (int il = 0; il < 2; il++) {
            unsigned word = 0;
#pragma unroll
            for (int r = 0; r < 16; r++) {
                float m = (mem[il][r] > 0.5f ? 0.f : mem[il][r]*0.25f) + acc[il][r];
                mem[il][r] = m;
                int lloc = (r & 3) + 8*(r >> 2) + 4*half;
                word |= (m > 0.5f) ? (1u << lloc) : 0u;
            }
            wds[il] = word;
        }
        unsigned f0 = wds[0] | __shfl_xor(wds[0], 32);
        unsigned f1 = wds[1] | __shfl_xor(wds[1], 32);
        if (half == 0) {
            uint2 o; o.x = f0; o.y = f1;
            ((uint2*)bits)[((size_t)(tb*H_ + h)*16 + (lbase >> 6))*1024 + mrow] = o;
        }
        __syncthreads();
    }
}

// ============ K4: outpre = y2 @ spikes, 4-way split-K over l ===============
// grid 2048 (7 blocks/CU by LDS): 2x resident waves, 4 serial iterations.
// Uniform-prefetch staging (all regs unconditionally defined).
__global__ __launch_bounds__(256) void attn_out_mfma(
    const unsigned short* __restrict__ y2hi, const unsigned short* __restrict__ y2mi,
    const unsigned short* __restrict__ y2lo,
    const unsigned* __restrict__ bits,
    float* __restrict__ op0, float* __restrict__ op1,
    float* __restrict__ op2, float* __restrict__ op3) {
    __shared__ unsigned short A_hi[48][72], A_mi[48][72], A_lo[48][72];
    const int tid = threadIdx.x;
    const int flat = blockIdx.x;
    const int xcd = flat & 7;
    const int ii = flat >> 3;            // 0..255
    const int tbh = xcd*8 + (ii >> 5);   // 0..63 (panel-sharers stay on one XCD)
    const int r5 = ii & 31;
    const int mtile = r5 >> 2;           // 0..7
    const int ls = r5 & 3;               // 0..3
    const int t = tbh >> 4, b = (tbh >> 3) & 1, h = tbh & 7;
    const int tb = t*B_ + b;
    const int w = tid >> 6, lane = tid & 63;
    const int q = lane >> 4, n15 = lane & 15;
    const int mb = mtile*128 + w*32;
    const int lt0 = ls * 256;

    floatx4 acc[3][2];
#pragma unroll
    for (int i = 0; i < 3; i++)
#pragma unroll
        for (int in = 0; in < 2; in++) acc[i][in] = (floatx4){0.f,0.f,0.f,0.f};

    const uint2* bvec = (const uint2*)bits;
    const size_t bbase = ((size_t)(tb*H_ + h)*16)*1024 + mb + n15;
    const size_t y2b = ((size_t)tb*C_ + h*48)*L_;

    const int s_r0 = tid >> 4;
    const int s_r1 = (tid + 256) >> 4;
    const int s_r2 = (tid + 512) >> 4;
    const int s_c  = tid & 15;
    const size_t ro0 = y2b + (size_t)s_r0*L_ + s_c*4;
    const size_t ro1 = y2b + (size_t)s_r1*L_ + s_c*4;
    const size_t ro2 = y2b + (size_t)s_r2*L_ + s_c*4;

    uint2 rA[3][3];
#pragma unroll
    for (int p = 0; p < 3; p++) {
        const unsigned short* yp = p == 0 ? y2hi : p == 1 ? y2mi : y2lo;
        rA[p][0] = *(const uint2*)(yp + ro0 + lt0);
        rA[p][1] = *(const uint2*)(yp + ro1 + lt0);
        rA[p][2] = *(const uint2*)(yp + ro2 + lt0);
    }

    for (int it = 0; it < 4; it++) {
        const int lt = lt0 + it*64;
        *(uint2*)&A_hi[s_r0][s_c*4] = rA[0][0];
        *(uint2*)&A_hi[s_r1][s_c*4] = rA[0][1];
        *(uint2*)&A_hi[s_r2][s_c*4] = rA[0][2];
        *(uint2*)&A_mi[s_r0][s_c*4] = rA[1][0];
        *(uint2*)&A_mi[s_r1][s_c*4] = rA[1][1];
        *(uint2*)&A_mi[s_r2][s_c*4] = rA[1][2];
        *(uint2*)&A_lo[s_r0][s_c*4] = rA[2][0];
        *(uint2*)&A_lo[s_r1][s_c*4] = rA[2][1];
        *(uint2*)&A_lo[s_r2][s_c*4] = rA[2][2];
        uint2 bw0 = bvec[bbase + (size_t)(lt >> 6)*1024];
        uint2 bw1 = bvec[bbase + (size_t)(lt >> 6)*1024 + 16];
        __syncthreads();
        if (it < 3) {   // wave-uniform scalar guard
            const int nlt = lt + 64;
#pragma unroll
            for (int p = 0; p < 3; p++) {
                const unsigned short* yp = p == 0 ? y2hi : p == 1 ? y2mi : y2lo;
                rA[p][0] = *(const uint2*)(yp + ro0 + nlt);
                rA[p][1] = *(const uint2*)(yp + ro1 + nlt);
                rA[p][2] = *(const uint2*)(yp + ro2 + nlt);
            }
        }
#pragma unroll
        for (int kc = 0; kc < 2; kc++) {
            unsigned word0 = kc ? bw0.y : bw0.x;
            unsigned word1 = kc ? bw1.y : bw1.x;
            unsigned byt0 = (word0 >> (q*8)) & 0xFFu;
            unsigned byt1 = (word1 >> (q*8)) & 0xFFu;
            union { unsigned u[4]; short8 v; } bu0, bu1;
#pragma unroll
            for (int p = 0; p < 4; p++) {
                bu0.u[p] = (((byt0 >> (2*p)) & 1u) ? 0x3F80u : 0u)
                         | (((byt0 >> (2*p+1)) & 1u) ? 0x3F800000u : 0u);
                bu1.u[p] = (((byt1 >> (2*p)) & 1u) ? 0x3F80u : 0u)
                         | (((byt1 >> (2*p+1)) & 1u) ? 0x3F800000u : 0u);
            }
            short8 bf0 = bu0.v, bf1 = bu1.v;
#pragma unroll
            for (int i = 0; i < 3; i++) {
                int ra = i*16 + n15;
                short8 ah = *(short8*)&A_hi[ra][kc*32 + q*8];
                short8 am = *(short8*)&A_mi[ra][kc*32 + q*8];
                short8 al = *(short8*)&A_lo[ra][kc*32 + q*8];
                acc[i][0] = __builtin_amdgcn_mfma_f32_16x16x32_bf16(ah, bf0, acc[i][0], 0,0,0);
                acc[i][0] = __builtin_amdgcn_mfma_f32_16x16x32_bf16(am, bf0, acc[i][0], 0,0,0);
                acc[i][0] = __builtin_amdgcn_mfma_f32_16x16x32_bf16(al, bf0, acc[i][0], 0,0,0);
                acc[i][1] = __builtin_amdgcn_mfma_f32_16x16x32_bf16(ah, bf1, acc[i][1], 0,0,0);
                acc[i][1] = __builtin_amdgcn_mfma_f32_16x16x32_bf16(am, bf1, acc[i][1], 0,0,0);
                acc[i][1] = __builtin_amdgcn_mfma_f32_16x16x32_bf16(al, bf1, acc[i][1], 0,0,0);
            }
        }
        __syncthreads();
    }
    float* outP = ls == 0 ? op0 : ls == 1 ? op1 : ls == 2 ? op2 : op3;
#pragma unroll
    for (int i = 0; i < 3; i++)
#pragma unroll
        for (int r = 0; r < 4; r++) {
            int d = i*16 + q*4 + r;
#pragma unroll
            for (int in = 0; in < 2; in++)
                outP[((size_t)tb*C_ + h*48 + d)*L_ + mb + in*16 + n15] = acc[i][in][r];
        }
}

// ============ K6: out = BN2(proj @ outs) + x (MFMA, 96x64 tile) ============
__global__ __launch_bounds__(256) void gemm2_mfma(
    const unsigned short* __restrict__ whi, const unsigned short* __restrict__ wmi,
    const unsigned short* __restrict__ wlo, const unsigned short* __restrict__ xT,
    const float* __restrict__ g, const float* __restrict__ be,
    const float* __restrict__ mn, const float* __restrict__ vr,
    const float* __restrict__ res, float* __restrict__ out) {
    __shared__ unsigned short A_hi[96][40], A_mi[96][40], A_lo[96][40];
    __shared__ unsigned short B_s[64][40];
    const int tid = threadIdx.x;
    const int tb = blockIdx.y;
    const int mt = blockIdx.x >> 4, lt = blockIdx.x & 15;
    const int l0 = lt * 64;
    const int w = tid >> 6, lane = tid & 63;
    const int q = lane >> 4, n15 = lane & 15;
    const int mw = (w & 1) * 48, lw = (w >> 1) * 32;

    floatx4 acc[3][2];
#pragma unroll
    for (int i = 0; i < 3; i++)
#pragma unroll
        for (int j = 0; j < 2; j++) acc[i][j] = (floatx4){0.f,0.f,0.f,0.f};

    const int a_r0 = tid >> 3;
    const int a_r1 = (tid + 256) >> 3;
    const int a_r2 = (tid + 512) >> 3;
    const int a_c  = tid & 7;
    const int br = tid >> 2, bc = tid & 3;
    const size_t aro0 = (size_t)(mt*96 + a_r0)*C_;
    const size_t aro1 = (size_t)(mt*96 + a_r1)*C_;
    const size_t aro2 = (size_t)(mt*96 + a_r2)*C_;
    const size_t brow = ((size_t)tb*L_ + l0 + br)*C_;

    uint2 rA[3][3];
    uint4 rB;
#pragma unroll
    for (int p = 0; p < 3; p++) {
        const unsigned short* wp = p == 0 ? whi : p == 1 ? wmi : wlo;
        rA[p][0] = *(const uint2*)(wp + aro0 + a_c*4);
        rA[p][1] = *(const uint2*)(wp + aro1 + a_c*4);
        rA[p][2] = *(const uint2*)(wp + aro2 + a_c*4);
    }
    rB = *(const uint4*)(xT + brow + bc*8);

    for (int ck = 0; ck < C_; ck += 32) {
        {
            *(uint2*)&A_hi[a_r0][a_c*4] = rA[0][0];
            *(uint2*)&A_hi[a_r1][a_c*4] = rA[0][1];
            *(uint2*)&A_hi[a_r2][a_c*4] = rA[0][2];
            *(uint2*)&A_mi[a_r0][a_c*4] = rA[1][0];
            *(uint2*)&A_mi[a_r1][a_c*4] = rA[1][1];
            *(uint2*)&A_mi[a_r2][a_c*4] = rA[1][2];
            *(uint2*)&A_lo[a_r0][a_c*4] = rA[2][0];
            *(uint2*)&A_lo[a_r1][a_c*4] = rA[2][1];
            *(uint2*)&A_lo[a_r2][a_c*4] = rA[2][2];
        }
        *(uint4*)&B_s[br][bc*8] = rB;
        __syncthreads();
        if (ck + 32 < C_) {
            const int nk = ck + 32;
#pragma unroll
            for (int p = 0; p < 3; p++) {
                const unsigned short* wp = p == 0 ? whi : p == 1 ? wmi : wlo;
                rA[p][0] = *(const uint2*)(wp + aro0 + nk + a_c*4);
                rA[p][1] = *(const uint2*)(wp + aro1 + nk + a_c*4);
                rA[p][2] = *(const uint2*)(wp + aro2 + nk + a_c*4);
            }
            rB = *(const uint4*)(xT + brow + nk + bc*8);
        }
        short8 bb[2];
#pragma unroll
        for (int in = 0; in < 2; in++)
            bb[in] = *(short8*)&B_s[lw + in*16 + n15][q*8];
#pragma unroll
        for (int im = 0; im < 3; im++) {
            short8 ah = *(short8*)&A_hi[mw + im*16 + n15][q*8];
            short8 am = *(short8*)&A_mi[mw + im*16 + n15][q*8];
            short8 al = *(short8*)&A_lo[mw + im*16 + n15][q*8];
#pragma unroll
            for (int in = 0; in < 2; in++) {
                acc[im][in] = __builtin_amdgcn_mfma_f32_16x16x32_bf16(ah, bb[in], acc[im][in], 0,0,0);
                acc[im][in] = __builtin_amdgcn_mfma_f32_16x16x32_bf16(am, bb[in], acc[im][in], 0,0,0);
                acc[im][in] = __builtin_amdgcn_mfma_f32_16x16x32_bf16(al, bb[in], acc[im][in], 0,0,0);
            }
        }
        __syncthreads();
    }
#pragma unroll
    for (int im = 0; im < 3; im++)
#pragma unroll
        for (int r = 0; r < 4; r++) {
            int o = mt*96 + mw + im*16 + q*4 + r;
            float inv = g[o] / sqrtf(vr[o] + 1e-5f);
            float sh = be[o] - mn[o]*inv;
#pragma unroll
            for (int in = 0; in < 2; in++) {
                int l = l0 + lw + in*16 + n15;
                size_t idx = ((size_t)tb*C_ + o)*L_ + l;
                out[idx] = acc[im][in][r]*inv + sh + res[idx];
            }
        }
}

extern "C" void kernel_launch(void* const* d_in, const int* in_sizes, int n_in,
                              void* d_out, int out_size, void* d_ws, size_t ws_size,
                              hipStream_t stream) {
    const float* x   = (const float*)d_in[0];
    const float* W_w = (const float*)d_in[1];
    const float* g1  = (const float*)d_in[2];
    const float* b1  = (const float*)d_in[3];
    const float* m1  = (const float*)d_in[4];
    const float* v1  = (const float*)d_in[5];
    const float* pw  = (const float*)d_in[6];
    const float* g2  = (const float*)d_in[7];
    const float* b2  = (const float*)d_in[8];
    const float* m2  = (const float*)d_in[9];
    const float* v2  = (const float*)d_in[10];

    float* ws = (float*)d_ws;
    unsigned short* xsT  = (unsigned short*)ws;
    unsigned short* y1hi = (unsigned short*)(ws + 1572864);
    unsigned short* y1mi = (unsigned short*)(ws + 3145728);
    unsigned short* y1lo = (unsigned short*)(ws + 4718592);
    unsigned short* y2hi = (unsigned short*)(ws + 6291456);
    unsigned short* y2mi = (unsigned short*)(ws + 7864320);
    unsigned short* y2lo = (unsigned short*)(ws + 9437184);
    unsigned*       bits = (unsigned*)(ws + 11010048);
    unsigned short* wspl[3]  = {(unsigned short*)(ws + 13107200),
                                (unsigned short*)(ws + 13254656),
                                (unsigned short*)(ws + 13402112)};
    unsigned short* pwspl[3] = {(unsigned short*)(ws + 13549568),
                                (unsigned short*)(ws + 13623296),
                                (unsigned short*)(ws + 13697024)};
    unsigned short* xsF  = (unsigned short*)(ws + 13770752);
    float*          outpre  = (float*)(ws + 1572864);   // alias y1hi+y1mi (dead after K3)
    float*          outpre2 = (float*)(ws + 14557184);  // fresh 12.6 MB
    float*          outpre3 = (float*)(ws + 17702912);  // fresh 12.6 MB
    float*          outpre4 = (float*)(ws + 20848640);  // fresh 12.6 MB (ends 96 MB)
    unsigned short* outsT   = (unsigned short*)(ws + 4718592);  // alias y1lo
    float* out = (float*)d_out;

    // 1) xs scan (both layouts, prefetched, 384 blocks) + weight split
    scan_and_split<<<dim3(816), 256, 0, stream>>>(x, xsT, xsF,
                                                  W_w, C2_*C_/4, wspl[0], wspl[1], wspl[2],
                                                  pw,  C_*C_/4, pwspl[0], pwspl[1], pwspl[2]);
    // 2) y = BN1(W @ xs): stride-40 LDS + uniform register prefetch
    gemm1_mfma<<<dim3(1024), 256, 0, stream>>>(wspl[0], wspl[1], wspl[2], xsT,
                                               g1, b1, m1, v1,
                                               y1hi, y1mi, y1lo, y2hi, y2mi, y2lo);
    // 3) attn spikes: LDS-staged A (shared across waves), prefetched; B direct
    attn_spike_mfma<<<dim3(2048), 256, 0, stream>>>(y1hi, y1mi, y1lo, xsF, bits);
    // 4) outpre[0..3] = y2 @ spikes: 4-way split-K, grid 2048
    attn_out_mfma<<<dim3(2048), 256, 0, stream>>>(y2hi, y2mi, y2lo, bits,
                                                  outpre, outpre2, outpre3, outpre4);
    // 5) outs spikes = scan(sum of 4 partials) -> bf16 transposed
    scan_transpose4<<<dim3(384), 256, 0, stream>>>(outpre, outpre2, outpre3, outpre4, outsT);
    // 6) out = BN2(proj @ outs) + x: uniform-prefetch K-loop
    gemm2_mfma<<<dim3(64, 8), 256, 0, stream>>>(pwspl[0], pwspl[1], pwspl[2], outsT,
                                                g2, b2, m2, v2, x, out);
}